// Round 1
// baseline (4723.800 us; speedup 1.0000x reference)
//
#include <hip/hip_runtime.h>
#include <cstdint>
#include <cstddef>

#define NNODES 50000
#define NEDGE0 400000
#define NETOT  450000
#define NGRAPH 1024
#define CH     312
#define HC     624

// ---------------- GEMM: C[M,N] = A[M,K] @ B[K,N] (+bias, +relu) ----------------
__global__ __launch_bounds__(256) void gemm_f32(
    const float* __restrict__ A, const float* __restrict__ B,
    float* __restrict__ C, int M, int N, int K,
    const float* __restrict__ bias, int act)
{
  __shared__ float As[16][65];
  __shared__ float Bs[16][65];
  int bm = blockIdx.y * 64, bn = blockIdx.x * 64;
  int tx = threadIdx.x, ty = threadIdx.y;
  int tid = ty * 16 + tx;
  float acc[4][4] = {};
  for (int k0 = 0; k0 < K; k0 += 16) {
    for (int i = tid; i < 64 * 16; i += 256) {
      int m = i >> 4, kk = i & 15;
      int gm = bm + m, gk = k0 + kk;
      As[kk][m] = (gm < M && gk < K) ? A[(size_t)gm * K + gk] : 0.f;
    }
    for (int i = tid; i < 16 * 64; i += 256) {
      int kk = i >> 6, n = i & 63;
      int gk = k0 + kk, gn = bn + n;
      Bs[kk][n] = (gk < K && gn < N) ? B[(size_t)gk * N + gn] : 0.f;
    }
    __syncthreads();
    #pragma unroll
    for (int kk = 0; kk < 16; ++kk) {
      float a[4], b[4];
      #pragma unroll
      for (int i = 0; i < 4; ++i) a[i] = As[kk][ty * 4 + i];
      #pragma unroll
      for (int j = 0; j < 4; ++j) b[j] = Bs[kk][tx * 4 + j];
      #pragma unroll
      for (int i = 0; i < 4; ++i)
        #pragma unroll
        for (int j = 0; j < 4; ++j)
          acc[i][j] += a[i] * b[j];
    }
    __syncthreads();
  }
  #pragma unroll
  for (int i = 0; i < 4; ++i) {
    int gm = bm + ty * 4 + i;
    if (gm >= M) continue;
    #pragma unroll
    for (int j = 0; j < 4; ++j) {
      int gn = bn + tx * 4 + j;
      if (gn >= N) continue;
      float v = acc[i][j];
      if (bias) v += bias[gn];
      if (act == 1) v = v > 0.f ? v : 0.f;
      C[(size_t)gm * N + gn] = v;
    }
  }
}

// ---------------- attention scores: s[n,h] = sum_c h[n,h,c]*a[h,c] ----------------
__global__ __launch_bounds__(256) void scores_k(
    const float* __restrict__ h, const float* __restrict__ asrc,
    const float* __restrict__ adst, float* __restrict__ ssrc,
    float* __restrict__ sdst)
{
  int wave = (blockIdx.x * blockDim.x + threadIdx.x) >> 6;
  int lane = threadIdx.x & 63;
  if (wave >= NNODES) return;
  const float* hp = h + (size_t)wave * HC;
  float ss0 = 0, ss1 = 0, sd0 = 0, sd1 = 0;
  for (int c = lane; c < CH; c += 64) {
    float v0 = hp[c], v1 = hp[CH + c];
    ss0 += v0 * asrc[c];  ss1 += v1 * asrc[CH + c];
    sd0 += v0 * adst[c];  sd1 += v1 * adst[CH + c];
  }
  #pragma unroll
  for (int off = 32; off; off >>= 1) {
    ss0 += __shfl_xor(ss0, off);
    ss1 += __shfl_xor(ss1, off);
    sd0 += __shfl_xor(sd0, off);
    sd1 += __shfl_xor(sd1, off);
  }
  if (lane == 0) {
    ssrc[wave * 2] = ss0; ssrc[wave * 2 + 1] = ss1;
    sdst[wave * 2] = sd0; sdst[wave * 2 + 1] = sd1;
  }
}

// order-preserving float<->uint key for atomicMax
__device__ inline unsigned fkey(float v) {
  unsigned u = __float_as_uint(v);
  return (u & 0x80000000u) ? ~u : (u | 0x80000000u);
}
__device__ inline float fdec(unsigned k) {
  return __uint_as_float((k & 0x80000000u) ? (k & 0x7fffffffu) : ~k);
}

__global__ void alphamax_k(const int* __restrict__ ei,
    const float* __restrict__ ssrc, const float* __restrict__ sdst,
    float* __restrict__ alpha, unsigned* __restrict__ mkey)
{
  int e = blockIdx.x * blockDim.x + threadIdx.x;
  if (e >= NETOT) return;
  int s, d;
  if (e < NEDGE0) { s = ei[e]; d = ei[NEDGE0 + e]; }
  else { s = d = e - NEDGE0; }
  float a0 = ssrc[s * 2]     + sdst[d * 2];
  float a1 = ssrc[s * 2 + 1] + sdst[d * 2 + 1];
  a0 = a0 > 0.f ? a0 : 0.2f * a0;
  a1 = a1 > 0.f ? a1 : 0.2f * a1;
  alpha[e * 2] = a0; alpha[e * 2 + 1] = a1;
  atomicMax(&mkey[d * 2],     fkey(a0));
  atomicMax(&mkey[d * 2 + 1], fkey(a1));
}

__global__ void expz_k(const int* __restrict__ ei, float* __restrict__ alpha,
                       const unsigned* __restrict__ mkey, float* __restrict__ zsum)
{
  int e = blockIdx.x * blockDim.x + threadIdx.x;
  if (e >= NETOT) return;
  int d = (e < NEDGE0) ? ei[NEDGE0 + e] : e - NEDGE0;
  float m0 = fdec(mkey[d * 2]), m1 = fdec(mkey[d * 2 + 1]);
  float v0 = expf(alpha[e * 2] - m0);
  float v1 = expf(alpha[e * 2 + 1] - m1);
  alpha[e * 2] = v0; alpha[e * 2 + 1] = v1;
  atomicAdd(&zsum[d * 2], v0);
  atomicAdd(&zsum[d * 2 + 1], v1);
}

// wave per edge: out[dst,c] += 0.5*(coef0*h[src,0,c] + coef1*h[src,1,c])
__global__ __launch_bounds__(256) void msg_k(const int* __restrict__ ei,
    const float* __restrict__ h, const float* __restrict__ ebuf,
    const float* __restrict__ zsum, float* __restrict__ out)
{
  int wave = (blockIdx.x * blockDim.x + threadIdx.x) >> 6;
  int lane = threadIdx.x & 63;
  if (wave >= NETOT) return;
  int s, d;
  if (wave < NEDGE0) { s = ei[wave]; d = ei[NEDGE0 + wave]; }
  else { s = d = wave - NEDGE0; }
  float c0 = 0.5f * ebuf[wave * 2]     / (zsum[d * 2]     + 1e-16f);
  float c1 = 0.5f * ebuf[wave * 2 + 1] / (zsum[d * 2 + 1] + 1e-16f);
  const float* hp = h + (size_t)s * HC;
  float* op = out + (size_t)d * CH;
  for (int c = lane; c < CH; c += 64)
    atomicAdd(&op[c], c0 * hp[c] + c1 * hp[CH + c]);
}

__global__ void epi0_k(const float* __restrict__ xacc, const float* __restrict__ b,
                       float* __restrict__ hstate)
{
  int i = blockIdx.x * blockDim.x + threadIdx.x;
  if (i >= NNODES * CH) return;
  int c = i % CH;
  float v = xacc[i] + b[c];
  hstate[i] = v > 0.f ? v : 0.f;
}

__global__ void biasact_k(float* __restrict__ x, const float* __restrict__ b, int act)
{
  int i = blockIdx.x * blockDim.x + threadIdx.x;
  if (i >= NNODES * CH) return;
  int c = i % CH;
  float v = x[i] + b[c];
  if (act) v = v > 0.f ? v : 0.f;
  x[i] = v;
}

__global__ void gate_k(const float* __restrict__ t1, const float* __restrict__ fc1b,
                       const float* __restrict__ t2, const float* __restrict__ fc2b,
                       const float* __restrict__ mbias, const float* __restrict__ x,
                       float* __restrict__ hstate)
{
  int i = blockIdx.x * blockDim.x + threadIdx.x;
  if (i >= NNODES * CH) return;
  int c = i % CH;
  float g = t1[i] + fc1b[c] + t2[i] + fc2b[c] + mbias[c];
  g = 1.f / (1.f + expf(-g));
  hstate[i] = g * x[i] + (1.f - g) * hstate[i];
}

__global__ void poolacc_k(const float* __restrict__ hstate, const int* __restrict__ batch,
                          float* __restrict__ psum)
{
  int i = blockIdx.x * blockDim.x + threadIdx.x;
  if (i >= NNODES * CH) return;
  int n = i / CH, c = i % CH;
  atomicAdd(&psum[(size_t)batch[n] * CH + c], hstate[i]);
}

__global__ void poolcnt_k(const int* __restrict__ batch, float* __restrict__ pcnt)
{
  int n = blockIdx.x * blockDim.x + threadIdx.x;
  if (n >= NNODES) return;
  atomicAdd(&pcnt[batch[n]], 1.f);
}

__global__ void pooldiv_k(const float* __restrict__ psum, const float* __restrict__ pcnt,
                          float* __restrict__ pooled)
{
  int i = blockIdx.x * blockDim.x + threadIdx.x;
  if (i >= NGRAPH * CH) return;
  int g = i / CH;
  float c = pcnt[g];
  c = c > 1.f ? c : 1.f;
  pooled[i] = psum[i] / c;
}

extern "C" void kernel_launch(void* const* d_in, const int* in_sizes, int n_in,
                              void* d_out, int out_size, void* d_ws, size_t ws_size,
                              hipStream_t stream)
{
  const float* mol_x = (const float*)d_in[0];
  const int*   ei    = (const int*)d_in[1];
  const int*   batch = (const int*)d_in[2];
  const float* W0  = (const float*)d_in[3];
  const float* as0 = (const float*)d_in[4];
  const float* ad0 = (const float*)d_in[5];
  const float* b0  = (const float*)d_in[6];
  const float* W1  = (const float*)d_in[7];
  const float* as1 = (const float*)d_in[8];
  const float* ad1 = (const float*)d_in[9];
  const float* b1  = (const float*)d_in[10];
  const float* W2  = (const float*)d_in[11];
  const float* as2 = (const float*)d_in[12];
  const float* ad2 = (const float*)d_in[13];
  const float* b2  = (const float*)d_in[14];
  const float* fc1w = (const float*)d_in[15];
  const float* fc1b = (const float*)d_in[16];
  const float* fc2w = (const float*)d_in[17];
  const float* fc2b = (const float*)d_in[18];
  const float* mbias = (const float*)d_in[19];
  const float* g1w = (const float*)d_in[20];
  const float* g1b = (const float*)d_in[21];
  const float* g2w = (const float*)d_in[22];
  const float* g2b = (const float*)d_in[23];
  float* out = (float*)d_out;

  char* ws = (char*)d_ws;
  size_t off = 0;
  auto alloc = [&](size_t b) { size_t r = off; off += (b + 255) & ~(size_t)255; return r; };
  float*    h      = (float*)(ws + alloc((size_t)NNODES * HC * 4));
  float*    xbuf   = (float*)(ws + alloc((size_t)NNODES * CH * 4));
  float*    hstate = (float*)(ws + alloc((size_t)NNODES * CH * 4));
  float*    alpha  = (float*)(ws + alloc((size_t)NETOT * 2 * 4));
  float*    ssrc   = (float*)(ws + alloc((size_t)NNODES * 2 * 4));
  float*    sdst   = (float*)(ws + alloc((size_t)NNODES * 2 * 4));
  unsigned* mkey   = (unsigned*)(ws + alloc((size_t)NNODES * 2 * 4));
  float*    zsum   = (float*)(ws + alloc((size_t)NNODES * 2 * 4));
  float*    psum   = (float*)(ws + alloc((size_t)NGRAPH * CH * 4));
  float*    pcnt   = (float*)(ws + alloc((size_t)NGRAPH * 4));
  float*    pooled = (float*)(ws + alloc((size_t)NGRAPH * CH * 4));
  float*    gbuf   = (float*)(ws + alloc((size_t)NGRAPH * 1024 * 4));
  float*    t1 = h;                        // reuse h region after message pass
  float*    t2 = h + (size_t)NNODES * CH;

  dim3 blk(16, 16);
  auto gemm = [&](const float* A, const float* B, float* C, int M, int N, int K,
                  const float* bias, int act) {
    dim3 grid((N + 63) / 64, (M + 63) / 64);
    hipLaunchKernelGGL(gemm_f32, grid, blk, 0, stream, A, B, C, M, N, K, bias, act);
  };

  const int ELT = NNODES * CH;                 // 15.6M
  auto gat = [&](const float* X, int Din, const float* W, const float* as_,
                 const float* ad_) {
    gemm(X, W, h, NNODES, HC, Din, nullptr, 0);
    scores_k<<<(NNODES * 64 + 255) / 256, 256, 0, stream>>>(h, as_, ad_, ssrc, sdst);
    hipMemsetAsync(mkey, 0, (size_t)NNODES * 2 * 4, stream);
    hipMemsetAsync(zsum, 0, (size_t)NNODES * 2 * 4, stream);
    hipMemsetAsync(xbuf, 0, (size_t)NNODES * CH * 4, stream);
    alphamax_k<<<(NETOT + 255) / 256, 256, 0, stream>>>(ei, ssrc, sdst, alpha, mkey);
    expz_k<<<(NETOT + 255) / 256, 256, 0, stream>>>(ei, alpha, mkey, zsum);
    msg_k<<<(NETOT * 64 + 255) / 256, 256, 0, stream>>>(ei, h, alpha, zsum, xbuf);
  };

  // ---- layer 0 ----
  gat(mol_x, 78, W0, as0, ad0);
  epi0_k<<<(ELT + 255) / 256, 256, 0, stream>>>(xbuf, b0, hstate);

  // ---- layer 1 ----
  gat(hstate, CH, W1, as1, ad1);
  biasact_k<<<(ELT + 255) / 256, 256, 0, stream>>>(xbuf, b1, 1);
  gemm(xbuf, fc1w, t1, NNODES, CH, CH, nullptr, 0);
  gemm(hstate, fc2w, t2, NNODES, CH, CH, nullptr, 0);
  gate_k<<<(ELT + 255) / 256, 256, 0, stream>>>(t1, fc1b, t2, fc2b, mbias, xbuf, hstate);

  // ---- layer 2 ----
  gat(hstate, CH, W2, as2, ad2);
  biasact_k<<<(ELT + 255) / 256, 256, 0, stream>>>(xbuf, b2, 0);
  gemm(xbuf, fc1w, t1, NNODES, CH, CH, nullptr, 0);
  gemm(hstate, fc2w, t2, NNODES, CH, CH, nullptr, 0);
  gate_k<<<(ELT + 255) / 256, 256, 0, stream>>>(t1, fc1b, t2, fc2b, mbias, xbuf, hstate);

  // ---- pool + head ----
  hipMemsetAsync(psum, 0, (size_t)NGRAPH * CH * 4, stream);
  hipMemsetAsync(pcnt, 0, (size_t)NGRAPH * 4, stream);
  poolacc_k<<<(ELT + 255) / 256, 256, 0, stream>>>(hstate, batch, psum);
  poolcnt_k<<<(NNODES + 255) / 256, 256, 0, stream>>>(batch, pcnt);
  pooldiv_k<<<(NGRAPH * CH + 255) / 256, 256, 0, stream>>>(psum, pcnt, pooled);
  gemm(pooled, g1w, gbuf, NGRAPH, 1024, CH, g1b, 1);
  gemm(gbuf, g2w, out, NGRAPH, 128, 1024, g2b, 0);
}

// Round 2
// 4472.033 us; speedup vs baseline: 1.0563x; 1.0563x over previous
//
#include <hip/hip_runtime.h>
#include <cstdint>
#include <cstddef>

#define NNODES 50000
#define NEDGE0 400000
#define NETOT  450000
#define NGRAPH 1024
#define CH     312
#define HC     624

typedef __attribute__((ext_vector_type(4))) float f32x4;
typedef __attribute__((ext_vector_type(8))) short s16x8;

__device__ inline unsigned short f2bf(float x) {
  union { float f; unsigned u; } v; v.f = x;
  unsigned r = v.u + 0x7fffu + ((v.u >> 16) & 1u);   // RNE
  return (unsigned short)(r >> 16);
}

// ============ weight transpose+cast: in[K][N] f32 -> out[N][K] bf16 ============
__global__ void tcast_k(const float* __restrict__ in, unsigned short* __restrict__ out,
                        int K, int N) {
  int i = blockIdx.x * blockDim.x + threadIdx.x;
  if (i >= N * K) return;
  int n = i / K, k = i - n * K;
  out[i] = f2bf(in[(size_t)k * N + n]);
}

// ============ MFMA GEMM: C[M,N] f32 = A[M,K] f32 @ Bt[N,K] bf16 ============
// BM=128, BN=64, 256 threads (4 waves as 2x2), full K in LDS (K<=312, even).
__global__ __launch_bounds__(256) void gemm_mfma(
    const float* __restrict__ A, const unsigned short* __restrict__ Bt,
    float* __restrict__ C, int M, int N, int K)
{
  const int KP  = (K + 31) & ~31;     // K padded to 32
  const int RS  = KP + 8;             // row stride in shorts (bank-spread pad)
  const int RSH = RS >> 1;            // row stride in uints
  __shared__ short As[128 * 328];
  __shared__ short Bs[64 * 328];
  const int tid  = threadIdx.x;
  const int lane = tid & 63, w = tid >> 6;
  const int bm = blockIdx.y * 128, bn = blockIdx.x * 64;

  // ---- stage A (f32 -> bf16), zero-pad rows>=M and k>=K ----
  for (int r = w; r < 128; r += 4) {
    int gm = bm + r;
    const float2* src = (const float2*)(A + (size_t)gm * K);
    unsigned* dst = (unsigned*)(As) + r * RSH;
    for (int k2 = lane; k2 < RSH; k2 += 64) {
      unsigned val = 0;
      if (gm < M && 2 * k2 < K) {
        float2 f = src[k2];
        val = (unsigned)f2bf(f.x) | ((unsigned)f2bf(f.y) << 16);
      }
      dst[k2] = val;
    }
  }
  // ---- stage B panel (bf16 copy from transposed weights) ----
  for (int c = w; c < 64; c += 4) {
    int gn = bn + c;
    const unsigned* src = (const unsigned*)(Bt + (size_t)gn * K);
    unsigned* dst = (unsigned*)(Bs) + c * RSH;
    for (int k2 = lane; k2 < RSH; k2 += 64) {
      unsigned val = 0;
      if (gn < N && 2 * k2 < K) val = src[k2];
      dst[k2] = val;
    }
  }
  __syncthreads();

  const int wr = w >> 1, wc = w & 1;        // wave -> 64x32 output sub-tile
  const int r16 = lane & 15, g = lane >> 4;
  f32x4 zf = {0.f, 0.f, 0.f, 0.f};
  f32x4 acc[4][2];
  #pragma unroll
  for (int m = 0; m < 4; ++m)
    #pragma unroll
    for (int n = 0; n < 2; ++n) acc[m][n] = zf;

  const int nkt = KP >> 5;
  for (int kt = 0; kt < nkt; ++kt) {
    // consistent k-bijection for A and B frags: k = kt*32 + 8*g + j  (contiguous 16B)
    const int kb = (kt << 5) + (g << 3);
    s16x8 bf0 = *(const s16x8*)(Bs + (wc * 32 +      r16) * RS + kb);
    s16x8 bf1 = *(const s16x8*)(Bs + (wc * 32 + 16 + r16) * RS + kb);
    #pragma unroll
    for (int m = 0; m < 4; ++m) {
      s16x8 af = *(const s16x8*)(As + (wr * 64 + m * 16 + r16) * RS + kb);
      acc[m][0] = __builtin_amdgcn_mfma_f32_16x16x32_bf16(af, bf0, acc[m][0], 0, 0, 0);
      acc[m][1] = __builtin_amdgcn_mfma_f32_16x16x32_bf16(af, bf1, acc[m][1], 0, 0, 0);
    }
  }
  // ---- write C: D[row=4*g+r][col=r16] per 16x16 tile ----
  #pragma unroll
  for (int m = 0; m < 4; ++m) {
    int gm0 = bm + wr * 64 + m * 16 + g * 4;
    #pragma unroll
    for (int n = 0; n < 2; ++n) {
      int gn = bn + wc * 32 + n * 16 + r16;
      if (gn >= N) continue;
      #pragma unroll
      for (int r = 0; r < 4; ++r) {
        int gm = gm0 + r;
        if (gm < M) C[(size_t)gm * N + gn] = acc[m][n][r];
      }
    }
  }
}

// ============ legacy f32 tiled GEMM (head layers only) ============
__global__ __launch_bounds__(256) void gemm_f32(
    const float* __restrict__ A, const float* __restrict__ B,
    float* __restrict__ C, int M, int N, int K,
    const float* __restrict__ bias, int act)
{
  __shared__ float As[16][65];
  __shared__ float Bs[16][65];
  int bm = blockIdx.y * 64, bn = blockIdx.x * 64;
  int tx = threadIdx.x, ty = threadIdx.y;
  int tid = ty * 16 + tx;
  float acc[4][4] = {};
  for (int k0 = 0; k0 < K; k0 += 16) {
    for (int i = tid; i < 64 * 16; i += 256) {
      int m = i >> 4, kk = i & 15;
      int gm = bm + m, gk = k0 + kk;
      As[kk][m] = (gm < M && gk < K) ? A[(size_t)gm * K + gk] : 0.f;
    }
    for (int i = tid; i < 16 * 64; i += 256) {
      int kk = i >> 6, n = i & 63;
      int gk = k0 + kk, gn = bn + n;
      Bs[kk][n] = (gk < K && gn < N) ? B[(size_t)gk * N + gn] : 0.f;
    }
    __syncthreads();
    #pragma unroll
    for (int kk = 0; kk < 16; ++kk) {
      float a[4], b[4];
      #pragma unroll
      for (int i = 0; i < 4; ++i) a[i] = As[kk][ty * 4 + i];
      #pragma unroll
      for (int j = 0; j < 4; ++j) b[j] = Bs[kk][tx * 4 + j];
      #pragma unroll
      for (int i = 0; i < 4; ++i)
        #pragma unroll
        for (int j = 0; j < 4; ++j)
          acc[i][j] += a[i] * b[j];
    }
    __syncthreads();
  }
  #pragma unroll
  for (int i = 0; i < 4; ++i) {
    int gm = bm + ty * 4 + i;
    if (gm >= M) continue;
    #pragma unroll
    for (int j = 0; j < 4; ++j) {
      int gn = bn + tx * 4 + j;
      if (gn >= N) continue;
      float v = acc[i][j];
      if (bias) v += bias[gn];
      if (act == 1) v = v > 0.f ? v : 0.f;
      C[(size_t)gm * N + gn] = v;
    }
  }
}

// ============ attention scores: s[n,h] = sum_c h[n,h,c]*a[h,c] ============
__global__ __launch_bounds__(256) void scores_k(
    const float* __restrict__ h, const float* __restrict__ asrc,
    const float* __restrict__ adst, float* __restrict__ ssrc,
    float* __restrict__ sdst)
{
  int wave = (blockIdx.x * blockDim.x + threadIdx.x) >> 6;
  int lane = threadIdx.x & 63;
  if (wave >= NNODES) return;
  const float* hp = h + (size_t)wave * HC;
  float ss0 = 0, ss1 = 0, sd0 = 0, sd1 = 0;
  for (int c = lane; c < CH; c += 64) {
    float v0 = hp[c], v1 = hp[CH + c];
    ss0 += v0 * asrc[c];  ss1 += v1 * asrc[CH + c];
    sd0 += v0 * adst[c];  sd1 += v1 * adst[CH + c];
  }
  #pragma unroll
  for (int off = 32; off; off >>= 1) {
    ss0 += __shfl_xor(ss0, off);
    ss1 += __shfl_xor(ss1, off);
    sd0 += __shfl_xor(sd0, off);
    sd1 += __shfl_xor(sd1, off);
  }
  if (lane == 0) {
    ssrc[wave * 2] = ss0; ssrc[wave * 2 + 1] = ss1;
    sdst[wave * 2] = sd0; sdst[wave * 2 + 1] = sd1;
  }
}

// ============ CSR build ============
__global__ void hist_k(const int* __restrict__ ei, int* __restrict__ cnt) {
  int e = blockIdx.x * blockDim.x + threadIdx.x;
  if (e >= NETOT) return;
  int d = (e < NEDGE0) ? ei[NEDGE0 + e] : e - NEDGE0;
  atomicAdd(&cnt[d], 1);
}

__global__ __launch_bounds__(1024) void scan_k(const int* __restrict__ cnt,
                                               int* __restrict__ rowptr) {
  __shared__ int s[1024];
  int t = threadIdx.x;
  int carry = 0;
  for (int base = 0; base < NNODES; base += 1024) {
    int idx = base + t;
    int v = (idx < NNODES) ? cnt[idx] : 0;
    s[t] = v;
    __syncthreads();
    for (int off = 1; off < 1024; off <<= 1) {
      int x = (t >= off) ? s[t - off] : 0;
      __syncthreads();
      s[t] += x;
      __syncthreads();
    }
    if (idx < NNODES) rowptr[idx] = carry + s[t] - v;
    int tot = s[1023];
    __syncthreads();
    carry += tot;
  }
  if (t == 0) rowptr[NNODES] = carry;
}

__global__ void scatter_k(const int* __restrict__ ei, const int* __restrict__ rowptr,
                          int* __restrict__ cur, int* __restrict__ esrc) {
  int e = blockIdx.x * blockDim.x + threadIdx.x;
  if (e >= NETOT) return;
  int s, d;
  if (e < NEDGE0) { s = ei[e]; d = ei[NEDGE0 + e]; }
  else { s = d = e - NEDGE0; }
  int pos = rowptr[d] + atomicAdd(&cur[d], 1);
  esrc[pos] = s;
}

// ============ per-dst online softmax max/sum ============
__global__ void mz_k(const int* __restrict__ rowptr, const int* __restrict__ esrc,
                     const float* __restrict__ ssrc, const float* __restrict__ sdst,
                     float* __restrict__ mval, float* __restrict__ zval) {
  int n = blockIdx.x * blockDim.x + threadIdx.x;
  if (n >= NNODES) return;
  int e0 = rowptr[n], e1 = rowptr[n + 1];
  float sd0 = sdst[2 * n], sd1 = sdst[2 * n + 1];
  float m0 = -1e30f, m1 = -1e30f, z0 = 0.f, z1 = 0.f;
  for (int e = e0; e < e1; ++e) {
    int s = esrc[e];
    float a0 = ssrc[2 * s] + sd0;     a0 = a0 > 0.f ? a0 : 0.2f * a0;
    float a1 = ssrc[2 * s + 1] + sd1; a1 = a1 > 0.f ? a1 : 0.2f * a1;
    float nm0 = fmaxf(m0, a0);
    z0 = z0 * __expf(m0 - nm0) + __expf(a0 - nm0); m0 = nm0;
    float nm1 = fmaxf(m1, a1);
    z1 = z1 * __expf(m1 - nm1) + __expf(a1 - nm1); m1 = nm1;
  }
  mval[2 * n] = m0; mval[2 * n + 1] = m1;
  zval[2 * n] = z0; zval[2 * n + 1] = z1;
}

// ============ per-dst gather-accumulate + bias + act (wave per node) ============
__global__ __launch_bounds__(256) void msgcsr_k(
    const int* __restrict__ rowptr, const int* __restrict__ esrc,
    const float* __restrict__ ssrc, const float* __restrict__ sdst,
    const float* __restrict__ mval, const float* __restrict__ zval,
    const float* __restrict__ h, const float* __restrict__ bias, int act,
    float* __restrict__ out)
{
  int wave = (blockIdx.x * blockDim.x + threadIdx.x) >> 6;
  int lane = threadIdx.x & 63;
  if (wave >= NNODES) return;
  int e0 = rowptr[wave], e1 = rowptr[wave + 1];
  float sd0 = sdst[2 * wave], sd1 = sdst[2 * wave + 1];
  float m0 = mval[2 * wave], m1 = mval[2 * wave + 1];
  float i0 = 0.5f / (zval[2 * wave] + 1e-16f);
  float i1 = 0.5f / (zval[2 * wave + 1] + 1e-16f);
  float acc[5] = {0, 0, 0, 0, 0};
  for (int e = e0; e < e1; ++e) {
    int s = esrc[e];
    float a0 = ssrc[2 * s] + sd0;     a0 = a0 > 0.f ? a0 : 0.2f * a0;
    float a1 = ssrc[2 * s + 1] + sd1; a1 = a1 > 0.f ? a1 : 0.2f * a1;
    float c0 = __expf(a0 - m0) * i0;
    float c1 = __expf(a1 - m1) * i1;
    const float* hp = h + (size_t)s * HC;
    #pragma unroll
    for (int i = 0; i < 5; ++i) {
      int c = lane + (i << 6);
      if (c < CH) acc[i] += c0 * hp[c] + c1 * hp[CH + c];
    }
  }
  float* op = out + (size_t)wave * CH;
  #pragma unroll
  for (int i = 0; i < 5; ++i) {
    int c = lane + (i << 6);
    if (c < CH) {
      float v = acc[i] + bias[c];
      if (act) v = v > 0.f ? v : 0.f;
      op[c] = v;
    }
  }
}

// ============ gated residual ============
__global__ void gate_k(const float* __restrict__ t1, const float* __restrict__ fc1b,
                       const float* __restrict__ t2, const float* __restrict__ fc2b,
                       const float* __restrict__ mbias, const float* __restrict__ x,
                       float* __restrict__ hstate)
{
  int i = blockIdx.x * blockDim.x + threadIdx.x;
  if (i >= NNODES * CH) return;
  int c = i % CH;
  float g = t1[i] + fc1b[c] + t2[i] + fc2b[c] + mbias[c];
  g = 1.f / (1.f + __expf(-g));
  hstate[i] = g * x[i] + (1.f - g) * hstate[i];
}

// ============ pooling ============
__global__ void poolacc_k(const float* __restrict__ hstate, const int* __restrict__ batch,
                          float* __restrict__ psum)
{
  int i = blockIdx.x * blockDim.x + threadIdx.x;
  if (i >= NNODES * CH) return;
  int n = i / CH, c = i % CH;
  atomicAdd(&psum[(size_t)batch[n] * CH + c], hstate[i]);
}

__global__ void poolcnt_k(const int* __restrict__ batch, float* __restrict__ pcnt)
{
  int n = blockIdx.x * blockDim.x + threadIdx.x;
  if (n >= NNODES) return;
  atomicAdd(&pcnt[batch[n]], 1.f);
}

__global__ void pooldiv_k(const float* __restrict__ psum, const float* __restrict__ pcnt,
                          float* __restrict__ pooled)
{
  int i = blockIdx.x * blockDim.x + threadIdx.x;
  if (i >= NGRAPH * CH) return;
  int g = i / CH;
  float c = pcnt[g];
  c = c > 1.f ? c : 1.f;
  pooled[i] = psum[i] / c;
}

extern "C" void kernel_launch(void* const* d_in, const int* in_sizes, int n_in,
                              void* d_out, int out_size, void* d_ws, size_t ws_size,
                              hipStream_t stream)
{
  const float* mol_x = (const float*)d_in[0];
  const int*   ei    = (const int*)d_in[1];
  const int*   batch = (const int*)d_in[2];
  const float* W0  = (const float*)d_in[3];
  const float* as0 = (const float*)d_in[4];
  const float* ad0 = (const float*)d_in[5];
  const float* b0  = (const float*)d_in[6];
  const float* W1  = (const float*)d_in[7];
  const float* as1 = (const float*)d_in[8];
  const float* ad1 = (const float*)d_in[9];
  const float* b1  = (const float*)d_in[10];
  const float* W2  = (const float*)d_in[11];
  const float* as2 = (const float*)d_in[12];
  const float* ad2 = (const float*)d_in[13];
  const float* b2  = (const float*)d_in[14];
  const float* fc1w = (const float*)d_in[15];
  const float* fc1b = (const float*)d_in[16];
  const float* fc2w = (const float*)d_in[17];
  const float* fc2b = (const float*)d_in[18];
  const float* mbias = (const float*)d_in[19];
  const float* g1w = (const float*)d_in[20];
  const float* g1b = (const float*)d_in[21];
  const float* g2w = (const float*)d_in[22];
  const float* g2b = (const float*)d_in[23];
  float* out = (float*)d_out;

  char* ws = (char*)d_ws;
  size_t off = 0;
  auto alloc = [&](size_t b) { size_t r = off; off += (b + 255) & ~(size_t)255; return r; };
  float* h      = (float*)(ws + alloc((size_t)NNODES * HC * 4));
  float* xbuf   = (float*)(ws + alloc((size_t)NNODES * CH * 4));
  float* hstate = (float*)(ws + alloc((size_t)NNODES * CH * 4));
  float* ssrc   = (float*)(ws + alloc((size_t)NNODES * 2 * 4));
  float* sdst   = (float*)(ws + alloc((size_t)NNODES * 2 * 4));
  float* mval   = (float*)(ws + alloc((size_t)NNODES * 2 * 4));
  float* zval   = (float*)(ws + alloc((size_t)NNODES * 2 * 4));
  int*   cnt    = (int*)(ws + alloc((size_t)NNODES * 4));
  int*   cnt2   = (int*)(ws + alloc((size_t)NNODES * 4));
  int*   rowptr = (int*)(ws + alloc((size_t)(NNODES + 1) * 4));
  int*   esrc   = (int*)(ws + alloc((size_t)NETOT * 4));
  float* psum   = (float*)(ws + alloc((size_t)NGRAPH * CH * 4));
  float* pcnt   = (float*)(ws + alloc((size_t)NGRAPH * 4));
  float* pooled = (float*)(ws + alloc((size_t)NGRAPH * CH * 4));
  float* gbuf   = (float*)(ws + alloc((size_t)NGRAPH * 1024 * 4));
  unsigned short* w0t  = (unsigned short*)(ws + alloc((size_t)HC * 78 * 2));
  unsigned short* w1t  = (unsigned short*)(ws + alloc((size_t)HC * CH * 2));
  unsigned short* w2t  = (unsigned short*)(ws + alloc((size_t)HC * CH * 2));
  unsigned short* fc1t = (unsigned short*)(ws + alloc((size_t)CH * CH * 2));
  unsigned short* fc2t = (unsigned short*)(ws + alloc((size_t)CH * CH * 2));
  float* t1 = h;                          // reuse h region after message pass
  float* t2 = h + (size_t)NNODES * CH;

  // ---- pre-pass: CSR build + weight transpose/cast ----
  hipMemsetAsync(cnt, 0, (size_t)NNODES * 4, stream);
  hipMemsetAsync(cnt2, 0, (size_t)NNODES * 4, stream);
  hist_k<<<(NETOT + 255) / 256, 256, 0, stream>>>(ei, cnt);
  scan_k<<<1, 1024, 0, stream>>>(cnt, rowptr);
  scatter_k<<<(NETOT + 255) / 256, 256, 0, stream>>>(ei, rowptr, cnt2, esrc);
  tcast_k<<<(78 * HC + 255) / 256, 256, 0, stream>>>(W0, w0t, 78, HC);
  tcast_k<<<(CH * HC + 255) / 256, 256, 0, stream>>>(W1, w1t, CH, HC);
  tcast_k<<<(CH * HC + 255) / 256, 256, 0, stream>>>(W2, w2t, CH, HC);
  tcast_k<<<(CH * CH + 255) / 256, 256, 0, stream>>>(fc1w, fc1t, CH, CH);
  tcast_k<<<(CH * CH + 255) / 256, 256, 0, stream>>>(fc2w, fc2t, CH, CH);

  auto mgemm = [&](const float* A, const unsigned short* Bt, float* C,
                   int M, int N, int K) {
    dim3 grid((N + 63) / 64, (M + 127) / 128);
    hipLaunchKernelGGL(gemm_mfma, grid, dim3(256), 0, stream, A, Bt, C, M, N, K);
  };
  dim3 blk16(16, 16);
  auto fgemm = [&](const float* A, const float* B, float* C, int M, int N, int K,
                   const float* bias, int act) {
    dim3 grid((N + 63) / 64, (M + 63) / 64);
    hipLaunchKernelGGL(gemm_f32, grid, blk16, 0, stream, A, B, C, M, N, K, bias, act);
  };

  const int MSGB = (NNODES * 64 + 255) / 256;
  auto gat = [&](const float* X, int Din, const unsigned short* Wt,
                 const float* as_, const float* ad_, const float* bias, int act,
                 float* dst) {
    mgemm(X, Wt, h, NNODES, HC, Din);
    scores_k<<<MSGB, 256, 0, stream>>>(h, as_, ad_, ssrc, sdst);
    mz_k<<<(NNODES + 255) / 256, 256, 0, stream>>>(rowptr, esrc, ssrc, sdst, mval, zval);
    msgcsr_k<<<MSGB, 256, 0, stream>>>(rowptr, esrc, ssrc, sdst, mval, zval, h,
                                       bias, act, dst);
  };

  const int ELT = NNODES * CH;

  // ---- layer 0 ----
  gat(mol_x, 78, w0t, as0, ad0, b0, 1, hstate);

  // ---- layer 1 ----
  gat(hstate, CH, w1t, as1, ad1, b1, 1, xbuf);
  mgemm(xbuf,   fc1t, t1, NNODES, CH, CH);
  mgemm(hstate, fc2t, t2, NNODES, CH, CH);
  gate_k<<<(ELT + 255) / 256, 256, 0, stream>>>(t1, fc1b, t2, fc2b, mbias, xbuf, hstate);

  // ---- layer 2 ----
  gat(hstate, CH, w2t, as2, ad2, b2, 0, xbuf);
  mgemm(xbuf,   fc1t, t1, NNODES, CH, CH);
  mgemm(hstate, fc2t, t2, NNODES, CH, CH);
  gate_k<<<(ELT + 255) / 256, 256, 0, stream>>>(t1, fc1b, t2, fc2b, mbias, xbuf, hstate);

  // ---- pool + head ----
  hipMemsetAsync(psum, 0, (size_t)NGRAPH * CH * 4, stream);
  hipMemsetAsync(pcnt, 0, (size_t)NGRAPH * 4, stream);
  poolacc_k<<<(ELT + 255) / 256, 256, 0, stream>>>(hstate, batch, psum);
  poolcnt_k<<<(NNODES + 255) / 256, 256, 0, stream>>>(batch, pcnt);
  pooldiv_k<<<(NGRAPH * CH + 255) / 256, 256, 0, stream>>>(psum, pcnt, pooled);
  fgemm(pooled, g1w, gbuf, NGRAPH, 1024, CH, g1b, 1);
  fgemm(gbuf, g2w, out, NGRAPH, 128, 1024, g2b, 0);
}

// Round 3
// 1244.768 us; speedup vs baseline: 3.7949x; 3.5927x over previous
//
#include <hip/hip_runtime.h>
#include <cstdint>
#include <cstddef>

#define NNODES 50000
#define NEDGE0 400000
#define NETOT  450000
#define NGRAPH 1024
#define CH     312
#define HC     624
#define MP     50048     // NNODES padded to 128
#define KPA    320       // CH padded to 64 (activation row stride, shorts)
#define KP0    128       // 78 padded (layer-0 input)
#define NP_HC  640       // HC padded to 128 (weight rows)
#define NP_CH  384       // CH padded to 128

typedef __attribute__((ext_vector_type(4))) float f32x4;
typedef __attribute__((ext_vector_type(8))) short s16x8;
typedef unsigned short ushort_t;

__device__ __forceinline__ unsigned short f2bf(float x) {
  union { float f; unsigned u; } v; v.f = x;
  unsigned r = v.u + 0x7fffu + ((v.u >> 16) & 1u);   // RNE
  return (unsigned short)(r >> 16);
}
__device__ __forceinline__ float bf2f(unsigned short u) {
  union { unsigned u; float f; } v; v.u = ((unsigned)u) << 16;
  return v.f;
}
__device__ __forceinline__ void gl_lds16(const unsigned short* g, unsigned short* l) {
  __builtin_amdgcn_global_load_lds(
      (const __attribute__((address_space(1))) unsigned int*)g,
      (__attribute__((address_space(3))) unsigned int*)l, 16, 0, 0);
}

// ============ conversions ============
// mol_x f32 [NNODES][78] -> xb0 bf16 [MP][KP0], zero-padded
__global__ void cvt0_k(const float* __restrict__ in, unsigned short* __restrict__ out) {
  int i = blockIdx.x * blockDim.x + threadIdx.x;
  if (i >= MP * KP0) return;
  int n = i >> 7, c = i & 127;
  out[i] = (n < NNODES && c < 78) ? f2bf(in[(size_t)n * 78 + c]) : (unsigned short)0;
}

// weights: in f32 [K][N] -> out bf16 [NP_][KP_], transposed, zero-padded
__global__ void tcast_k(const float* __restrict__ in, unsigned short* __restrict__ out,
                        int K, int N, int KP_, int NP_) {
  int i = blockIdx.x * blockDim.x + threadIdx.x;
  if (i >= NP_ * KP_) return;
  int n = i / KP_, k = i - n * KP_;
  out[i] = (n < N && k < K) ? f2bf(in[(size_t)k * N + n]) : (unsigned short)0;
}

// ============ MFMA GEMM: C[M,N] = A[MP,KP_]bf16 @ Bt[NP,KP_]bf16 ============
// BM=128 BN=128 BK=64, 256 thr (4 waves 2x2), dbuf LDS, gload_lds + chunk-XOR swizzle.
__global__ __launch_bounds__(256) void gemm_bb(
    const unsigned short* __restrict__ A, const unsigned short* __restrict__ Bt,
    float* __restrict__ Cf, unsigned short* __restrict__ Cb,
    int M, int N, int KP_, int ldc)
{
  __shared__ unsigned short As[2][128 * 64];
  __shared__ unsigned short Bs[2][128 * 64];
  const int tid = threadIdx.x, lane = tid & 63, w = tid >> 6;
  const int bm = blockIdx.y * 128, bn = blockIdx.x * 128;
  const int rr = lane >> 3;                 // row within 8-row group
  const int cc8 = (lane & 7) ^ rr;          // pre-swizzled source chunk

  const int nkt = KP_ >> 6;
  int buf = 0;

  // stage k-tile kt into buffer b (A: 32 rows/wave, B: 32 rows/wave, 16B/lane)
  auto stage = [&](int b, int kt) {
    #pragma unroll
    for (int i = 0; i < 4; ++i) {
      int R = w * 32 + i * 8;
      const unsigned short* gA = A + (size_t)(bm + R + rr) * KP_ + kt * 64 + cc8 * 8;
      gl_lds16(gA, &As[b][R * 64]);
      const unsigned short* gB = Bt + (size_t)(bn + R + rr) * KP_ + kt * 64 + cc8 * 8;
      gl_lds16(gB, &Bs[b][R * 64]);
    }
  };

  const int wr = w >> 1, wc = w & 1;
  const int r16 = lane & 15, g4 = lane >> 4;
  f32x4 zf = {0.f, 0.f, 0.f, 0.f};
  f32x4 acc[4][4];
  #pragma unroll
  for (int m = 0; m < 4; ++m)
    #pragma unroll
    for (int n = 0; n < 4; ++n) acc[m][n] = zf;

  stage(0, 0);
  __syncthreads();
  for (int kt = 0; kt < nkt; ++kt) {
    if (kt + 1 < nkt) stage(buf ^ 1, kt + 1);
    #pragma unroll
    for (int k2 = 0; k2 < 2; ++k2) {
      s16x8 bfr[4], afr[4];
      #pragma unroll
      for (int n = 0; n < 4; ++n) {
        int rB = wc * 64 + n * 16 + r16;
        int ch = (k2 * 4 + g4) ^ (rB & 7);
        bfr[n] = *(const s16x8*)&Bs[buf][rB * 64 + ch * 8];
      }
      #pragma unroll
      for (int m = 0; m < 4; ++m) {
        int rA = wr * 64 + m * 16 + r16;
        int ch = (k2 * 4 + g4) ^ (rA & 7);
        afr[m] = *(const s16x8*)&As[buf][rA * 64 + ch * 8];
      }
      #pragma unroll
      for (int m = 0; m < 4; ++m)
        #pragma unroll
        for (int n = 0; n < 4; ++n)
          acc[m][n] = __builtin_amdgcn_mfma_f32_16x16x32_bf16(afr[m], bfr[n],
                                                              acc[m][n], 0, 0, 0);
    }
    __syncthreads();
    buf ^= 1;
  }

  #pragma unroll
  for (int m = 0; m < 4; ++m) {
    int gm0 = bm + wr * 64 + m * 16 + g4 * 4;
    #pragma unroll
    for (int n = 0; n < 4; ++n) {
      int gn = bn + wc * 64 + n * 16 + r16;
      if (gn >= N) continue;
      #pragma unroll
      for (int r = 0; r < 4; ++r) {
        int gm = gm0 + r;
        if (gm < M) {
          float v = acc[m][n][r];
          if (Cb) Cb[(size_t)gm * ldc + gn] = f2bf(v);
          else    Cf[(size_t)gm * ldc + gn] = v;
        }
      }
    }
  }
}

// ============ legacy f32 tiled GEMM (head layers only) ============
__global__ __launch_bounds__(256) void gemm_f32(
    const float* __restrict__ A, const float* __restrict__ B,
    float* __restrict__ C, int M, int N, int K,
    const float* __restrict__ bias, int act)
{
  __shared__ float As[16][65];
  __shared__ float Bs[16][65];
  int bm = blockIdx.y * 64, bn = blockIdx.x * 64;
  int tx = threadIdx.x, ty = threadIdx.y;
  int tid = ty * 16 + tx;
  float acc[4][4] = {};
  for (int k0 = 0; k0 < K; k0 += 16) {
    for (int i = tid; i < 64 * 16; i += 256) {
      int m = i >> 4, kk = i & 15;
      int gm = bm + m, gk = k0 + kk;
      As[kk][m] = (gm < M && gk < K) ? A[(size_t)gm * K + gk] : 0.f;
    }
    for (int i = tid; i < 16 * 64; i += 256) {
      int kk = i >> 6, n = i & 63;
      int gk = k0 + kk, gn = bn + n;
      Bs[kk][n] = (gk < K && gn < N) ? B[(size_t)gk * N + gn] : 0.f;
    }
    __syncthreads();
    #pragma unroll
    for (int kk = 0; kk < 16; ++kk) {
      float a[4], b[4];
      #pragma unroll
      for (int i = 0; i < 4; ++i) a[i] = As[kk][ty * 4 + i];
      #pragma unroll
      for (int j = 0; j < 4; ++j) b[j] = Bs[kk][tx * 4 + j];
      #pragma unroll
      for (int i = 0; i < 4; ++i)
        #pragma unroll
        for (int j = 0; j < 4; ++j)
          acc[i][j] += a[i] * b[j];
    }
    __syncthreads();
  }
  #pragma unroll
  for (int i = 0; i < 4; ++i) {
    int gm = bm + ty * 4 + i;
    if (gm >= M) continue;
    #pragma unroll
    for (int j = 0; j < 4; ++j) {
      int gn = bn + tx * 4 + j;
      if (gn >= N) continue;
      float v = acc[i][j];
      if (bias) v += bias[gn];
      if (act == 1) v = v > 0.f ? v : 0.f;
      C[(size_t)gm * N + gn] = v;
    }
  }
}

// ============ attention scores (h bf16) ============
__global__ __launch_bounds__(256) void scores_k(
    const unsigned short* __restrict__ h, const float* __restrict__ asrc,
    const float* __restrict__ adst, float* __restrict__ ssrc,
    float* __restrict__ sdst)
{
  int wave = (blockIdx.x * blockDim.x + threadIdx.x) >> 6;
  int lane = threadIdx.x & 63;
  if (wave >= NNODES) return;
  const unsigned short* hp = h + (size_t)wave * HC;
  float ss0 = 0, ss1 = 0, sd0 = 0, sd1 = 0;
  for (int c = lane; c < CH; c += 64) {
    float v0 = bf2f(hp[c]), v1 = bf2f(hp[CH + c]);
    ss0 += v0 * asrc[c];  ss1 += v1 * asrc[CH + c];
    sd0 += v0 * adst[c];  sd1 += v1 * adst[CH + c];
  }
  #pragma unroll
  for (int off = 32; off; off >>= 1) {
    ss0 += __shfl_xor(ss0, off);
    ss1 += __shfl_xor(ss1, off);
    sd0 += __shfl_xor(sd0, off);
    sd1 += __shfl_xor(sd1, off);
  }
  if (lane == 0) {
    ssrc[wave * 2] = ss0; ssrc[wave * 2 + 1] = ss1;
    sdst[wave * 2] = sd0; sdst[wave * 2 + 1] = sd1;
  }
}

// ============ CSR build ============
__global__ void hist_k(const int* __restrict__ ei, int* __restrict__ cnt) {
  int e = blockIdx.x * blockDim.x + threadIdx.x;
  if (e >= NETOT) return;
  int d = (e < NEDGE0) ? ei[NEDGE0 + e] : e - NEDGE0;
  atomicAdd(&cnt[d], 1);
}

__global__ __launch_bounds__(1024) void scan_k(const int* __restrict__ cnt,
                                               int* __restrict__ rowptr) {
  __shared__ int wsum[16];
  __shared__ int carry_s;
  int t = threadIdx.x, lane = t & 63, wv = t >> 6;
  if (t == 0) carry_s = 0;
  __syncthreads();
  for (int base = 0; base < NNODES; base += 1024) {
    int idx = base + t;
    int v = (idx < NNODES) ? cnt[idx] : 0;
    int s = v;
    #pragma unroll
    for (int off = 1; off < 64; off <<= 1) {
      int x = __shfl_up(s, off);
      if (lane >= off) s += x;
    }
    if (lane == 63) wsum[wv] = s;
    __syncthreads();
    if (wv == 0) {
      int ws = (lane < 16) ? wsum[lane] : 0;
      #pragma unroll
      for (int off = 1; off < 16; off <<= 1) {
        int x = __shfl_up(ws, off);
        if (lane >= off) ws += x;
      }
      if (lane < 16) wsum[lane] = ws;
    }
    __syncthreads();
    int carry = carry_s;
    int woff = wv ? wsum[wv - 1] : 0;
    if (idx < NNODES) rowptr[idx] = carry + woff + s - v;
    __syncthreads();
    if (t == 1023) carry_s = carry + wsum[15];
    __syncthreads();
  }
  if (t == 0) rowptr[NNODES] = carry_s;
}

__global__ void scatter_k(const int* __restrict__ ei, const int* __restrict__ rowptr,
                          int* __restrict__ cur, int* __restrict__ esrc) {
  int e = blockIdx.x * blockDim.x + threadIdx.x;
  if (e >= NETOT) return;
  int s, d;
  if (e < NEDGE0) { s = ei[e]; d = ei[NEDGE0 + e]; }
  else { s = d = e - NEDGE0; }
  int pos = rowptr[d] + atomicAdd(&cur[d], 1);
  esrc[pos] = s;
}

// ============ per-dst online softmax max/sum ============
__global__ void mz_k(const int* __restrict__ rowptr, const int* __restrict__ esrc,
                     const float* __restrict__ ssrc, const float* __restrict__ sdst,
                     float* __restrict__ mval, float* __restrict__ zval) {
  int n = blockIdx.x * blockDim.x + threadIdx.x;
  if (n >= NNODES) return;
  int e0 = rowptr[n], e1 = rowptr[n + 1];
  float sd0 = sdst[2 * n], sd1 = sdst[2 * n + 1];
  float m0 = -1e30f, m1 = -1e30f, z0 = 0.f, z1 = 0.f;
  for (int e = e0; e < e1; ++e) {
    int s = esrc[e];
    float a0 = ssrc[2 * s] + sd0;     a0 = a0 > 0.f ? a0 : 0.2f * a0;
    float a1 = ssrc[2 * s + 1] + sd1; a1 = a1 > 0.f ? a1 : 0.2f * a1;
    float nm0 = fmaxf(m0, a0);
    z0 = z0 * __expf(m0 - nm0) + __expf(a0 - nm0); m0 = nm0;
    float nm1 = fmaxf(m1, a1);
    z1 = z1 * __expf(m1 - nm1) + __expf(a1 - nm1); m1 = nm1;
  }
  mval[2 * n] = m0; mval[2 * n + 1] = m1;
  zval[2 * n] = z0; zval[2 * n + 1] = z1;
}

// ============ per-dst gather-accumulate + bias + act -> bf16 [MP][KPA] ============
__global__ __launch_bounds__(256) void msgcsr_k(
    const int* __restrict__ rowptr, const int* __restrict__ esrc,
    const float* __restrict__ ssrc, const float* __restrict__ sdst,
    const float* __restrict__ mval, const float* __restrict__ zval,
    const unsigned short* __restrict__ h, const float* __restrict__ bias, int act,
    unsigned short* __restrict__ out)
{
  int wave = (blockIdx.x * blockDim.x + threadIdx.x) >> 6;
  int lane = threadIdx.x & 63;
  if (wave >= NNODES) return;
  int e0 = rowptr[wave], e1 = rowptr[wave + 1];
  float sd0 = sdst[2 * wave], sd1 = sdst[2 * wave + 1];
  float m0 = mval[2 * wave], m1 = mval[2 * wave + 1];
  float i0 = 0.5f / (zval[2 * wave] + 1e-16f);
  float i1 = 0.5f / (zval[2 * wave + 1] + 1e-16f);
  float acc[5] = {0, 0, 0, 0, 0};
  for (int e = e0; e < e1; ++e) {
    int s = esrc[e];
    float a0 = ssrc[2 * s] + sd0;     a0 = a0 > 0.f ? a0 : 0.2f * a0;
    float a1 = ssrc[2 * s + 1] + sd1; a1 = a1 > 0.f ? a1 : 0.2f * a1;
    float c0 = __expf(a0 - m0) * i0;
    float c1 = __expf(a1 - m1) * i1;
    const unsigned short* hp = h + (size_t)s * HC;
    #pragma unroll
    for (int i = 0; i < 5; ++i) {
      int c = lane + (i << 6);
      if (c < CH) acc[i] += c0 * bf2f(hp[c]) + c1 * bf2f(hp[CH + c]);
    }
  }
  unsigned short* op = out + (size_t)wave * KPA;
  #pragma unroll
  for (int i = 0; i < 5; ++i) {
    int c = lane + (i << 6);
    float v = 0.f;
    if (c < CH) {
      v = acc[i] + bias[c];
      if (act) v = v > 0.f ? v : 0.f;
    }
    op[c] = f2bf(v);
  }
}

// ============ gated residual: hstate = sig(t1+b1+t2+b2+mb)*x + (1-..)*hstate ============
__global__ void gate_k(const float* __restrict__ t1, const float* __restrict__ fc1b,
                       const float* __restrict__ t2, const float* __restrict__ fc2b,
                       const float* __restrict__ mbias, const unsigned short* __restrict__ x,
                       unsigned short* __restrict__ hstate)
{
  int i = blockIdx.x * blockDim.x + threadIdx.x;
  if (i >= NNODES * KPA) return;
  int n = i / KPA, c = i - n * KPA;
  if (c >= CH) { hstate[i] = 0; return; }
  size_t tix = (size_t)n * CH + c;
  float g = t1[tix] + fc1b[c] + t2[tix] + fc2b[c] + mbias[c];
  g = 1.f / (1.f + __expf(-g));
  float xv = bf2f(x[i]), hv = bf2f(hstate[i]);
  hstate[i] = f2bf(g * xv + (1.f - g) * hv);
}

// ============ pooling ============
__global__ void poolacc_k(const unsigned short* __restrict__ hstate,
                          const int* __restrict__ batch, float* __restrict__ psum)
{
  int i = blockIdx.x * blockDim.x + threadIdx.x;
  if (i >= NNODES * CH) return;
  int n = i / CH, c = i - n * CH;
  atomicAdd(&psum[(size_t)batch[n] * CH + c], bf2f(hstate[(size_t)n * KPA + c]));
}

__global__ void poolcnt_k(const int* __restrict__ batch, float* __restrict__ pcnt)
{
  int n = blockIdx.x * blockDim.x + threadIdx.x;
  if (n >= NNODES) return;
  atomicAdd(&pcnt[batch[n]], 1.f);
}

__global__ void pooldiv_k(const float* __restrict__ psum, const float* __restrict__ pcnt,
                          float* __restrict__ pooled)
{
  int i = blockIdx.x * blockDim.x + threadIdx.x;
  if (i >= NGRAPH * CH) return;
  int g = i / CH;
  float c = pcnt[g];
  c = c > 1.f ? c : 1.f;
  pooled[i] = psum[i] / c;
}

extern "C" void kernel_launch(void* const* d_in, const int* in_sizes, int n_in,
                              void* d_out, int out_size, void* d_ws, size_t ws_size,
                              hipStream_t stream)
{
  const float* mol_x = (const float*)d_in[0];
  const int*   ei    = (const int*)d_in[1];
  const int*   batch = (const int*)d_in[2];
  const float* W0  = (const float*)d_in[3];
  const float* as0 = (const float*)d_in[4];
  const float* ad0 = (const float*)d_in[5];
  const float* b0  = (const float*)d_in[6];
  const float* W1  = (const float*)d_in[7];
  const float* as1 = (const float*)d_in[8];
  const float* ad1 = (const float*)d_in[9];
  const float* b1  = (const float*)d_in[10];
  const float* W2  = (const float*)d_in[11];
  const float* as2 = (const float*)d_in[12];
  const float* ad2 = (const float*)d_in[13];
  const float* b2  = (const float*)d_in[14];
  const float* fc1w = (const float*)d_in[15];
  const float* fc1b = (const float*)d_in[16];
  const float* fc2w = (const float*)d_in[17];
  const float* fc2b = (const float*)d_in[18];
  const float* mbias = (const float*)d_in[19];
  const float* g1w = (const float*)d_in[20];
  const float* g1b = (const float*)d_in[21];
  const float* g2w = (const float*)d_in[22];
  const float* g2b = (const float*)d_in[23];
  float* out = (float*)d_out;

  char* ws = (char*)d_ws;
  size_t off = 0;
  auto alloc = [&](size_t b) { size_t r = off; off += (b + 255) & ~(size_t)255; return r; };
  // h (bf16, layer output) overlaps t1/t2 (f32, fc outputs) — disjoint lifetimes
  char*  hreg   = ws + alloc((size_t)NNODES * CH * 4 * 2);          // 124.8 MB
  unsigned short* h_b = (unsigned short*)hreg;                      // [NNODES][HC] bf16
  float* t1 = (float*)hreg;                                         // [NNODES][CH] f32
  float* t2 = t1 + (size_t)NNODES * CH;
  unsigned short* xb0     = (unsigned short*)(ws + alloc((size_t)MP * KP0 * 2));
  unsigned short* hstate_b= (unsigned short*)(ws + alloc((size_t)MP * KPA * 2));
  unsigned short* xbuf_b  = (unsigned short*)(ws + alloc((size_t)MP * KPA * 2));
  float* ssrc   = (float*)(ws + alloc((size_t)NNODES * 2 * 4));
  float* sdst   = (float*)(ws + alloc((size_t)NNODES * 2 * 4));
  float* mval   = (float*)(ws + alloc((size_t)NNODES * 2 * 4));
  float* zval   = (float*)(ws + alloc((size_t)NNODES * 2 * 4));
  int*   cnt    = (int*)(ws + alloc((size_t)NNODES * 4));
  int*   cnt2   = (int*)(ws + alloc((size_t)NNODES * 4));
  int*   rowptr = (int*)(ws + alloc((size_t)(NNODES + 1) * 4));
  int*   esrc   = (int*)(ws + alloc((size_t)NETOT * 4));
  float* psum   = (float*)(ws + alloc((size_t)NGRAPH * CH * 4));
  float* pcnt   = (float*)(ws + alloc((size_t)NGRAPH * 4));
  float* pooled = (float*)(ws + alloc((size_t)NGRAPH * CH * 4));
  float* gbuf   = (float*)(ws + alloc((size_t)NGRAPH * 1024 * 4));
  unsigned short* w0t  = (unsigned short*)(ws + alloc((size_t)NP_HC * KP0 * 2));
  unsigned short* w1t  = (unsigned short*)(ws + alloc((size_t)NP_HC * KPA * 2));
  unsigned short* w2t  = (unsigned short*)(ws + alloc((size_t)NP_HC * KPA * 2));
  unsigned short* fc1t = (unsigned short*)(ws + alloc((size_t)NP_CH * KPA * 2));
  unsigned short* fc2t = (unsigned short*)(ws + alloc((size_t)NP_CH * KPA * 2));

  // ---- pre-pass: CSR build + conversions ----
  hipMemsetAsync(cnt, 0, (size_t)NNODES * 4, stream);
  hipMemsetAsync(cnt2, 0, (size_t)NNODES * 4, stream);
  hist_k<<<(NETOT + 255) / 256, 256, 0, stream>>>(ei, cnt);
  scan_k<<<1, 1024, 0, stream>>>(cnt, rowptr);
  scatter_k<<<(NETOT + 255) / 256, 256, 0, stream>>>(ei, rowptr, cnt2, esrc);
  cvt0_k<<<(MP * KP0 + 255) / 256, 256, 0, stream>>>(mol_x, xb0);
  tcast_k<<<(NP_HC * KP0 + 255) / 256, 256, 0, stream>>>(W0, w0t, 78, HC, KP0, NP_HC);
  tcast_k<<<(NP_HC * KPA + 255) / 256, 256, 0, stream>>>(W1, w1t, CH, HC, KPA, NP_HC);
  tcast_k<<<(NP_HC * KPA + 255) / 256, 256, 0, stream>>>(W2, w2t, CH, HC, KPA, NP_HC);
  tcast_k<<<(NP_CH * KPA + 255) / 256, 256, 0, stream>>>(fc1w, fc1t, CH, CH, KPA, NP_CH);
  tcast_k<<<(NP_CH * KPA + 255) / 256, 256, 0, stream>>>(fc2w, fc2t, CH, CH, KPA, NP_CH);

  auto mgemm = [&](const unsigned short* A, const unsigned short* Bt,
                   float* Cf, unsigned short* Cb, int M, int N, int KP_, int ldc) {
    dim3 grid((N + 127) / 128, (M + 127) / 128);
    hipLaunchKernelGGL(gemm_bb, grid, dim3(256), 0, stream, A, Bt, Cf, Cb, M, N, KP_, ldc);
  };
  dim3 blk16(16, 16);
  auto fgemm = [&](const float* A, const float* B, float* C, int M, int N, int K,
                   const float* bias, int act) {
    dim3 grid((N + 63) / 64, (M + 63) / 64);
    hipLaunchKernelGGL(gemm_f32, grid, blk16, 0, stream, A, B, C, M, N, K, bias, act);
  };

  const int MSGB = (NNODES * 64 + 255) / 256;
  auto gat = [&](const unsigned short* X, int KP_, const unsigned short* Wt,
                 const float* as_, const float* ad_, const float* bias, int act,
                 unsigned short* dst) {
    mgemm(X, Wt, nullptr, h_b, NNODES, HC, KP_, HC);
    scores_k<<<MSGB, 256, 0, stream>>>(h_b, as_, ad_, ssrc, sdst);
    mz_k<<<(NNODES + 255) / 256, 256, 0, stream>>>(rowptr, esrc, ssrc, sdst, mval, zval);
    msgcsr_k<<<MSGB, 256, 0, stream>>>(rowptr, esrc, ssrc, sdst, mval, zval, h_b,
                                       bias, act, dst);
  };

  const int GELT = (NNODES * KPA + 255) / 256;

  // ---- layer 0 ----
  gat(xb0, KP0, w0t, as0, ad0, b0, 1, hstate_b);

  // ---- layer 1 ----
  gat(hstate_b, KPA, w1t, as1, ad1, b1, 1, xbuf_b);
  mgemm(xbuf_b,   fc1t, t1, nullptr, NNODES, CH, KPA, CH);
  mgemm(hstate_b, fc2t, t2, nullptr, NNODES, CH, KPA, CH);
  gate_k<<<GELT, 256, 0, stream>>>(t1, fc1b, t2, fc2b, mbias, xbuf_b, hstate_b);

  // ---- layer 2 ----
  gat(hstate_b, KPA, w2t, as2, ad2, b2, 0, xbuf_b);
  mgemm(xbuf_b,   fc1t, t1, nullptr, NNODES, CH, KPA, CH);
  mgemm(hstate_b, fc2t, t2, nullptr, NNODES, CH, KPA, CH);
  gate_k<<<GELT, 256, 0, stream>>>(t1, fc1b, t2, fc2b, mbias, xbuf_b, hstate_b);

  // ---- pool + head ----
  hipMemsetAsync(psum, 0, (size_t)NGRAPH * CH * 4, stream);
  hipMemsetAsync(pcnt, 0, (size_t)NGRAPH * 4, stream);
  poolacc_k<<<(NNODES * CH + 255) / 256, 256, 0, stream>>>(hstate_b, batch, psum);
  poolcnt_k<<<(NNODES + 255) / 256, 256, 0, stream>>>(batch, pcnt);
  pooldiv_k<<<(NGRAPH * CH + 255) / 256, 256, 0, stream>>>(psum, pcnt, pooled);
  fgemm(pooled, g1w, gbuf, NGRAPH, 1024, CH, g1b, 1);
  fgemm(gbuf, g2w, out, NGRAPH, 128, 1024, g2b, 0);
}

// Round 4
// 1189.790 us; speedup vs baseline: 3.9703x; 1.0462x over previous
//
#include <hip/hip_runtime.h>
#include <cstdint>
#include <cstddef>

#define NNODES 50000
#define NEDGE0 400000
#define NETOT  450000
#define NGRAPH 1024
#define CH     312
#define HC     624
#define MP     50048     // NNODES padded to 128
#define KPA    320       // CH padded to 64 (activation row stride, shorts)
#define KP0    128       // 78 padded (layer-0 input)
#define NP_HC  640       // HC padded to 128 (weight rows)
#define NP_CH  384       // CH padded to 128
#define GW1    1024      // head fc1 width

typedef __attribute__((ext_vector_type(4))) float f32x4;
typedef __attribute__((ext_vector_type(8))) short s16x8;

__device__ __forceinline__ unsigned short f2bf(float x) {
  union { float f; unsigned u; } v; v.f = x;
  unsigned r = v.u + 0x7fffu + ((v.u >> 16) & 1u);   // RNE
  return (unsigned short)(r >> 16);
}
__device__ __forceinline__ float bf2f(unsigned short u) {
  union { unsigned u; float f; } v; v.u = ((unsigned)u) << 16;
  return v.f;
}
__device__ __forceinline__ void gl_lds16(const unsigned short* g, unsigned short* l) {
  __builtin_amdgcn_global_load_lds(
      (const __attribute__((address_space(1))) unsigned int*)g,
      (__attribute__((address_space(3))) unsigned int*)l, 16, 0, 0);
}

// ============ conversions ============
__global__ void cvt0_k(const float* __restrict__ in, unsigned short* __restrict__ out) {
  int i = blockIdx.x * blockDim.x + threadIdx.x;
  if (i >= MP * KP0) return;
  int n = i >> 7, c = i & 127;
  out[i] = (n < NNODES && c < 78) ? f2bf(in[(size_t)n * 78 + c]) : (unsigned short)0;
}

// weights: in f32 [K][N] -> out bf16 [NP_][KP_], transposed, zero-padded
__global__ void tcast_k(const float* __restrict__ in, unsigned short* __restrict__ out,
                        int K, int N, int KP_, int NP_) {
  int i = blockIdx.x * blockDim.x + threadIdx.x;
  if (i >= NP_ * KP_) return;
  int n = i / KP_, k = i - n * KP_;
  out[i] = (n < N && k < K) ? f2bf(in[(size_t)k * N + n]) : (unsigned short)0;
}

// ============ MFMA GEMM: C[M,N] = A[MP,KP_]bf16 @ Bt[NP,KP_]bf16 (+bias,+relu) ====
// BM=128 BN=128 BK=64, 256 thr (4 waves 2x2), dbuf LDS, gload_lds + chunk-XOR swizzle.
__global__ __launch_bounds__(256) void gemm_bb(
    const unsigned short* __restrict__ A, const unsigned short* __restrict__ Bt,
    float* __restrict__ Cf, unsigned short* __restrict__ Cb,
    int M, int N, int KP_, int ldc, const float* __restrict__ bias, int act)
{
  __shared__ unsigned short As[2][128 * 64];
  __shared__ unsigned short Bs[2][128 * 64];
  const int tid = threadIdx.x, lane = tid & 63, w = tid >> 6;
  const int bm = blockIdx.y * 128, bn = blockIdx.x * 128;
  const int rr = lane >> 3;                 // row within 8-row group
  const int cc8 = (lane & 7) ^ rr;          // pre-swizzled source chunk

  const int nkt = KP_ >> 6;
  int buf = 0;

  auto stage = [&](int b, int kt) {
    #pragma unroll
    for (int i = 0; i < 4; ++i) {
      int R = w * 32 + i * 8;
      const unsigned short* gA = A + (size_t)(bm + R + rr) * KP_ + kt * 64 + cc8 * 8;
      gl_lds16(gA, &As[b][R * 64]);
      const unsigned short* gB = Bt + (size_t)(bn + R + rr) * KP_ + kt * 64 + cc8 * 8;
      gl_lds16(gB, &Bs[b][R * 64]);
    }
  };

  const int wr = w >> 1, wc = w & 1;
  const int r16 = lane & 15, g4 = lane >> 4;
  f32x4 zf = {0.f, 0.f, 0.f, 0.f};
  f32x4 acc[4][4];
  #pragma unroll
  for (int m = 0; m < 4; ++m)
    #pragma unroll
    for (int n = 0; n < 4; ++n) acc[m][n] = zf;

  stage(0, 0);
  __syncthreads();
  for (int kt = 0; kt < nkt; ++kt) {
    if (kt + 1 < nkt) stage(buf ^ 1, kt + 1);
    #pragma unroll
    for (int k2 = 0; k2 < 2; ++k2) {
      s16x8 bfr[4], afr[4];
      #pragma unroll
      for (int n = 0; n < 4; ++n) {
        int rB = wc * 64 + n * 16 + r16;
        int ch = (k2 * 4 + g4) ^ (rB & 7);
        bfr[n] = *(const s16x8*)&Bs[buf][rB * 64 + ch * 8];
      }
      #pragma unroll
      for (int m = 0; m < 4; ++m) {
        int rA = wr * 64 + m * 16 + r16;
        int ch = (k2 * 4 + g4) ^ (rA & 7);
        afr[m] = *(const s16x8*)&As[buf][rA * 64 + ch * 8];
      }
      #pragma unroll
      for (int m = 0; m < 4; ++m)
        #pragma unroll
        for (int n = 0; n < 4; ++n)
          acc[m][n] = __builtin_amdgcn_mfma_f32_16x16x32_bf16(afr[m], bfr[n],
                                                              acc[m][n], 0, 0, 0);
    }
    __syncthreads();
    buf ^= 1;
  }

  #pragma unroll
  for (int m = 0; m < 4; ++m) {
    int gm0 = bm + wr * 64 + m * 16 + g4 * 4;
    #pragma unroll
    for (int n = 0; n < 4; ++n) {
      int gn = bn + wc * 64 + n * 16 + r16;
      if (gn >= N) continue;
      float bv = bias ? bias[gn] : 0.f;
      #pragma unroll
      for (int r = 0; r < 4; ++r) {
        int gm = gm0 + r;
        if (gm < M) {
          float v = acc[m][n][r] + bv;
          if (act) v = v > 0.f ? v : 0.f;
          if (Cb) Cb[(size_t)gm * ldc + gn] = f2bf(v);
          else    Cf[(size_t)gm * ldc + gn] = v;
        }
      }
    }
  }
}

// ============ attention scores (h bf16) ============
__global__ __launch_bounds__(256) void scores_k(
    const unsigned short* __restrict__ h, const float* __restrict__ asrc,
    const float* __restrict__ adst, float* __restrict__ ssrc,
    float* __restrict__ sdst)
{
  int wave = (blockIdx.x * blockDim.x + threadIdx.x) >> 6;
  int lane = threadIdx.x & 63;
  if (wave >= NNODES) return;
  const unsigned short* hp = h + (size_t)wave * HC;
  float ss0 = 0, ss1 = 0, sd0 = 0, sd1 = 0;
  for (int c = lane; c < CH; c += 64) {
    float v0 = bf2f(hp[c]), v1 = bf2f(hp[CH + c]);
    ss0 += v0 * asrc[c];  ss1 += v1 * asrc[CH + c];
    sd0 += v0 * adst[c];  sd1 += v1 * adst[CH + c];
  }
  #pragma unroll
  for (int off = 32; off; off >>= 1) {
    ss0 += __shfl_xor(ss0, off);
    ss1 += __shfl_xor(ss1, off);
    sd0 += __shfl_xor(sd0, off);
    sd1 += __shfl_xor(sd1, off);
  }
  if (lane == 0) {
    ssrc[wave * 2] = ss0; ssrc[wave * 2 + 1] = ss1;
    sdst[wave * 2] = sd0; sdst[wave * 2 + 1] = sd1;
  }
}

// ============ CSR build ============
__global__ void hist_k(const int* __restrict__ ei, int* __restrict__ cnt) {
  int e = blockIdx.x * blockDim.x + threadIdx.x;
  if (e >= NETOT) return;
  int d = (e < NEDGE0) ? ei[NEDGE0 + e] : e - NEDGE0;
  atomicAdd(&cnt[d], 1);
}

__global__ __launch_bounds__(1024) void scan_k(const int* __restrict__ cnt,
                                               int* __restrict__ rowptr) {
  __shared__ int wsum[16];
  __shared__ int carry_s;
  int t = threadIdx.x, lane = t & 63, wv = t >> 6;
  if (t == 0) carry_s = 0;
  __syncthreads();
  for (int base = 0; base < NNODES; base += 1024) {
    int idx = base + t;
    int v = (idx < NNODES) ? cnt[idx] : 0;
    int s = v;
    #pragma unroll
    for (int off = 1; off < 64; off <<= 1) {
      int x = __shfl_up(s, off);
      if (lane >= off) s += x;
    }
    if (lane == 63) wsum[wv] = s;
    __syncthreads();
    if (wv == 0) {
      int ws = (lane < 16) ? wsum[lane] : 0;
      #pragma unroll
      for (int off = 1; off < 16; off <<= 1) {
        int x = __shfl_up(ws, off);
        if (lane >= off) ws += x;
      }
      if (lane < 16) wsum[lane] = ws;
    }
    __syncthreads();
    int carry = carry_s;
    int woff = wv ? wsum[wv - 1] : 0;
    if (idx < NNODES) rowptr[idx] = carry + woff + s - v;
    __syncthreads();
    if (t == 1023) carry_s = carry + wsum[15];
    __syncthreads();
  }
  if (t == 0) rowptr[NNODES] = carry_s;
}

__global__ void scatter_k(const int* __restrict__ ei, const int* __restrict__ rowptr,
                          int* __restrict__ cur, int* __restrict__ esrc) {
  int e = blockIdx.x * blockDim.x + threadIdx.x;
  if (e >= NETOT) return;
  int s, d;
  if (e < NEDGE0) { s = ei[e]; d = ei[NEDGE0 + e]; }
  else { s = d = e - NEDGE0; }
  int pos = rowptr[d] + atomicAdd(&cur[d], 1);
  esrc[pos] = s;
}

// ============ per-dst online softmax max/sum ============
__global__ void mz_k(const int* __restrict__ rowptr, const int* __restrict__ esrc,
                     const float* __restrict__ ssrc, const float* __restrict__ sdst,
                     float* __restrict__ mval, float* __restrict__ zval) {
  int n = blockIdx.x * blockDim.x + threadIdx.x;
  if (n >= NNODES) return;
  int e0 = rowptr[n], e1 = rowptr[n + 1];
  float sd0 = sdst[2 * n], sd1 = sdst[2 * n + 1];
  float m0 = -1e30f, m1 = -1e30f, z0 = 0.f, z1 = 0.f;
  for (int e = e0; e < e1; ++e) {
    int s = esrc[e];
    float a0 = ssrc[2 * s] + sd0;     a0 = a0 > 0.f ? a0 : 0.2f * a0;
    float a1 = ssrc[2 * s + 1] + sd1; a1 = a1 > 0.f ? a1 : 0.2f * a1;
    float nm0 = fmaxf(m0, a0);
    z0 = z0 * __expf(m0 - nm0) + __expf(a0 - nm0); m0 = nm0;
    float nm1 = fmaxf(m1, a1);
    z1 = z1 * __expf(m1 - nm1) + __expf(a1 - nm1); m1 = nm1;
  }
  mval[2 * n] = m0; mval[2 * n + 1] = m1;
  zval[2 * n] = z0; zval[2 * n + 1] = z1;
}

// ============ per-dst gather-accumulate + bias + act -> bf16 [MP][KPA] ============
__global__ __launch_bounds__(256) void msgcsr_k(
    const int* __restrict__ rowptr, const int* __restrict__ esrc,
    const float* __restrict__ ssrc, const float* __restrict__ sdst,
    const float* __restrict__ mval, const float* __restrict__ zval,
    const unsigned short* __restrict__ h, const float* __restrict__ bias, int act,
    unsigned short* __restrict__ out)
{
  int wave = (blockIdx.x * blockDim.x + threadIdx.x) >> 6;
  int lane = threadIdx.x & 63;
  if (wave >= NNODES) return;
  int e0 = rowptr[wave], e1 = rowptr[wave + 1];
  float sd0 = sdst[2 * wave], sd1 = sdst[2 * wave + 1];
  float m0 = mval[2 * wave], m1 = mval[2 * wave + 1];
  float i0 = 0.5f / (zval[2 * wave] + 1e-16f);
  float i1 = 0.5f / (zval[2 * wave + 1] + 1e-16f);
  float acc[5] = {0, 0, 0, 0, 0};
  for (int e = e0; e < e1; ++e) {
    int s = esrc[e];
    float a0 = ssrc[2 * s] + sd0;     a0 = a0 > 0.f ? a0 : 0.2f * a0;
    float a1 = ssrc[2 * s + 1] + sd1; a1 = a1 > 0.f ? a1 : 0.2f * a1;
    float c0 = __expf(a0 - m0) * i0;
    float c1 = __expf(a1 - m1) * i1;
    const unsigned short* hp = h + (size_t)s * HC;
    #pragma unroll
    for (int i = 0; i < 5; ++i) {
      int c = lane + (i << 6);
      if (c < CH) acc[i] += c0 * bf2f(hp[c]) + c1 * bf2f(hp[CH + c]);
    }
  }
  unsigned short* op = out + (size_t)wave * KPA;
  #pragma unroll
  for (int i = 0; i < 5; ++i) {
    int c = lane + (i << 6);
    float v = 0.f;
    if (c < CH) {
      v = acc[i] + bias[c];
      if (act) v = v > 0.f ? v : 0.f;
    }
    op[c] = f2bf(v);
  }
}

// ============ gated residual ============
__global__ void gate_k(const float* __restrict__ t1, const float* __restrict__ fc1b,
                       const float* __restrict__ t2, const float* __restrict__ fc2b,
                       const float* __restrict__ mbias, const unsigned short* __restrict__ x,
                       unsigned short* __restrict__ hstate)
{
  int i = blockIdx.x * blockDim.x + threadIdx.x;
  if (i >= NNODES * KPA) return;
  int n = i / KPA, c = i - n * KPA;
  if (c >= CH) { hstate[i] = 0; return; }
  size_t tix = (size_t)n * CH + c;
  float g = t1[tix] + fc1b[c] + t2[tix] + fc2b[c] + mbias[c];
  g = 1.f / (1.f + __expf(-g));
  float xv = bf2f(x[i]), hv = bf2f(hstate[i]);
  hstate[i] = f2bf(g * xv + (1.f - g) * hv);
}

// ============ pooling ============
__global__ void poolacc_k(const unsigned short* __restrict__ hstate,
                          const int* __restrict__ batch, float* __restrict__ psum)
{
  int i = blockIdx.x * blockDim.x + threadIdx.x;
  if (i >= NNODES * CH) return;
  int n = i / CH, c = i - n * CH;
  atomicAdd(&psum[(size_t)batch[n] * CH + c], bf2f(hstate[(size_t)n * KPA + c]));
}

__global__ void poolcnt_k(const int* __restrict__ batch, float* __restrict__ pcnt)
{
  int n = blockIdx.x * blockDim.x + threadIdx.x;
  if (n >= NNODES) return;
  atomicAdd(&pcnt[batch[n]], 1.f);
}

// psum/pcnt -> pooled bf16 [NGRAPH][KPA], zero-padded
__global__ void pooldiv_k(const float* __restrict__ psum, const float* __restrict__ pcnt,
                          unsigned short* __restrict__ pooled_b)
{
  int i = blockIdx.x * blockDim.x + threadIdx.x;
  if (i >= NGRAPH * KPA) return;
  int g = i / KPA, c = i - g * KPA;
  float v = 0.f;
  if (c < CH) {
    float n = pcnt[g];
    n = n > 1.f ? n : 1.f;
    v = psum[(size_t)g * CH + c] / n;
  }
  pooled_b[i] = f2bf(v);
}

extern "C" void kernel_launch(void* const* d_in, const int* in_sizes, int n_in,
                              void* d_out, int out_size, void* d_ws, size_t ws_size,
                              hipStream_t stream)
{
  const float* mol_x = (const float*)d_in[0];
  const int*   ei    = (const int*)d_in[1];
  const int*   batch = (const int*)d_in[2];
  const float* W0  = (const float*)d_in[3];
  const float* as0 = (const float*)d_in[4];
  const float* ad0 = (const float*)d_in[5];
  const float* b0  = (const float*)d_in[6];
  const float* W1  = (const float*)d_in[7];
  const float* as1 = (const float*)d_in[8];
  const float* ad1 = (const float*)d_in[9];
  const float* b1  = (const float*)d_in[10];
  const float* W2  = (const float*)d_in[11];
  const float* as2 = (const float*)d_in[12];
  const float* ad2 = (const float*)d_in[13];
  const float* b2  = (const float*)d_in[14];
  const float* fc1w = (const float*)d_in[15];
  const float* fc1b = (const float*)d_in[16];
  const float* fc2w = (const float*)d_in[17];
  const float* fc2b = (const float*)d_in[18];
  const float* mbias = (const float*)d_in[19];
  const float* g1w = (const float*)d_in[20];
  const float* g1b = (const float*)d_in[21];
  const float* g2w = (const float*)d_in[22];
  const float* g2b = (const float*)d_in[23];
  float* out = (float*)d_out;

  char* ws = (char*)d_ws;
  size_t off = 0;
  auto alloc = [&](size_t b) { size_t r = off; off += (b + 255) & ~(size_t)255; return r; };
  // h (bf16, layer output) overlaps t1/t2 (f32, fc outputs) — disjoint lifetimes
  char*  hreg   = ws + alloc((size_t)NNODES * CH * 4 * 2);          // 124.8 MB
  unsigned short* h_b = (unsigned short*)hreg;                      // [NNODES][HC] bf16
  float* t1 = (float*)hreg;                                         // [NNODES][CH] f32
  float* t2 = t1 + (size_t)NNODES * CH;
  unsigned short* xb0      = (unsigned short*)(ws + alloc((size_t)MP * KP0 * 2));
  unsigned short* hstate_b = (unsigned short*)(ws + alloc((size_t)MP * KPA * 2));
  unsigned short* xbuf_b   = (unsigned short*)(ws + alloc((size_t)MP * KPA * 2));
  float* ssrc   = (float*)(ws + alloc((size_t)NNODES * 2 * 4));
  float* sdst   = (float*)(ws + alloc((size_t)NNODES * 2 * 4));
  float* mval   = (float*)(ws + alloc((size_t)NNODES * 2 * 4));
  float* zval   = (float*)(ws + alloc((size_t)NNODES * 2 * 4));
  int*   cnt    = (int*)(ws + alloc((size_t)NNODES * 4));
  int*   cnt2   = (int*)(ws + alloc((size_t)NNODES * 4));
  int*   rowptr = (int*)(ws + alloc((size_t)(NNODES + 1) * 4));
  int*   esrc   = (int*)(ws + alloc((size_t)NETOT * 4));
  float* psum   = (float*)(ws + alloc((size_t)NGRAPH * CH * 4));
  float* pcnt   = (float*)(ws + alloc((size_t)NGRAPH * 4));
  unsigned short* pooled_b = (unsigned short*)(ws + alloc((size_t)NGRAPH * KPA * 2));
  unsigned short* gbuf_b   = (unsigned short*)(ws + alloc((size_t)NGRAPH * GW1 * 2));
  unsigned short* w0t  = (unsigned short*)(ws + alloc((size_t)NP_HC * KP0 * 2));
  unsigned short* w1t  = (unsigned short*)(ws + alloc((size_t)NP_HC * KPA * 2));
  unsigned short* w2t  = (unsigned short*)(ws + alloc((size_t)NP_HC * KPA * 2));
  unsigned short* fc1t = (unsigned short*)(ws + alloc((size_t)NP_CH * KPA * 2));
  unsigned short* fc2t = (unsigned short*)(ws + alloc((size_t)NP_CH * KPA * 2));
  unsigned short* g1t  = (unsigned short*)(ws + alloc((size_t)GW1 * KPA * 2));
  unsigned short* g2t  = (unsigned short*)(ws + alloc((size_t)128 * GW1 * 2));

  // ---- pre-pass: CSR build + conversions ----
  hipMemsetAsync(cnt, 0, (size_t)NNODES * 4, stream);
  hipMemsetAsync(cnt2, 0, (size_t)NNODES * 4, stream);
  hist_k<<<(NETOT + 255) / 256, 256, 0, stream>>>(ei, cnt);
  scan_k<<<1, 1024, 0, stream>>>(cnt, rowptr);
  scatter_k<<<(NETOT + 255) / 256, 256, 0, stream>>>(ei, rowptr, cnt2, esrc);
  cvt0_k<<<(MP * KP0 + 255) / 256, 256, 0, stream>>>(mol_x, xb0);
  tcast_k<<<(NP_HC * KP0 + 255) / 256, 256, 0, stream>>>(W0, w0t, 78, HC, KP0, NP_HC);
  tcast_k<<<(NP_HC * KPA + 255) / 256, 256, 0, stream>>>(W1, w1t, CH, HC, KPA, NP_HC);
  tcast_k<<<(NP_HC * KPA + 255) / 256, 256, 0, stream>>>(W2, w2t, CH, HC, KPA, NP_HC);
  tcast_k<<<(NP_CH * KPA + 255) / 256, 256, 0, stream>>>(fc1w, fc1t, CH, CH, KPA, NP_CH);
  tcast_k<<<(NP_CH * KPA + 255) / 256, 256, 0, stream>>>(fc2w, fc2t, CH, CH, KPA, NP_CH);
  tcast_k<<<(GW1 * KPA + 255) / 256, 256, 0, stream>>>(g1w, g1t, CH, GW1, KPA, GW1);
  tcast_k<<<(128 * GW1 + 255) / 256, 256, 0, stream>>>(g2w, g2t, GW1, 128, GW1, 128);

  auto mgemm = [&](const unsigned short* A, const unsigned short* Bt,
                   float* Cf, unsigned short* Cb, int M, int N, int KP_, int ldc,
                   const float* bias, int act) {
    dim3 grid((N + 127) / 128, (M + 127) / 128);
    hipLaunchKernelGGL(gemm_bb, grid, dim3(256), 0, stream, A, Bt, Cf, Cb,
                       M, N, KP_, ldc, bias, act);
  };

  const int MSGB = (NNODES * 64 + 255) / 256;
  auto gat = [&](const unsigned short* X, int KP_, const unsigned short* Wt,
                 const float* as_, const float* ad_, const float* bias, int act,
                 unsigned short* dst) {
    mgemm(X, Wt, nullptr, h_b, NNODES, HC, KP_, HC, nullptr, 0);
    scores_k<<<MSGB, 256, 0, stream>>>(h_b, as_, ad_, ssrc, sdst);
    mz_k<<<(NNODES + 255) / 256, 256, 0, stream>>>(rowptr, esrc, ssrc, sdst, mval, zval);
    msgcsr_k<<<MSGB, 256, 0, stream>>>(rowptr, esrc, ssrc, sdst, mval, zval, h_b,
                                       bias, act, dst);
  };

  const int GELT = (NNODES * KPA + 255) / 256;

  // ---- layer 0 ----
  gat(xb0, KP0, w0t, as0, ad0, b0, 1, hstate_b);

  // ---- layer 1 ----
  gat(hstate_b, KPA, w1t, as1, ad1, b1, 1, xbuf_b);
  mgemm(xbuf_b,   fc1t, t1, nullptr, NNODES, CH, KPA, CH, nullptr, 0);
  mgemm(hstate_b, fc2t, t2, nullptr, NNODES, CH, KPA, CH, nullptr, 0);
  gate_k<<<GELT, 256, 0, stream>>>(t1, fc1b, t2, fc2b, mbias, xbuf_b, hstate_b);

  // ---- layer 2 ----
  gat(hstate_b, KPA, w2t, as2, ad2, b2, 0, xbuf_b);
  mgemm(xbuf_b,   fc1t, t1, nullptr, NNODES, CH, KPA, CH, nullptr, 0);
  mgemm(hstate_b, fc2t, t2, nullptr, NNODES, CH, KPA, CH, nullptr, 0);
  gate_k<<<GELT, 256, 0, stream>>>(t1, fc1b, t2, fc2b, mbias, xbuf_b, hstate_b);

  // ---- pool + head (all MFMA) ----
  hipMemsetAsync(psum, 0, (size_t)NGRAPH * CH * 4, stream);
  hipMemsetAsync(pcnt, 0, (size_t)NGRAPH * 4, stream);
  poolacc_k<<<(NNODES * CH + 255) / 256, 256, 0, stream>>>(hstate_b, batch, psum);
  poolcnt_k<<<(NNODES + 255) / 256, 256, 0, stream>>>(batch, pcnt);
  pooldiv_k<<<(NGRAPH * KPA + 255) / 256, 256, 0, stream>>>(psum, pcnt, pooled_b);
  mgemm(pooled_b, g1t, nullptr, gbuf_b, NGRAPH, GW1, KPA, GW1, g1b, 1);
  mgemm(gbuf_b,   g2t, out, nullptr, NGRAPH, 128, GW1, 128, g2b, 0);
}

// Round 5
// 957.414 us; speedup vs baseline: 4.9339x; 1.2427x over previous
//
#include <hip/hip_runtime.h>
#include <cstdint>
#include <cstddef>

#define NNODES 50000
#define NEDGE0 400000
#define NETOT  450000
#define NGRAPH 1024
#define CH     312
#define HC     624
#define MP     50048     // NNODES padded to 128
#define KPA    320       // CH padded to 64 (slot width, shorts)
#define AST    640       // activation row stride = 2 slots
#define KP0    128       // 78 padded (layer-0 input)
#define NP_HC  640       // HC padded (weight rows; 624..627 = score cols)
#define NFEAT  628       // feature GEMM N (624 h + 4 score cols)
#define GW1    1024      // head fc1 width

typedef __attribute__((ext_vector_type(4))) float f32x4;
typedef __attribute__((ext_vector_type(8))) short s16x8;

__device__ __forceinline__ unsigned short f2bf(float x) {
  union { float f; unsigned u; } v; v.f = x;
  unsigned r = v.u + 0x7fffu + ((v.u >> 16) & 1u);   // RNE
  return (unsigned short)(r >> 16);
}
__device__ __forceinline__ float bf2f(unsigned short u) {
  union { unsigned u; float f; } v; v.u = ((unsigned)u) << 16;
  return v.f;
}
__device__ __forceinline__ void gl_lds16(const unsigned short* g, unsigned short* l) {
  __builtin_amdgcn_global_load_lds(
      (const __attribute__((address_space(1))) unsigned int*)g,
      (__attribute__((address_space(3))) unsigned int*)l, 16, 0, 0);
}

// ============ conversions / weight prep ============
__global__ void cvt0_k(const float* __restrict__ in, unsigned short* __restrict__ out) {
  int i = blockIdx.x * blockDim.x + threadIdx.x;
  if (i >= MP * KP0) return;
  int n = i >> 7, c = i & 127;
  out[i] = (n < NNODES && c < 78) ? f2bf(in[(size_t)n * 78 + c]) : (unsigned short)0;
}

// weights: in f32 [K][N] -> out bf16 [NP_][KP_], transposed, zero-padded
__global__ void tcast_k(const float* __restrict__ in, unsigned short* __restrict__ out,
                        int K, int N, int KP_, int NP_) {
  int i = blockIdx.x * blockDim.x + threadIdx.x;
  if (i >= NP_ * KP_) return;
  int n = i / KP_, k = i - n * KP_;
  out[i] = (n < N && k < K) ? f2bf(in[(size_t)k * N + n]) : (unsigned short)0;
}

// score columns: wt rows 624..627 <- contracted W·a (src h0, src h1, dst h0, dst h1)
__global__ void swfill_k(const float* __restrict__ W, const float* __restrict__ a_s,
                         const float* __restrict__ a_d, unsigned short* __restrict__ wt,
                         int K, int KP_) {
  int tid = blockIdx.x * blockDim.x + threadIdx.x;
  if (tid >= 4 * KP_) return;
  int j = tid / KP_, k = tid - j * KP_;
  int hd = j & 1;
  const float* a = (j < 2) ? a_s : a_d;
  float s = 0.f;
  if (k < K)
    for (int c = 0; c < CH; ++c)
      s += W[(size_t)k * HC + hd * CH + c] * a[hd * CH + c];
  wt[(size_t)(HC + j) * KP_ + k] = f2bf(s);
}

// stacked [fc1;fc2] -> fc12t[384][640] bf16 transposed
__global__ void tcast2_k(const float* __restrict__ fc1, const float* __restrict__ fc2,
                         unsigned short* __restrict__ out) {
  int i = blockIdx.x * blockDim.x + threadIdx.x;
  if (i >= 384 * AST) return;
  int n = i / AST, k = i - n * AST;
  float v = 0.f;
  if (n < CH) {
    if (k < CH) v = fc1[(size_t)k * CH + n];
    else if (k >= KPA && k - KPA < CH) v = fc2[(size_t)(k - KPA) * CH + n];
  }
  out[i] = f2bf(v);
}

__global__ void gbias_k(const float* __restrict__ b1, const float* __restrict__ b2,
                        const float* __restrict__ mb, float* __restrict__ gb) {
  int c = blockIdx.x * blockDim.x + threadIdx.x;
  if (c >= KPA) return;
  gb[c] = (c < CH) ? (b1[c] + b2[c] + mb[c]) : 0.f;
}

// ============ MFMA GEMM with fused epilogues ============
// BM=128 BN=128 BK=64, 4 waves, dbuf LDS, gload_lds + chunk-XOR swizzle.
// Epilogues: Sc (score cols >= 624, f32), gate (Xg/Hg given), bf16 Cb or f32 Cf.
__global__ __launch_bounds__(256) void gemm_bb(
    const unsigned short* __restrict__ A, int lda,
    const unsigned short* __restrict__ Bt,
    unsigned short* __restrict__ Cb, float* __restrict__ Cf,
    float* __restrict__ Sc, const float* __restrict__ bias,
    const unsigned short* __restrict__ Xg, const unsigned short* __restrict__ Hg,
    int M, int N, int KP_, int ldc, int act)
{
  __shared__ unsigned short As[2][128 * 64];
  __shared__ unsigned short Bs[2][128 * 64];
  const int tid = threadIdx.x, lane = tid & 63, w = tid >> 6;
  const int bm = blockIdx.y * 128, bn = blockIdx.x * 128;
  const int rr = lane >> 3;
  const int cc8 = (lane & 7) ^ rr;

  const int nkt = KP_ >> 6;
  int buf = 0;

  auto stage = [&](int b, int kt) {
    #pragma unroll
    for (int i = 0; i < 4; ++i) {
      int R = w * 32 + i * 8;
      const unsigned short* gA = A + (size_t)(bm + R + rr) * lda + kt * 64 + cc8 * 8;
      gl_lds16(gA, &As[b][R * 64]);
      const unsigned short* gB = Bt + (size_t)(bn + R + rr) * KP_ + kt * 64 + cc8 * 8;
      gl_lds16(gB, &Bs[b][R * 64]);
    }
  };

  const int wr = w >> 1, wc = w & 1;
  const int r16 = lane & 15, g4 = lane >> 4;
  f32x4 zf = {0.f, 0.f, 0.f, 0.f};
  f32x4 acc[4][4];
  #pragma unroll
  for (int m = 0; m < 4; ++m)
    #pragma unroll
    for (int n = 0; n < 4; ++n) acc[m][n] = zf;

  stage(0, 0);
  __syncthreads();
  for (int kt = 0; kt < nkt; ++kt) {
    if (kt + 1 < nkt) stage(buf ^ 1, kt + 1);
    #pragma unroll
    for (int k2 = 0; k2 < 2; ++k2) {
      s16x8 bfr[4], afr[4];
      #pragma unroll
      for (int n = 0; n < 4; ++n) {
        int rB = wc * 64 + n * 16 + r16;
        int ch = (k2 * 4 + g4) ^ (rB & 7);
        bfr[n] = *(const s16x8*)&Bs[buf][rB * 64 + ch * 8];
      }
      #pragma unroll
      for (int m = 0; m < 4; ++m) {
        int rA = wr * 64 + m * 16 + r16;
        int ch = (k2 * 4 + g4) ^ (rA & 7);
        afr[m] = *(const s16x8*)&As[buf][rA * 64 + ch * 8];
      }
      #pragma unroll
      for (int m = 0; m < 4; ++m)
        #pragma unroll
        for (int n = 0; n < 4; ++n)
          acc[m][n] = __builtin_amdgcn_mfma_f32_16x16x32_bf16(afr[m], bfr[n],
                                                              acc[m][n], 0, 0, 0);
    }
    __syncthreads();
    buf ^= 1;
  }

  #pragma unroll
  for (int m = 0; m < 4; ++m) {
    int gm0 = bm + wr * 64 + m * 16 + g4 * 4;
    #pragma unroll
    for (int n = 0; n < 4; ++n) {
      int gn = bn + wc * 64 + n * 16 + r16;
      if (gn >= N) continue;
      float bv = bias ? bias[gn] : 0.f;
      #pragma unroll
      for (int r = 0; r < 4; ++r) {
        int gm = gm0 + r;
        if (gm >= M) continue;
        float v = acc[m][n][r];
        if (Sc && gn >= HC) { Sc[(size_t)gm * 4 + (gn - HC)] = v; continue; }
        v += bv;
        if (Xg) {
          float g = 1.f / (1.f + __expf(-v));
          float xv = bf2f(Xg[(size_t)gm * ldc + gn]);
          float hv = bf2f(Hg[(size_t)gm * ldc + gn]);
          Cb[(size_t)gm * ldc + gn] = f2bf(g * xv + (1.f - g) * hv);
        } else {
          if (act) v = v > 0.f ? v : 0.f;
          if (Cb) Cb[(size_t)gm * ldc + gn] = f2bf(v);
          else    Cf[(size_t)gm * ldc + gn] = v;
        }
      }
    }
  }
}

// ============ CSR build ============
__global__ void hist_k(const int* __restrict__ ei, int* __restrict__ cnt) {
  int e = blockIdx.x * blockDim.x + threadIdx.x;
  if (e >= NETOT) return;
  int d = (e < NEDGE0) ? ei[NEDGE0 + e] : e - NEDGE0;
  atomicAdd(&cnt[d], 1);
}

__global__ __launch_bounds__(1024) void scan_k(const int* __restrict__ cnt,
                                               int* __restrict__ rowptr) {
  __shared__ int wsum[16];
  __shared__ int carry_s;
  int t = threadIdx.x, lane = t & 63, wv = t >> 6;
  if (t == 0) carry_s = 0;
  __syncthreads();
  for (int base = 0; base < NNODES; base += 1024) {
    int idx = base + t;
    int v = (idx < NNODES) ? cnt[idx] : 0;
    int s = v;
    #pragma unroll
    for (int off = 1; off < 64; off <<= 1) {
      int x = __shfl_up(s, off);
      if (lane >= off) s += x;
    }
    if (lane == 63) wsum[wv] = s;
    __syncthreads();
    if (wv == 0) {
      int ws = (lane < 16) ? wsum[lane] : 0;
      #pragma unroll
      for (int off = 1; off < 16; off <<= 1) {
        int x = __shfl_up(ws, off);
        if (lane >= off) ws += x;
      }
      if (lane < 16) wsum[lane] = ws;
    }
    __syncthreads();
    int carry = carry_s;
    int woff = wv ? wsum[wv - 1] : 0;
    if (idx < NNODES) rowptr[idx] = carry + woff + s - v;
    __syncthreads();
    if (t == 1023) carry_s = carry + wsum[15];
    __syncthreads();
  }
  if (t == 0) rowptr[NNODES] = carry_s;
}

__global__ void scatter_k(const int* __restrict__ ei, const int* __restrict__ rowptr,
                          int* __restrict__ cur, int* __restrict__ esrc) {
  int e = blockIdx.x * blockDim.x + threadIdx.x;
  if (e >= NETOT) return;
  int s, d;
  if (e < NEDGE0) { s = ei[e]; d = ei[NEDGE0 + e]; }
  else { s = d = e - NEDGE0; }
  int pos = rowptr[d] + atomicAdd(&cur[d], 1);
  esrc[pos] = s;
}

// ============ fused edge softmax + gather (wave per node) ============
// Sc[n][4] = {ssrc_h0, ssrc_h1, sdst_h0, sdst_h1}; out slot stride AST, bias+act.
__global__ __launch_bounds__(256) void msgcsr_k(
    const int* __restrict__ rowptr, const int* __restrict__ esrc,
    const float* __restrict__ Sc, const unsigned short* __restrict__ h,
    const float* __restrict__ bias, int act, unsigned short* __restrict__ out)
{
  int wid = (blockIdx.x * blockDim.x + threadIdx.x) >> 6;
  int lane = threadIdx.x & 63;
  if (wid >= NNODES) return;
  int e0 = rowptr[wid], e1 = rowptr[wid + 1];
  float sd0 = Sc[(size_t)wid * 4 + 2], sd1 = Sc[(size_t)wid * 4 + 3];

  const int  j1   = lane;                         // chunk id 0..63 (of 78)
  const bool j1h1 = (j1 >= 39);                   // head of chunk j1
  const int  j2   = 64 + (lane < 14 ? lane : 13); // chunks 64..77
  const bool j2on = (lane < 14);

  float f1[8] = {0,0,0,0,0,0,0,0};
  float f2[8] = {0,0,0,0,0,0,0,0};
  float m0 = -1e30f, m1 = -1e30f, z0 = 0.f, z1 = 0.f;

  for (int base = e0; base < e1; base += 64) {
    int cnt = e1 - base; if (cnt > 64) cnt = 64;
    int sl = 0;
    float a0 = -1e30f, a1 = -1e30f;
    if (lane < cnt) {
      sl = esrc[base + lane];
      f32x4 sv = *(const f32x4*)(Sc + (size_t)sl * 4);
      a0 = sv[0] + sd0; a0 = a0 > 0.f ? a0 : 0.2f * a0;
      a1 = sv[1] + sd1; a1 = a1 > 0.f ? a1 : 0.2f * a1;
    }
    // chunk max (wave reduce)
    float cm0 = a0, cm1 = a1;
    #pragma unroll
    for (int off = 32; off; off >>= 1) {
      cm0 = fmaxf(cm0, __shfl_xor(cm0, off));
      cm1 = fmaxf(cm1, __shfl_xor(cm1, off));
    }
    float nm0 = fmaxf(m0, cm0), nm1 = fmaxf(m1, cm1);
    float r0 = __expf(m0 - nm0), r1 = __expf(m1 - nm1);
    z0 *= r0; z1 *= r1;
    float rA = j1h1 ? r1 : r0;
    #pragma unroll
    for (int r = 0; r < 8; ++r) { f1[r] *= rA; f2[r] *= r1; }
    m0 = nm0; m1 = nm1;

    float w0 = (lane < cnt) ? __expf(a0 - nm0) : 0.f;
    float w1 = (lane < cnt) ? __expf(a1 - nm1) : 0.f;
    float cz0 = w0, cz1 = w1;
    #pragma unroll
    for (int off = 32; off; off >>= 1) {
      cz0 += __shfl_xor(cz0, off);
      cz1 += __shfl_xor(cz1, off);
    }
    z0 += cz0; z1 += cz1;

    for (int e = 0; e < cnt; ++e) {
      int   s   = __shfl(sl, e);
      float we0 = __shfl(w0, e), we1 = __shfl(w1, e);
      const unsigned short* hp = h + (size_t)s * HC;
      s16x8 c1 = *(const s16x8*)(hp + j1 * 8);
      s16x8 c2 = *(const s16x8*)(hp + j2 * 8);
      float wa = j1h1 ? we1 : we0;
      float wb = j2on ? we1 : 0.f;
      #pragma unroll
      for (int r = 0; r < 8; ++r) {
        f1[r] += wa * bf2f((unsigned short)c1[r]);
        f2[r] += wb * bf2f((unsigned short)c2[r]);
      }
    }
  }

  float i0 = 0.5f / (z0 + 1e-16f), i1 = 0.5f / (z1 + 1e-16f);
  float sA = j1h1 ? i1 : i0;
  #pragma unroll
  for (int r = 0; r < 8; ++r) { f1[r] *= sA; f2[r] *= i1; }

  // combine heads: out chunk j (=lane<39): head0 = f1(lane), head1 = chunk j+39
  float vout[8];
  #pragma unroll
  for (int r = 0; r < 8; ++r) {
    float p1 = __shfl(f1[r], lane + 39);   // valid for lane<25
    float p2 = __shfl(f2[r], lane - 25);   // valid for 25<=lane<39
    vout[r] = f1[r] + ((lane < 25) ? p1 : p2);
  }
  s16x8 res;
  if (lane < 39) {
    #pragma unroll
    for (int r = 0; r < 8; ++r) {
      float v = vout[r] + bias[lane * 8 + r];
      if (act) v = v > 0.f ? v : 0.f;
      res[r] = (short)f2bf(v);
    }
  } else {
    #pragma unroll
    for (int r = 0; r < 8; ++r) res[r] = 0;
  }
  if (lane < 40)
    *(s16x8*)(out + (size_t)wid * AST + lane * 8) = res;
}

// ============ pooling (sorted batch -> graph ranges) ============
__global__ void gptr_k(const int* __restrict__ batch, int* __restrict__ gptr) {
  int g = blockIdx.x * blockDim.x + threadIdx.x;
  if (g > NGRAPH) return;
  int lo = 0, hi = NNODES;
  while (lo < hi) { int mid = (lo + hi) >> 1; if (batch[mid] < g) lo = mid + 1; else hi = mid; }
  gptr[g] = lo;
}

__global__ __launch_bounds__(256) void pool_k(const unsigned short* __restrict__ hs,
                                              const int* __restrict__ gptr,
                                              unsigned short* __restrict__ pooled) {
  int g = blockIdx.x;
  int n0 = gptr[g], n1 = gptr[g + 1];
  float inv = (n1 > n0) ? 1.f / (float)(n1 - n0) : 0.f;
  for (int c = threadIdx.x; c < KPA; c += 256) {
    float s = 0.f;
    if (c < CH)
      for (int n = n0; n < n1; ++n) s += bf2f(hs[(size_t)n * AST + c]);
    pooled[(size_t)g * KPA + c] = f2bf(s * inv);
  }
}

extern "C" void kernel_launch(void* const* d_in, const int* in_sizes, int n_in,
                              void* d_out, int out_size, void* d_ws, size_t ws_size,
                              hipStream_t stream)
{
  const float* mol_x = (const float*)d_in[0];
  const int*   ei    = (const int*)d_in[1];
  const int*   batch = (const int*)d_in[2];
  const float* W0  = (const float*)d_in[3];
  const float* as0 = (const float*)d_in[4];
  const float* ad0 = (const float*)d_in[5];
  const float* b0  = (const float*)d_in[6];
  const float* W1  = (const float*)d_in[7];
  const float* as1 = (const float*)d_in[8];
  const float* ad1 = (const float*)d_in[9];
  const float* b1  = (const float*)d_in[10];
  const float* W2  = (const float*)d_in[11];
  const float* as2 = (const float*)d_in[12];
  const float* ad2 = (const float*)d_in[13];
  const float* b2  = (const float*)d_in[14];
  const float* fc1w = (const float*)d_in[15];
  const float* fc1b = (const float*)d_in[16];
  const float* fc2w = (const float*)d_in[17];
  const float* fc2b = (const float*)d_in[18];
  const float* mbias = (const float*)d_in[19];
  const float* g1w = (const float*)d_in[20];
  const float* g1b = (const float*)d_in[21];
  const float* g2w = (const float*)d_in[22];
  const float* g2b = (const float*)d_in[23];
  float* out = (float*)d_out;

  char* ws = (char*)d_ws;
  size_t off = 0;
  auto alloc = [&](size_t b) { size_t r = off; off += (b + 255) & ~(size_t)255; return r; };
  unsigned short* h_b  = (unsigned short*)(ws + alloc((size_t)NNODES * HC * 2));
  unsigned short* actA = (unsigned short*)(ws + alloc((size_t)MP * AST * 2));
  unsigned short* actB = (unsigned short*)(ws + alloc((size_t)MP * AST * 2));
  unsigned short* xb0  = (unsigned short*)(ws + alloc((size_t)MP * KP0 * 2));
  float* Sc     = (float*)(ws + alloc((size_t)MP * 4 * 4));
  int*   cnt    = (int*)(ws + alloc((size_t)NNODES * 4));
  int*   cnt2   = (int*)(ws + alloc((size_t)NNODES * 4));
  int*   rowptr = (int*)(ws + alloc((size_t)(NNODES + 1) * 4));
  int*   esrc   = (int*)(ws + alloc((size_t)NETOT * 4));
  int*   gptr   = (int*)(ws + alloc((size_t)(NGRAPH + 1) * 4));
  float* gbias  = (float*)(ws + alloc((size_t)KPA * 4));
  unsigned short* pooled_b = (unsigned short*)(ws + alloc((size_t)NGRAPH * KPA * 2));
  unsigned short* gbuf_b   = (unsigned short*)(ws + alloc((size_t)NGRAPH * GW1 * 2));
  unsigned short* w0t   = (unsigned short*)(ws + alloc((size_t)NP_HC * KP0 * 2));
  unsigned short* w1t   = (unsigned short*)(ws + alloc((size_t)NP_HC * KPA * 2));
  unsigned short* w2t   = (unsigned short*)(ws + alloc((size_t)NP_HC * KPA * 2));
  unsigned short* fc12t = (unsigned short*)(ws + alloc((size_t)384 * AST * 2));
  unsigned short* g1t   = (unsigned short*)(ws + alloc((size_t)GW1 * KPA * 2));
  unsigned short* g2t   = (unsigned short*)(ws + alloc((size_t)128 * GW1 * 2));

  // ---- pre-pass ----
  hipMemsetAsync(cnt, 0, (size_t)NNODES * 4, stream);
  hipMemsetAsync(cnt2, 0, (size_t)NNODES * 4, stream);
  hist_k<<<(NETOT + 255) / 256, 256, 0, stream>>>(ei, cnt);
  scan_k<<<1, 1024, 0, stream>>>(cnt, rowptr);
  scatter_k<<<(NETOT + 255) / 256, 256, 0, stream>>>(ei, rowptr, cnt2, esrc);
  gptr_k<<<(NGRAPH + 256) / 256, 256, 0, stream>>>(batch, gptr);
  cvt0_k<<<(MP * KP0 + 255) / 256, 256, 0, stream>>>(mol_x, xb0);
  tcast_k<<<(NP_HC * KP0 + 255) / 256, 256, 0, stream>>>(W0, w0t, 78, HC, KP0, NP_HC);
  tcast_k<<<(NP_HC * KPA + 255) / 256, 256, 0, stream>>>(W1, w1t, CH, HC, KPA, NP_HC);
  tcast_k<<<(NP_HC * KPA + 255) / 256, 256, 0, stream>>>(W2, w2t, CH, HC, KPA, NP_HC);
  swfill_k<<<(4 * KP0 + 255) / 256, 256, 0, stream>>>(W0, as0, ad0, w0t, 78, KP0);
  swfill_k<<<(4 * KPA + 255) / 256, 256, 0, stream>>>(W1, as1, ad1, w1t, CH, KPA);
  swfill_k<<<(4 * KPA + 255) / 256, 256, 0, stream>>>(W2, as2, ad2, w2t, CH, KPA);
  tcast2_k<<<(384 * AST + 255) / 256, 256, 0, stream>>>(fc1w, fc2w, fc12t);
  gbias_k<<<2, 256, 0, stream>>>(fc1b, fc2b, mbias, gbias);
  tcast_k<<<(GW1 * KPA + 255) / 256, 256, 0, stream>>>(g1w, g1t, CH, GW1, KPA, GW1);
  tcast_k<<<(128 * GW1 + 255) / 256, 256, 0, stream>>>(g2w, g2t, GW1, 128, GW1, 128);

  auto mgemm = [&](const unsigned short* A, int lda, const unsigned short* Bt,
                   unsigned short* Cb, float* Cf, float* Sc_, const float* bias,
                   const unsigned short* Xg, const unsigned short* Hg,
                   int M, int N, int KP_, int ldc, int act) {
    dim3 grid((N + 127) / 128, (M + 127) / 128);
    hipLaunchKernelGGL(gemm_bb, grid, dim3(256), 0, stream, A, lda, Bt, Cb, Cf,
                       Sc_, bias, Xg, Hg, M, N, KP_, ldc, act);
  };

  const int MSGB = (NNODES * 64 + 255) / 256;
  // act buffers: x-slot = +0, h-slot = +KPA (stride AST)
  unsigned short* hA = actA + KPA;
  unsigned short* hB = actB + KPA;

  // ---- layer 0: feature GEMM (+scores) -> msgcsr writes hstate0 (actA h-slot) ----
  mgemm(xb0, KP0, w0t, h_b, nullptr, Sc, nullptr, nullptr, nullptr,
        NNODES, NFEAT, KP0, HC, 0);
  msgcsr_k<<<MSGB, 256, 0, stream>>>(rowptr, esrc, Sc, h_b, b0, 1, hA);

  // ---- layer 1 ----
  mgemm(hA, AST, w1t, h_b, nullptr, Sc, nullptr, nullptr, nullptr,
        NNODES, NFEAT, KPA, HC, 0);
  msgcsr_k<<<MSGB, 256, 0, stream>>>(rowptr, esrc, Sc, h_b, b1, 1, actA);  // x-slot
  mgemm(actA, AST, fc12t, hB, nullptr, nullptr, gbias, actA, hA,
        NNODES, KPA, AST, AST, 0);                                         // gate -> hB

  // ---- layer 2 ----
  mgemm(hB, AST, w2t, h_b, nullptr, Sc, nullptr, nullptr, nullptr,
        NNODES, NFEAT, KPA, HC, 0);
  msgcsr_k<<<MSGB, 256, 0, stream>>>(rowptr, esrc, Sc, h_b, b2, 0, actB);  // x-slot
  mgemm(actB, AST, fc12t, hA, nullptr, nullptr, gbias, actB, hB,
        NNODES, KPA, AST, AST, 0);                                         // gate -> hA

  // ---- pool + head ----
  pool_k<<<NGRAPH, 256, 0, stream>>>(hA, gptr, pooled_b);
  mgemm(pooled_b, KPA, g1t, gbuf_b, nullptr, nullptr, g1b, nullptr, nullptr,
        NGRAPH, GW1, KPA, GW1, 1);
  mgemm(gbuf_b, GW1, g2t, nullptr, out, nullptr, g2b, nullptr, nullptr,
        NGRAPH, 128, GW1, 128, 0);
}

// Round 6
// 914.067 us; speedup vs baseline: 5.1679x; 1.0474x over previous
//
#include <hip/hip_runtime.h>
#include <cstdint>
#include <cstddef>

#define NNODES 50000
#define NEDGE0 400000
#define NETOT  450000
#define NGRAPH 1024
#define CH     312
#define HC     624
#define MP     50048     // NNODES padded to 128
#define KPA    320       // CH padded to 64 (slot width, shorts)
#define AST    640       // activation row stride = 2 slots
#define KP0    128       // 78 padded (layer-0 input)
#define NP_HC  640       // HC padded (weight rows; 624..627 = score cols)
#define NFEAT  628       // feature GEMM N (624 h + 4 score cols)
#define GW1    1024      // head fc1 width

typedef __attribute__((ext_vector_type(4))) float f32x4;
typedef __attribute__((ext_vector_type(8))) short s16x8;

__device__ __forceinline__ unsigned short f2bf(float x) {
  union { float f; unsigned u; } v; v.f = x;
  unsigned r = v.u + 0x7fffu + ((v.u >> 16) & 1u);   // RNE
  return (unsigned short)(r >> 16);
}
__device__ __forceinline__ float bf2f(unsigned short u) {
  union { unsigned u; float f; } v; v.u = ((unsigned)u) << 16;
  return v.f;
}
__device__ __forceinline__ void gl_lds16(const unsigned short* g, unsigned short* l) {
  __builtin_amdgcn_global_load_lds(
      (const __attribute__((address_space(1))) unsigned int*)g,
      (__attribute__((address_space(3))) unsigned int*)l, 16, 0, 0);
}

// ============ conversions / weight prep ============
__global__ void cvt0_k(const float* __restrict__ in, unsigned short* __restrict__ out) {
  int i = blockIdx.x * blockDim.x + threadIdx.x;
  if (i >= MP * KP0) return;
  int n = i >> 7, c = i & 127;
  out[i] = (n < NNODES && c < 78) ? f2bf(in[(size_t)n * 78 + c]) : (unsigned short)0;
}

// weights: in f32 [K][N] -> out bf16 [NP_][KP_], transposed, zero-padded
__global__ void tcast_k(const float* __restrict__ in, unsigned short* __restrict__ out,
                        int K, int N, int KP_, int NP_) {
  int i = blockIdx.x * blockDim.x + threadIdx.x;
  if (i >= NP_ * KP_) return;
  int n = i / KP_, k = i - n * KP_;
  out[i] = (n < N && k < K) ? f2bf(in[(size_t)k * N + n]) : (unsigned short)0;
}

// score columns: wt rows 624..627 <- contracted W·a (src h0, src h1, dst h0, dst h1)
__global__ void swfill_k(const float* __restrict__ W, const float* __restrict__ a_s,
                         const float* __restrict__ a_d, unsigned short* __restrict__ wt,
                         int K, int KP_) {
  int tid = blockIdx.x * blockDim.x + threadIdx.x;
  if (tid >= 4 * KP_) return;
  int j = tid / KP_, k = tid - j * KP_;
  int hd = j & 1;
  const float* a = (j < 2) ? a_s : a_d;
  float s = 0.f;
  if (k < K)
    for (int c = 0; c < CH; ++c)
      s += W[(size_t)k * HC + hd * CH + c] * a[hd * CH + c];
  wt[(size_t)(HC + j) * KP_ + k] = f2bf(s);
}

// stacked [fc1;fc2] -> fc12t[384][640] bf16 transposed
__global__ void tcast2_k(const float* __restrict__ fc1, const float* __restrict__ fc2,
                         unsigned short* __restrict__ out) {
  int i = blockIdx.x * blockDim.x + threadIdx.x;
  if (i >= 384 * AST) return;
  int n = i / AST, k = i - n * AST;
  float v = 0.f;
  if (n < CH) {
    if (k < CH) v = fc1[(size_t)k * CH + n];
    else if (k >= KPA && k - KPA < CH) v = fc2[(size_t)(k - KPA) * CH + n];
  }
  out[i] = f2bf(v);
}

__global__ void gbias_k(const float* __restrict__ b1, const float* __restrict__ b2,
                        const float* __restrict__ mb, float* __restrict__ gb) {
  int c = blockIdx.x * blockDim.x + threadIdx.x;
  if (c >= KPA) return;
  gb[c] = (c < CH) ? (b1[c] + b2[c] + mb[c]) : 0.f;
}

// ============ MFMA GEMM with fused epilogues ============
// BM=128 BN=128 BK=64, 4 waves, dbuf LDS, gload_lds + chunk-XOR swizzle.
// 1D grid + bijective XCD chunk swizzle (same-A blocks colocate on one XCD L2).
__global__ __launch_bounds__(256) void gemm_bb(
    const unsigned short* __restrict__ A, int lda,
    const unsigned short* __restrict__ Bt,
    unsigned short* __restrict__ Cb, float* __restrict__ Cf,
    float* __restrict__ Sc, const float* __restrict__ bias,
    const unsigned short* __restrict__ Xg, const unsigned short* __restrict__ Hg,
    int M, int N, int KP_, int ldc, int act, int gx)
{
  // ---- XCD-bijective block swizzle (m204) ----
  const int nwg = gridDim.x, orig = blockIdx.x;
  const int q = nwg >> 3, r = nwg & 7;
  const int xcd = orig & 7, loc = orig >> 3;
  const int swz = (xcd < r ? xcd * (q + 1) : r * (q + 1) + (xcd - r) * q) + loc;
  const int bn = (swz % gx) * 128, bm = (swz / gx) * 128;

  __shared__ unsigned short As[2][128 * 64];
  __shared__ unsigned short Bs[2][128 * 64];
  const int tid = threadIdx.x, lane = tid & 63, w = tid >> 6;
  const int rr = lane >> 3;
  const int cc8 = (lane & 7) ^ rr;

  const int nkt = KP_ >> 6;
  int buf = 0;

  auto stage = [&](int b, int kt) {
    #pragma unroll
    for (int i = 0; i < 4; ++i) {
      int R = w * 32 + i * 8;
      const unsigned short* gA = A + (size_t)(bm + R + rr) * lda + kt * 64 + cc8 * 8;
      gl_lds16(gA, &As[b][R * 64]);
      const unsigned short* gB = Bt + (size_t)(bn + R + rr) * KP_ + kt * 64 + cc8 * 8;
      gl_lds16(gB, &Bs[b][R * 64]);
    }
  };

  const int wr = w >> 1, wc = w & 1;
  const int r16 = lane & 15, g4 = lane >> 4;
  f32x4 zf = {0.f, 0.f, 0.f, 0.f};
  f32x4 acc[4][4];
  #pragma unroll
  for (int m = 0; m < 4; ++m)
    #pragma unroll
    for (int n = 0; n < 4; ++n) acc[m][n] = zf;

  stage(0, 0);
  __syncthreads();
  for (int kt = 0; kt < nkt; ++kt) {
    if (kt + 1 < nkt) stage(buf ^ 1, kt + 1);
    #pragma unroll
    for (int k2 = 0; k2 < 2; ++k2) {
      s16x8 bfr[4], afr[4];
      #pragma unroll
      for (int n = 0; n < 4; ++n) {
        int rB = wc * 64 + n * 16 + r16;
        int ch = (k2 * 4 + g4) ^ (rB & 7);
        bfr[n] = *(const s16x8*)&Bs[buf][rB * 64 + ch * 8];
      }
      #pragma unroll
      for (int m = 0; m < 4; ++m) {
        int rA = wr * 64 + m * 16 + r16;
        int ch = (k2 * 4 + g4) ^ (rA & 7);
        afr[m] = *(const s16x8*)&As[buf][rA * 64 + ch * 8];
      }
      __builtin_amdgcn_s_setprio(1);
      #pragma unroll
      for (int m = 0; m < 4; ++m)
        #pragma unroll
        for (int n = 0; n < 4; ++n)
          acc[m][n] = __builtin_amdgcn_mfma_f32_16x16x32_bf16(afr[m], bfr[n],
                                                              acc[m][n], 0, 0, 0);
      __builtin_amdgcn_s_setprio(0);
    }
    __syncthreads();
    buf ^= 1;
  }

  #pragma unroll
  for (int m = 0; m < 4; ++m) {
    int gm0 = bm + wr * 64 + m * 16 + g4 * 4;
    #pragma unroll
    for (int n = 0; n < 4; ++n) {
      int gn = bn + wc * 64 + n * 16 + r16;
      if (gn >= N) continue;
      float bv = bias ? bias[gn] : 0.f;
      #pragma unroll
      for (int r2 = 0; r2 < 4; ++r2) {
        int gm = gm0 + r2;
        if (gm >= M) continue;
        float v = acc[m][n][r2];
        if (Sc && gn >= HC) { Sc[(size_t)gm * 4 + (gn - HC)] = v; continue; }
        v += bv;
        if (Xg) {
          float g = 1.f / (1.f + __expf(-v));
          float xv = bf2f(Xg[(size_t)gm * ldc + gn]);
          float hv = bf2f(Hg[(size_t)gm * ldc + gn]);
          Cb[(size_t)gm * ldc + gn] = f2bf(g * xv + (1.f - g) * hv);
        } else {
          if (act) v = v > 0.f ? v : 0.f;
          if (Cb) Cb[(size_t)gm * ldc + gn] = f2bf(v);
          else    Cf[(size_t)gm * ldc + gn] = v;
        }
      }
    }
  }
}

// ============ CSR build ============
__global__ void hist_k(const int* __restrict__ ei, int* __restrict__ cnt) {
  int e = blockIdx.x * blockDim.x + threadIdx.x;
  if (e >= NETOT) return;
  int d = (e < NEDGE0) ? ei[NEDGE0 + e] : e - NEDGE0;
  atomicAdd(&cnt[d], 1);
}

__global__ __launch_bounds__(1024) void scan_k(const int* __restrict__ cnt,
                                               int* __restrict__ rowptr) {
  __shared__ int wsum[16];
  __shared__ int carry_s;
  int t = threadIdx.x, lane = t & 63, wv = t >> 6;
  if (t == 0) carry_s = 0;
  __syncthreads();
  for (int base = 0; base < NNODES; base += 1024) {
    int idx = base + t;
    int v = (idx < NNODES) ? cnt[idx] : 0;
    int s = v;
    #pragma unroll
    for (int off = 1; off < 64; off <<= 1) {
      int x = __shfl_up(s, off);
      if (lane >= off) s += x;
    }
    if (lane == 63) wsum[wv] = s;
    __syncthreads();
    if (wv == 0) {
      int ws = (lane < 16) ? wsum[lane] : 0;
      #pragma unroll
      for (int off = 1; off < 16; off <<= 1) {
        int x = __shfl_up(ws, off);
        if (lane >= off) ws += x;
      }
      if (lane < 16) wsum[lane] = ws;
    }
    __syncthreads();
    int carry = carry_s;
    int woff = wv ? wsum[wv - 1] : 0;
    if (idx < NNODES) rowptr[idx] = carry + woff + s - v;
    __syncthreads();
    if (t == 1023) carry_s = carry + wsum[15];
    __syncthreads();
  }
  if (t == 0) rowptr[NNODES] = carry_s;
}

__global__ void scatter_k(const int* __restrict__ ei, const int* __restrict__ rowptr,
                          int* __restrict__ cur, int* __restrict__ esrc) {
  int e = blockIdx.x * blockDim.x + threadIdx.x;
  if (e >= NETOT) return;
  int s, d;
  if (e < NEDGE0) { s = ei[e]; d = ei[NEDGE0 + e]; }
  else { s = d = e - NEDGE0; }
  int pos = rowptr[d] + atomicAdd(&cur[d], 1);
  esrc[pos] = s;
}

// ============ fused edge softmax + gather (wave per node) ============
__global__ __launch_bounds__(256) void msgcsr_k(
    const int* __restrict__ rowptr, const int* __restrict__ esrc,
    const float* __restrict__ Sc, const unsigned short* __restrict__ h,
    const float* __restrict__ bias, int act, unsigned short* __restrict__ out)
{
  int wid = (blockIdx.x * blockDim.x + threadIdx.x) >> 6;
  int lane = threadIdx.x & 63;
  if (wid >= NNODES) return;
  int e0 = rowptr[wid], e1 = rowptr[wid + 1];
  float sd0 = Sc[(size_t)wid * 4 + 2], sd1 = Sc[(size_t)wid * 4 + 3];

  const int  j1   = lane;
  const bool j1h1 = (j1 >= 39);
  const int  j2   = 64 + (lane < 14 ? lane : 13);
  const bool j2on = (lane < 14);

  float f1[8] = {0,0,0,0,0,0,0,0};
  float f2[8] = {0,0,0,0,0,0,0,0};
  float m0 = -1e30f, m1 = -1e30f, z0 = 0.f, z1 = 0.f;

  for (int base = e0; base < e1; base += 64) {
    int cnt = e1 - base; if (cnt > 64) cnt = 64;
    int sl = 0;
    float a0 = -1e30f, a1 = -1e30f;
    if (lane < cnt) {
      sl = esrc[base + lane];
      f32x4 sv = *(const f32x4*)(Sc + (size_t)sl * 4);
      a0 = sv[0] + sd0; a0 = a0 > 0.f ? a0 : 0.2f * a0;
      a1 = sv[1] + sd1; a1 = a1 > 0.f ? a1 : 0.2f * a1;
    }
    float cm0 = a0, cm1 = a1;
    #pragma unroll
    for (int off = 32; off; off >>= 1) {
      cm0 = fmaxf(cm0, __shfl_xor(cm0, off));
      cm1 = fmaxf(cm1, __shfl_xor(cm1, off));
    }
    float nm0 = fmaxf(m0, cm0), nm1 = fmaxf(m1, cm1);
    float r0 = __expf(m0 - nm0), r1 = __expf(m1 - nm1);
    z0 *= r0; z1 *= r1;
    float rA = j1h1 ? r1 : r0;
    #pragma unroll
    for (int r = 0; r < 8; ++r) { f1[r] *= rA; f2[r] *= r1; }
    m0 = nm0; m1 = nm1;

    float w0 = (lane < cnt) ? __expf(a0 - nm0) : 0.f;
    float w1 = (lane < cnt) ? __expf(a1 - nm1) : 0.f;
    float cz0 = w0, cz1 = w1;
    #pragma unroll
    for (int off = 32; off; off >>= 1) {
      cz0 += __shfl_xor(cz0, off);
      cz1 += __shfl_xor(cz1, off);
    }
    z0 += cz0; z1 += cz1;

    for (int e = 0; e < cnt; ++e) {
      int   s   = __shfl(sl, e);
      float we0 = __shfl(w0, e), we1 = __shfl(w1, e);
      const unsigned short* hp = h + (size_t)s * HC;
      s16x8 c1 = *(const s16x8*)(hp + j1 * 8);
      s16x8 c2 = *(const s16x8*)(hp + j2 * 8);
      float wa = j1h1 ? we1 : we0;
      float wb = j2on ? we1 : 0.f;
      #pragma unroll
      for (int r = 0; r < 8; ++r) {
        f1[r] += wa * bf2f((unsigned short)c1[r]);
        f2[r] += wb * bf2f((unsigned short)c2[r]);
      }
    }
  }

  float i0 = 0.5f / (z0 + 1e-16f), i1 = 0.5f / (z1 + 1e-16f);
  float sA = j1h1 ? i1 : i0;
  #pragma unroll
  for (int r = 0; r < 8; ++r) { f1[r] *= sA; f2[r] *= i1; }

  float vout[8];
  #pragma unroll
  for (int r = 0; r < 8; ++r) {
    float p1 = __shfl(f1[r], lane + 39);
    float p2 = __shfl(f2[r], lane - 25);
    vout[r] = f1[r] + ((lane < 25) ? p1 : p2);
  }
  s16x8 res;
  if (lane < 39) {
    #pragma unroll
    for (int r = 0; r < 8; ++r) {
      float v = vout[r] + bias[lane * 8 + r];
      if (act) v = v > 0.f ? v : 0.f;
      res[r] = (short)f2bf(v);
    }
  } else {
    #pragma unroll
    for (int r = 0; r < 8; ++r) res[r] = 0;
  }
  if (lane < 40)
    *(s16x8*)(out + (size_t)wid * AST + lane * 8) = res;
}

// ============ pooling (sorted batch -> graph ranges) ============
__global__ void gptr_k(const int* __restrict__ batch, int* __restrict__ gptr) {
  int g = blockIdx.x * blockDim.x + threadIdx.x;
  if (g > NGRAPH) return;
  int lo = 0, hi = NNODES;
  while (lo < hi) { int mid = (lo + hi) >> 1; if (batch[mid] < g) lo = mid + 1; else hi = mid; }
  gptr[g] = lo;
}

__global__ __launch_bounds__(256) void pool_k(const unsigned short* __restrict__ hs,
                                              const int* __restrict__ gptr,
                                              unsigned short* __restrict__ pooled) {
  int g = blockIdx.x;
  int n0 = gptr[g], n1 = gptr[g + 1];
  float inv = (n1 > n0) ? 1.f / (float)(n1 - n0) : 0.f;
  for (int c = threadIdx.x; c < KPA; c += 256) {
    float s = 0.f;
    if (c < CH)
      for (int n = n0; n < n1; ++n) s += bf2f(hs[(size_t)n * AST + c]);
    pooled[(size_t)g * KPA + c] = f2bf(s * inv);
  }
}

extern "C" void kernel_launch(void* const* d_in, const int* in_sizes, int n_in,
                              void* d_out, int out_size, void* d_ws, size_t ws_size,
                              hipStream_t stream)
{
  const float* mol_x = (const float*)d_in[0];
  const int*   ei    = (const int*)d_in[1];
  const int*   batch = (const int*)d_in[2];
  const float* W0  = (const float*)d_in[3];
  const float* as0 = (const float*)d_in[4];
  const float* ad0 = (const float*)d_in[5];
  const float* b0  = (const float*)d_in[6];
  const float* W1  = (const float*)d_in[7];
  const float* as1 = (const float*)d_in[8];
  const float* ad1 = (const float*)d_in[9];
  const float* b1  = (const float*)d_in[10];
  const float* W2  = (const float*)d_in[11];
  const float* as2 = (const float*)d_in[12];
  const float* ad2 = (const float*)d_in[13];
  const float* b2  = (const float*)d_in[14];
  const float* fc1w = (const float*)d_in[15];
  const float* fc1b = (const float*)d_in[16];
  const float* fc2w = (const float*)d_in[17];
  const float* fc2b = (const float*)d_in[18];
  const float* mbias = (const float*)d_in[19];
  const float* g1w = (const float*)d_in[20];
  const float* g1b = (const float*)d_in[21];
  const float* g2w = (const float*)d_in[22];
  const float* g2b = (const float*)d_in[23];
  float* out = (float*)d_out;

  char* ws = (char*)d_ws;
  size_t off = 0;
  auto alloc = [&](size_t b) { size_t r = off; off += (b + 255) & ~(size_t)255; return r; };
  unsigned short* h_b  = (unsigned short*)(ws + alloc((size_t)NNODES * HC * 2));
  unsigned short* actA = (unsigned short*)(ws + alloc((size_t)MP * AST * 2));
  unsigned short* actB = (unsigned short*)(ws + alloc((size_t)MP * AST * 2));
  unsigned short* xb0  = (unsigned short*)(ws + alloc((size_t)MP * KP0 * 2));
  float* Sc     = (float*)(ws + alloc((size_t)MP * 4 * 4));
  int*   cnt    = (int*)(ws + alloc((size_t)NNODES * 4));
  int*   cnt2   = (int*)(ws + alloc((size_t)NNODES * 4));
  int*   rowptr = (int*)(ws + alloc((size_t)(NNODES + 1) * 4));
  int*   esrc   = (int*)(ws + alloc((size_t)NETOT * 4));
  int*   gptr   = (int*)(ws + alloc((size_t)(NGRAPH + 1) * 4));
  float* gbias  = (float*)(ws + alloc((size_t)KPA * 4));
  unsigned short* pooled_b = (unsigned short*)(ws + alloc((size_t)NGRAPH * KPA * 2));
  unsigned short* gbuf_b   = (unsigned short*)(ws + alloc((size_t)NGRAPH * GW1 * 2));
  unsigned short* w0t   = (unsigned short*)(ws + alloc((size_t)NP_HC * KP0 * 2));
  unsigned short* w1t   = (unsigned short*)(ws + alloc((size_t)NP_HC * KPA * 2));
  unsigned short* w2t   = (unsigned short*)(ws + alloc((size_t)NP_HC * KPA * 2));
  unsigned short* fc12t = (unsigned short*)(ws + alloc((size_t)384 * AST * 2));
  unsigned short* g1t   = (unsigned short*)(ws + alloc((size_t)GW1 * KPA * 2));
  unsigned short* g2t   = (unsigned short*)(ws + alloc((size_t)128 * GW1 * 2));

  // ---- pre-pass ----
  hipMemsetAsync(cnt, 0, (size_t)NNODES * 4, stream);
  hipMemsetAsync(cnt2, 0, (size_t)NNODES * 4, stream);
  hist_k<<<(NETOT + 255) / 256, 256, 0, stream>>>(ei, cnt);
  scan_k<<<1, 1024, 0, stream>>>(cnt, rowptr);
  scatter_k<<<(NETOT + 255) / 256, 256, 0, stream>>>(ei, rowptr, cnt2, esrc);
  gptr_k<<<(NGRAPH + 256) / 256, 256, 0, stream>>>(batch, gptr);
  cvt0_k<<<(MP * KP0 + 255) / 256, 256, 0, stream>>>(mol_x, xb0);
  tcast_k<<<(NP_HC * KP0 + 255) / 256, 256, 0, stream>>>(W0, w0t, 78, HC, KP0, NP_HC);
  tcast_k<<<(NP_HC * KPA + 255) / 256, 256, 0, stream>>>(W1, w1t, CH, HC, KPA, NP_HC);
  tcast_k<<<(NP_HC * KPA + 255) / 256, 256, 0, stream>>>(W2, w2t, CH, HC, KPA, NP_HC);
  swfill_k<<<(4 * KP0 + 255) / 256, 256, 0, stream>>>(W0, as0, ad0, w0t, 78, KP0);
  swfill_k<<<(4 * KPA + 255) / 256, 256, 0, stream>>>(W1, as1, ad1, w1t, CH, KPA);
  swfill_k<<<(4 * KPA + 255) / 256, 256, 0, stream>>>(W2, as2, ad2, w2t, CH, KPA);
  tcast2_k<<<(384 * AST + 255) / 256, 256, 0, stream>>>(fc1w, fc2w, fc12t);
  gbias_k<<<2, 256, 0, stream>>>(fc1b, fc2b, mbias, gbias);
  tcast_k<<<(GW1 * KPA + 255) / 256, 256, 0, stream>>>(g1w, g1t, CH, GW1, KPA, GW1);
  tcast_k<<<(128 * GW1 + 255) / 256, 256, 0, stream>>>(g2w, g2t, GW1, 128, GW1, 128);

  auto mgemm = [&](const unsigned short* A, int lda, const unsigned short* Bt,
                   unsigned short* Cb, float* Cf, float* Sc_, const float* bias,
                   const unsigned short* Xg, const unsigned short* Hg,
                   int M, int N, int KP_, int ldc, int act) {
    int gx = (N + 127) / 128, gy = (M + 127) / 128;
    hipLaunchKernelGGL(gemm_bb, dim3(gx * gy), dim3(256), 0, stream, A, lda, Bt,
                       Cb, Cf, Sc_, bias, Xg, Hg, M, N, KP_, ldc, act, gx);
  };

  const int MSGB = (NNODES * 64 + 255) / 256;
  unsigned short* hA = actA + KPA;
  unsigned short* hB = actB + KPA;

  // ---- layer 0 ----
  mgemm(xb0, KP0, w0t, h_b, nullptr, Sc, nullptr, nullptr, nullptr,
        NNODES, NFEAT, KP0, HC, 0);
  msgcsr_k<<<MSGB, 256, 0, stream>>>(rowptr, esrc, Sc, h_b, b0, 1, hA);

  // ---- layer 1 ----
  mgemm(hA, AST, w1t, h_b, nullptr, Sc, nullptr, nullptr, nullptr,
        NNODES, NFEAT, KPA, HC, 0);
  msgcsr_k<<<MSGB, 256, 0, stream>>>(rowptr, esrc, Sc, h_b, b1, 1, actA);
  mgemm(actA, AST, fc12t, hB, nullptr, nullptr, gbias, actA, hA,
        NNODES, KPA, AST, AST, 0);

  // ---- layer 2 ----
  mgemm(hB, AST, w2t, h_b, nullptr, Sc, nullptr, nullptr, nullptr,
        NNODES, NFEAT, KPA, HC, 0);
  msgcsr_k<<<MSGB, 256, 0, stream>>>(rowptr, esrc, Sc, h_b, b2, 0, actB);
  mgemm(actB, AST, fc12t, hA, nullptr, nullptr, gbias, actB, hB,
        NNODES, KPA, AST, AST, 0);

  // ---- pool + head ----
  pool_k<<<NGRAPH, 256, 0, stream>>>(hA, gptr, pooled_b);
  mgemm(pooled_b, KPA, g1t, gbuf_b, nullptr, nullptr, g1b, nullptr, nullptr,
        NGRAPH, GW1, KPA, GW1, 1);
  mgemm(gbuf_b, GW1, g2t, nullptr, out, nullptr, g2b, nullptr, nullptr,
        NGRAPH, 128, GW1, 128, 0);
}

// Round 7
// 802.357 us; speedup vs baseline: 5.8874x; 1.1392x over previous
//
#include <hip/hip_runtime.h>
#include <cstdint>
#include <cstddef>

#define NNODES 50000
#define NEDGE0 400000
#define NETOT  450000
#define NGRAPH 1024
#define CH     312
#define HC     624
#define MP     50048     // NNODES padded to 128
#define KPA    320       // CH padded to 64 (slot width, shorts)
#define AST    640       // activation row stride = 2 slots
#define KP0    128       // 78 padded (layer-0 input)
#define NP_HC  640       // HC padded (weight rows; 624..627 = score cols)
#define NFEAT  628       // feature GEMM N (624 h + 4 score cols)
#define GW1    1024      // head fc1 width

typedef __attribute__((ext_vector_type(4))) float f32x4;
typedef __attribute__((ext_vector_type(8))) short s16x8;

__device__ __forceinline__ unsigned short f2bf(float x) {
  union { float f; unsigned u; } v; v.f = x;
  unsigned r = v.u + 0x7fffu + ((v.u >> 16) & 1u);   // RNE
  return (unsigned short)(r >> 16);
}
__device__ __forceinline__ float bf2f(unsigned short u) {
  union { unsigned u; float f; } v; v.u = ((unsigned)u) << 16;
  return v.f;
}
__device__ __forceinline__ void gl_lds16(const unsigned short* g, unsigned short* l) {
  __builtin_amdgcn_global_load_lds(
      (const __attribute__((address_space(1))) unsigned int*)g,
      (__attribute__((address_space(3))) unsigned int*)l, 16, 0, 0);
}

// ============ conversions / weight prep ============
__global__ void cvt0_k(const float* __restrict__ in, unsigned short* __restrict__ out) {
  int i = blockIdx.x * blockDim.x + threadIdx.x;
  if (i >= MP * KP0) return;
  int n = i >> 7, c = i & 127;
  out[i] = (n < NNODES && c < 78) ? f2bf(in[(size_t)n * 78 + c]) : (unsigned short)0;
}

// weights: in f32 [K][N] -> out bf16 [NP_][KP_], transposed, zero-padded
__global__ void tcast_k(const float* __restrict__ in, unsigned short* __restrict__ out,
                        int K, int N, int KP_, int NP_) {
  int i = blockIdx.x * blockDim.x + threadIdx.x;
  if (i >= NP_ * KP_) return;
  int n = i / KP_, k = i - n * KP_;
  out[i] = (n < N && k < K) ? f2bf(in[(size_t)k * N + n]) : (unsigned short)0;
}

// score columns: wt rows 624..627 <- contracted W·a (src h0, src h1, dst h0, dst h1)
__global__ void swfill_k(const float* __restrict__ W, const float* __restrict__ a_s,
                         const float* __restrict__ a_d, unsigned short* __restrict__ wt,
                         int K, int KP_) {
  int tid = blockIdx.x * blockDim.x + threadIdx.x;
  if (tid >= 4 * KP_) return;
  int j = tid / KP_, k = tid - j * KP_;
  int hd = j & 1;
  const float* a = (j < 2) ? a_s : a_d;
  float s = 0.f;
  if (k < K)
    for (int c = 0; c < CH; ++c)
      s += W[(size_t)k * HC + hd * CH + c] * a[hd * CH + c];
  wt[(size_t)(HC + j) * KP_ + k] = f2bf(s);
}

// stacked [fc1;fc2] -> fc12t[384][640] bf16 transposed
__global__ void tcast2_k(const float* __restrict__ fc1, const float* __restrict__ fc2,
                         unsigned short* __restrict__ out) {
  int i = blockIdx.x * blockDim.x + threadIdx.x;
  if (i >= 384 * AST) return;
  int n = i / AST, k = i - n * AST;
  float v = 0.f;
  if (n < CH) {
    if (k < CH) v = fc1[(size_t)k * CH + n];
    else if (k >= KPA && k - KPA < CH) v = fc2[(size_t)(k - KPA) * CH + n];
  }
  out[i] = f2bf(v);
}

__global__ void gbias_k(const float* __restrict__ b1, const float* __restrict__ b2,
                        const float* __restrict__ mb, float* __restrict__ gb) {
  int c = blockIdx.x * blockDim.x + threadIdx.x;
  if (c >= KPA) return;
  gb[c] = (c < CH) ? (b1[c] + b2[c] + mb[c]) : 0.f;
}

// ============ MFMA GEMM with fused epilogues ============
// BM=128 BN=64 BK=64, 4 waves (each 32 rows x 64 cols), 48KB LDS -> 3 blocks/CU.
// Depth-2 counted-vmcnt pipeline (no vmcnt(0) drain in steady state), raw barriers.
// 1D grid + bijective XCD chunk swizzle.
__global__ __launch_bounds__(256) void gemm_bb(
    const unsigned short* __restrict__ A, int lda,
    const unsigned short* __restrict__ Bt,
    unsigned short* __restrict__ Cb, float* __restrict__ Cf,
    float* __restrict__ Sc, const float* __restrict__ bias,
    const unsigned short* __restrict__ Xg, const unsigned short* __restrict__ Hg,
    int M, int N, int KP_, int ldc, int act, int gx)
{
  // ---- XCD-bijective block swizzle (m204) ----
  const int nwg = gridDim.x, orig = blockIdx.x;
  const int q = nwg >> 3, r = nwg & 7;
  const int xcd = orig & 7, loc = orig >> 3;
  const int swz = (xcd < r ? xcd * (q + 1) : r * (q + 1) + (xcd - r) * q) + loc;
  const int bn = (swz % gx) * 64, bm = (swz / gx) * 128;

  __shared__ unsigned short As[2][128 * 64];
  __shared__ unsigned short Bs[2][64 * 64];
  const int tid = threadIdx.x, lane = tid & 63, w = tid >> 6;
  const int rr = lane >> 3;
  const int cc8 = (lane & 7) ^ rr;

  const int nkt = KP_ >> 6;

  // stage k-tile kt into buffer b: 6 gload_lds per thread (4 A + 2 B)
  auto stage = [&](int b, int kt) {
    #pragma unroll
    for (int i = 0; i < 4; ++i) {
      int R = w * 32 + i * 8;
      gl_lds16(A + (size_t)(bm + R + rr) * lda + kt * 64 + cc8 * 8, &As[b][R * 64]);
    }
    #pragma unroll
    for (int i = 0; i < 2; ++i) {
      int R = w * 16 + i * 8;
      gl_lds16(Bt + (size_t)(bn + R + rr) * KP_ + kt * 64 + cc8 * 8, &Bs[b][R * 64]);
    }
  };

  const int r16 = lane & 15, g4 = lane >> 4;
  f32x4 zf = {0.f, 0.f, 0.f, 0.f};
  f32x4 acc[2][4];
  #pragma unroll
  for (int m = 0; m < 2; ++m)
    #pragma unroll
    for (int n = 0; n < 4; ++n) acc[m][n] = zf;

  stage(0, 0);
  stage(1, 1);
  int buf = 0;
  for (int kt = 0; kt < nkt; ++kt) {
    if (kt == nkt - 1) asm volatile("s_waitcnt vmcnt(0)" ::: "memory");
    else               asm volatile("s_waitcnt vmcnt(6)" ::: "memory");
    __builtin_amdgcn_s_barrier();              // buf[kt] visible to all waves
    #pragma unroll
    for (int k2 = 0; k2 < 2; ++k2) {
      s16x8 bfr[4], afr[2];
      #pragma unroll
      for (int n = 0; n < 4; ++n) {
        int rB = n * 16 + r16;
        int ch = (k2 * 4 + g4) ^ (rB & 7);
        bfr[n] = *(const s16x8*)&Bs[buf][rB * 64 + ch * 8];
      }
      #pragma unroll
      for (int m = 0; m < 2; ++m) {
        int rA = w * 32 + m * 16 + r16;
        int ch = (k2 * 4 + g4) ^ (rA & 7);
        afr[m] = *(const s16x8*)&As[buf][rA * 64 + ch * 8];
      }
      __builtin_amdgcn_s_setprio(1);
      #pragma unroll
      for (int m = 0; m < 2; ++m)
        #pragma unroll
        for (int n = 0; n < 4; ++n)
          acc[m][n] = __builtin_amdgcn_mfma_f32_16x16x32_bf16(afr[m], bfr[n],
                                                              acc[m][n], 0, 0, 0);
      __builtin_amdgcn_s_setprio(0);
    }
    __builtin_amdgcn_s_barrier();              // all waves done reading buf
    if (kt + 2 < nkt) stage(buf, kt + 2);      // overwrite safely, loads fly on
    buf ^= 1;
  }

  #pragma unroll
  for (int m = 0; m < 2; ++m) {
    int gm0 = bm + w * 32 + m * 16 + g4 * 4;
    #pragma unroll
    for (int n = 0; n < 4; ++n) {
      int gn = bn + n * 16 + r16;
      if (gn >= N) continue;
      float bv = bias ? bias[gn] : 0.f;
      #pragma unroll
      for (int r2 = 0; r2 < 4; ++r2) {
        int gm = gm0 + r2;
        if (gm >= M) continue;
        float v = acc[m][n][r2];
        if (Sc && gn >= HC) { Sc[(size_t)gm * 4 + (gn - HC)] = v; continue; }
        v += bv;
        if (Xg) {
          float g = 1.f / (1.f + __expf(-v));
          float xv = bf2f(Xg[(size_t)gm * ldc + gn]);
          float hv = bf2f(Hg[(size_t)gm * ldc + gn]);
          Cb[(size_t)gm * ldc + gn] = f2bf(g * xv + (1.f - g) * hv);
        } else {
          if (act) v = v > 0.f ? v : 0.f;
          if (Cb) Cb[(size_t)gm * ldc + gn] = f2bf(v);
          else    Cf[(size_t)gm * ldc + gn] = v;
        }
      }
    }
  }
}

// ============ CSR build ============
__global__ void hist_k(const int* __restrict__ ei, int* __restrict__ cnt) {
  int e = blockIdx.x * blockDim.x + threadIdx.x;
  if (e >= NETOT) return;
  int d = (e < NEDGE0) ? ei[NEDGE0 + e] : e - NEDGE0;
  atomicAdd(&cnt[d], 1);
}

__global__ __launch_bounds__(1024) void scan_k(const int* __restrict__ cnt,
                                               int* __restrict__ rowptr) {
  __shared__ int wsum[16];
  __shared__ int carry_s;
  int t = threadIdx.x, lane = t & 63, wv = t >> 6;
  if (t == 0) carry_s = 0;
  __syncthreads();
  for (int base = 0; base < NNODES; base += 1024) {
    int idx = base + t;
    int v = (idx < NNODES) ? cnt[idx] : 0;
    int s = v;
    #pragma unroll
    for (int off = 1; off < 64; off <<= 1) {
      int x = __shfl_up(s, off);
      if (lane >= off) s += x;
    }
    if (lane == 63) wsum[wv] = s;
    __syncthreads();
    if (wv == 0) {
      int ws = (lane < 16) ? wsum[lane] : 0;
      #pragma unroll
      for (int off = 1; off < 16; off <<= 1) {
        int x = __shfl_up(ws, off);
        if (lane >= off) ws += x;
      }
      if (lane < 16) wsum[lane] = ws;
    }
    __syncthreads();
    int carry = carry_s;
    int woff = wv ? wsum[wv - 1] : 0;
    if (idx < NNODES) rowptr[idx] = carry + woff + s - v;
    __syncthreads();
    if (t == 1023) carry_s = carry + wsum[15];
    __syncthreads();
  }
  if (t == 0) rowptr[NNODES] = carry_s;
}

__global__ void scatter_k(const int* __restrict__ ei, const int* __restrict__ rowptr,
                          int* __restrict__ cur, int* __restrict__ esrc) {
  int e = blockIdx.x * blockDim.x + threadIdx.x;
  if (e >= NETOT) return;
  int s, d;
  if (e < NEDGE0) { s = ei[e]; d = ei[NEDGE0 + e]; }
  else { s = d = e - NEDGE0; }
  int pos = rowptr[d] + atomicAdd(&cur[d], 1);
  esrc[pos] = s;
}

// ============ fused edge softmax + gather (wave per node) ============
__global__ __launch_bounds__(256) void msgcsr_k(
    const int* __restrict__ rowptr, const int* __restrict__ esrc,
    const float* __restrict__ Sc, const unsigned short* __restrict__ h,
    const float* __restrict__ bias, int act, unsigned short* __restrict__ out)
{
  int wid = (blockIdx.x * blockDim.x + threadIdx.x) >> 6;
  int lane = threadIdx.x & 63;
  if (wid >= NNODES) return;
  int e0 = rowptr[wid], e1 = rowptr[wid + 1];
  float sd0 = Sc[(size_t)wid * 4 + 2], sd1 = Sc[(size_t)wid * 4 + 3];

  const int  j1   = lane;
  const bool j1h1 = (j1 >= 39);
  const int  j2   = 64 + (lane < 14 ? lane : 13);
  const bool j2on = (lane < 14);

  float f1[8] = {0,0,0,0,0,0,0,0};
  float f2[8] = {0,0,0,0,0,0,0,0};
  float m0 = -1e30f, m1 = -1e30f, z0 = 0.f, z1 = 0.f;

  for (int base = e0; base < e1; base += 64) {
    int cnt = e1 - base; if (cnt > 64) cnt = 64;
    int sl = 0;
    float a0 = -1e30f, a1 = -1e30f;
    if (lane < cnt) {
      sl = esrc[base + lane];
      f32x4 sv = *(const f32x4*)(Sc + (size_t)sl * 4);
      a0 = sv[0] + sd0; a0 = a0 > 0.f ? a0 : 0.2f * a0;
      a1 = sv[1] + sd1; a1 = a1 > 0.f ? a1 : 0.2f * a1;
    }
    float cm0 = a0, cm1 = a1;
    #pragma unroll
    for (int off = 32; off; off >>= 1) {
      cm0 = fmaxf(cm0, __shfl_xor(cm0, off));
      cm1 = fmaxf(cm1, __shfl_xor(cm1, off));
    }
    float nm0 = fmaxf(m0, cm0), nm1 = fmaxf(m1, cm1);
    float r0 = __expf(m0 - nm0), r1 = __expf(m1 - nm1);
    z0 *= r0; z1 *= r1;
    float rA = j1h1 ? r1 : r0;
    #pragma unroll
    for (int r = 0; r < 8; ++r) { f1[r] *= rA; f2[r] *= r1; }
    m0 = nm0; m1 = nm1;

    float w0 = (lane < cnt) ? __expf(a0 - nm0) : 0.f;
    float w1 = (lane < cnt) ? __expf(a1 - nm1) : 0.f;
    float cz0 = w0, cz1 = w1;
    #pragma unroll
    for (int off = 32; off; off >>= 1) {
      cz0 += __shfl_xor(cz0, off);
      cz1 += __shfl_xor(cz1, off);
    }
    z0 += cz0; z1 += cz1;

    for (int e = 0; e < cnt; ++e) {
      int   s   = __shfl(sl, e);
      float we0 = __shfl(w0, e), we1 = __shfl(w1, e);
      const unsigned short* hp = h + (size_t)s * HC;
      s16x8 c1 = *(const s16x8*)(hp + j1 * 8);
      s16x8 c2 = *(const s16x8*)(hp + j2 * 8);
      float wa = j1h1 ? we1 : we0;
      float wb = j2on ? we1 : 0.f;
      #pragma unroll
      for (int r = 0; r < 8; ++r) {
        f1[r] += wa * bf2f((unsigned short)c1[r]);
        f2[r] += wb * bf2f((unsigned short)c2[r]);
      }
    }
  }

  float i0 = 0.5f / (z0 + 1e-16f), i1 = 0.5f / (z1 + 1e-16f);
  float sA = j1h1 ? i1 : i0;
  #pragma unroll
  for (int r = 0; r < 8; ++r) { f1[r] *= sA; f2[r] *= i1; }

  float vout[8];
  #pragma unroll
  for (int r = 0; r < 8; ++r) {
    float p1 = __shfl(f1[r], lane + 39);
    float p2 = __shfl(f2[r], lane - 25);
    vout[r] = f1[r] + ((lane < 25) ? p1 : p2);
  }
  s16x8 res;
  if (lane < 39) {
    #pragma unroll
    for (int r = 0; r < 8; ++r) {
      float v = vout[r] + bias[lane * 8 + r];
      if (act) v = v > 0.f ? v : 0.f;
      res[r] = (short)f2bf(v);
    }
  } else {
    #pragma unroll
    for (int r = 0; r < 8; ++r) res[r] = 0;
  }
  if (lane < 40)
    *(s16x8*)(out + (size_t)wid * AST + lane * 8) = res;
}

// ============ pooling (sorted batch -> graph ranges) ============
__global__ void gptr_k(const int* __restrict__ batch, int* __restrict__ gptr) {
  int g = blockIdx.x * blockDim.x + threadIdx.x;
  if (g > NGRAPH) return;
  int lo = 0, hi = NNODES;
  while (lo < hi) { int mid = (lo + hi) >> 1; if (batch[mid] < g) lo = mid + 1; else hi = mid; }
  gptr[g] = lo;
}

__global__ __launch_bounds__(256) void pool_k(const unsigned short* __restrict__ hs,
                                              const int* __restrict__ gptr,
                                              unsigned short* __restrict__ pooled) {
  int g = blockIdx.x;
  int n0 = gptr[g], n1 = gptr[g + 1];
  float inv = (n1 > n0) ? 1.f / (float)(n1 - n0) : 0.f;
  for (int c = threadIdx.x; c < KPA; c += 256) {
    float s = 0.f;
    if (c < CH)
      for (int n = n0; n < n1; ++n) s += bf2f(hs[(size_t)n * AST + c]);
    pooled[(size_t)g * KPA + c] = f2bf(s * inv);
  }
}

extern "C" void kernel_launch(void* const* d_in, const int* in_sizes, int n_in,
                              void* d_out, int out_size, void* d_ws, size_t ws_size,
                              hipStream_t stream)
{
  const float* mol_x = (const float*)d_in[0];
  const int*   ei    = (const int*)d_in[1];
  const int*   batch = (const int*)d_in[2];
  const float* W0  = (const float*)d_in[3];
  const float* as0 = (const float*)d_in[4];
  const float* ad0 = (const float*)d_in[5];
  const float* b0  = (const float*)d_in[6];
  const float* W1  = (const float*)d_in[7];
  const float* as1 = (const float*)d_in[8];
  const float* ad1 = (const float*)d_in[9];
  const float* b1  = (const float*)d_in[10];
  const float* W2  = (const float*)d_in[11];
  const float* as2 = (const float*)d_in[12];
  const float* ad2 = (const float*)d_in[13];
  const float* b2  = (const float*)d_in[14];
  const float* fc1w = (const float*)d_in[15];
  const float* fc1b = (const float*)d_in[16];
  const float* fc2w = (const float*)d_in[17];
  const float* fc2b = (const float*)d_in[18];
  const float* mbias = (const float*)d_in[19];
  const float* g1w = (const float*)d_in[20];
  const float* g1b = (const float*)d_in[21];
  const float* g2w = (const float*)d_in[22];
  const float* g2b = (const float*)d_in[23];
  float* out = (float*)d_out;

  char* ws = (char*)d_ws;
  size_t off = 0;
  auto alloc = [&](size_t b) { size_t r = off; off += (b + 255) & ~(size_t)255; return r; };
  unsigned short* h_b  = (unsigned short*)(ws + alloc((size_t)NNODES * HC * 2));
  unsigned short* actA = (unsigned short*)(ws + alloc((size_t)MP * AST * 2));
  unsigned short* actB = (unsigned short*)(ws + alloc((size_t)MP * AST * 2));
  unsigned short* xb0  = (unsigned short*)(ws + alloc((size_t)MP * KP0 * 2));
  float* Sc     = (float*)(ws + alloc((size_t)MP * 4 * 4));
  int*   cnt    = (int*)(ws + alloc((size_t)NNODES * 4));
  int*   cnt2   = (int*)(ws + alloc((size_t)NNODES * 4));
  int*   rowptr = (int*)(ws + alloc((size_t)(NNODES + 1) * 4));
  int*   esrc   = (int*)(ws + alloc((size_t)NETOT * 4));
  int*   gptr   = (int*)(ws + alloc((size_t)(NGRAPH + 1) * 4));
  float* gbias  = (float*)(ws + alloc((size_t)KPA * 4));
  unsigned short* pooled_b = (unsigned short*)(ws + alloc((size_t)NGRAPH * KPA * 2));
  unsigned short* gbuf_b   = (unsigned short*)(ws + alloc((size_t)NGRAPH * GW1 * 2));
  unsigned short* w0t   = (unsigned short*)(ws + alloc((size_t)NP_HC * KP0 * 2));
  unsigned short* w1t   = (unsigned short*)(ws + alloc((size_t)NP_HC * KPA * 2));
  unsigned short* w2t   = (unsigned short*)(ws + alloc((size_t)NP_HC * KPA * 2));
  unsigned short* fc12t = (unsigned short*)(ws + alloc((size_t)384 * AST * 2));
  unsigned short* g1t   = (unsigned short*)(ws + alloc((size_t)GW1 * KPA * 2));
  unsigned short* g2t   = (unsigned short*)(ws + alloc((size_t)128 * GW1 * 2));

  // ---- pre-pass ----
  hipMemsetAsync(cnt, 0, (size_t)NNODES * 4, stream);
  hipMemsetAsync(cnt2, 0, (size_t)NNODES * 4, stream);
  hist_k<<<(NETOT + 255) / 256, 256, 0, stream>>>(ei, cnt);
  scan_k<<<1, 1024, 0, stream>>>(cnt, rowptr);
  scatter_k<<<(NETOT + 255) / 256, 256, 0, stream>>>(ei, rowptr, cnt2, esrc);
  gptr_k<<<(NGRAPH + 256) / 256, 256, 0, stream>>>(batch, gptr);
  cvt0_k<<<(MP * KP0 + 255) / 256, 256, 0, stream>>>(mol_x, xb0);
  tcast_k<<<(NP_HC * KP0 + 255) / 256, 256, 0, stream>>>(W0, w0t, 78, HC, KP0, NP_HC);
  tcast_k<<<(NP_HC * KPA + 255) / 256, 256, 0, stream>>>(W1, w1t, CH, HC, KPA, NP_HC);
  tcast_k<<<(NP_HC * KPA + 255) / 256, 256, 0, stream>>>(W2, w2t, CH, HC, KPA, NP_HC);
  swfill_k<<<(4 * KP0 + 255) / 256, 256, 0, stream>>>(W0, as0, ad0, w0t, 78, KP0);
  swfill_k<<<(4 * KPA + 255) / 256, 256, 0, stream>>>(W1, as1, ad1, w1t, CH, KPA);
  swfill_k<<<(4 * KPA + 255) / 256, 256, 0, stream>>>(W2, as2, ad2, w2t, CH, KPA);
  tcast2_k<<<(384 * AST + 255) / 256, 256, 0, stream>>>(fc1w, fc2w, fc12t);
  gbias_k<<<2, 256, 0, stream>>>(fc1b, fc2b, mbias, gbias);
  tcast_k<<<(GW1 * KPA + 255) / 256, 256, 0, stream>>>(g1w, g1t, CH, GW1, KPA, GW1);
  tcast_k<<<(128 * GW1 + 255) / 256, 256, 0, stream>>>(g2w, g2t, GW1, 128, GW1, 128);

  auto mgemm = [&](const unsigned short* A, int lda, const unsigned short* Bt,
                   unsigned short* Cb, float* Cf, float* Sc_, const float* bias,
                   const unsigned short* Xg, const unsigned short* Hg,
                   int M, int N, int KP_, int ldc, int act) {
    int gx = (N + 63) / 64, gy = (M + 127) / 128;
    hipLaunchKernelGGL(gemm_bb, dim3(gx * gy), dim3(256), 0, stream, A, lda, Bt,
                       Cb, Cf, Sc_, bias, Xg, Hg, M, N, KP_, ldc, act, gx);
  };

  const int MSGB = (NNODES * 64 + 255) / 256;
  unsigned short* hA = actA + KPA;
  unsigned short* hB = actB + KPA;

  // ---- layer 0 ----
  mgemm(xb0, KP0, w0t, h_b, nullptr, Sc, nullptr, nullptr, nullptr,
        NNODES, NFEAT, KP0, HC, 0);
  msgcsr_k<<<MSGB, 256, 0, stream>>>(rowptr, esrc, Sc, h_b, b0, 1, hA);

  // ---- layer 1 ----
  mgemm(hA, AST, w1t, h_b, nullptr, Sc, nullptr, nullptr, nullptr,
        NNODES, NFEAT, KPA, HC, 0);
  msgcsr_k<<<MSGB, 256, 0, stream>>>(rowptr, esrc, Sc, h_b, b1, 1, actA);
  mgemm(actA, AST, fc12t, hB, nullptr, nullptr, gbias, actA, hA,
        NNODES, KPA, AST, AST, 0);

  // ---- layer 2 ----
  mgemm(hB, AST, w2t, h_b, nullptr, Sc, nullptr, nullptr, nullptr,
        NNODES, NFEAT, KPA, HC, 0);
  msgcsr_k<<<MSGB, 256, 0, stream>>>(rowptr, esrc, Sc, h_b, b2, 0, actB);
  mgemm(actB, AST, fc12t, hA, nullptr, nullptr, gbias, actB, hB,
        NNODES, KPA, AST, AST, 0);

  // ---- pool + head ----
  pool_k<<<NGRAPH, 256, 0, stream>>>(hA, gptr, pooled_b);
  mgemm(pooled_b, KPA, g1t, gbuf_b, nullptr, nullptr, g1b, nullptr, nullptr,
        NGRAPH, GW1, KPA, GW1, 1);
  mgemm(gbuf_b, GW1, g2t, nullptr, out, nullptr, g2b, nullptr, nullptr,
        NGRAPH, 128, GW1, 128, 0);
}

// Round 9
// 799.273 us; speedup vs baseline: 5.9101x; 1.0039x over previous
//
#include <hip/hip_runtime.h>
#include <cstdint>
#include <cstddef>

#define NNODES 50000
#define NEDGE0 400000
#define NETOT  450000
#define NGRAPH 1024
#define CH     312
#define HC     624
#define MP     50048     // NNODES padded to 128
#define KPA    320       // CH padded to 64 (slot width, shorts)
#define AST    640       // activation row stride = 2 slots
#define KP0    128       // 78 padded (layer-0 input)
#define NP_HC  640       // HC padded (weight rows; 624..627 = score cols)
#define NFEAT  628       // feature GEMM N (624 h + 4 score cols)
#define GW1    1024      // head fc1 width

typedef __attribute__((ext_vector_type(4))) float f32x4;
typedef __attribute__((ext_vector_type(8))) short s16x8;
typedef __attribute__((ext_vector_type(4))) short s16x4;
typedef _Float16 f16x2 __attribute__((ext_vector_type(2)));
typedef _Float16 f16x8 __attribute__((ext_vector_type(8)));
typedef decltype(__builtin_amdgcn_cvt_pkrtz(0.f, 0.f)) pk16x2;

__device__ __forceinline__ unsigned short f2bf(float x) {
  union { float f; unsigned u; } v; v.f = x;
  unsigned r = v.u + 0x7fffu + ((v.u >> 16) & 1u);   // RNE
  return (unsigned short)(r >> 16);
}
__device__ __forceinline__ float bf2f(unsigned short u) {
  union { unsigned u; float f; } v; v.u = ((unsigned)u) << 16;
  return v.f;
}
__device__ __forceinline__ void gl_lds16(const unsigned short* g, unsigned short* l) {
  __builtin_amdgcn_global_load_lds(
      (const __attribute__((address_space(1))) unsigned int*)g,
      (__attribute__((address_space(3))) unsigned int*)l, 16, 0, 0);
}

// ============ conversions / weight prep ============
__global__ void cvt0_k(const float* __restrict__ in, unsigned short* __restrict__ out) {
  int i = blockIdx.x * blockDim.x + threadIdx.x;
  if (i >= MP * KP0) return;
  int n = i >> 7, c = i & 127;
  out[i] = (n < NNODES && c < 78) ? f2bf(in[(size_t)n * 78 + c]) : (unsigned short)0;
}

// weights: in f32 [K][N] -> out bf16 [NP_][KP_], transposed, zero-padded
__global__ void tcast_k(const float* __restrict__ in, unsigned short* __restrict__ out,
                        int K, int N, int KP_, int NP_) {
  int i = blockIdx.x * blockDim.x + threadIdx.x;
  if (i >= NP_ * KP_) return;
  int n = i / KP_, k = i - n * KP_;
  out[i] = (n < N && k < K) ? f2bf(in[(size_t)k * N + n]) : (unsigned short)0;
}

// score columns: wt rows 624..627 <- contracted W·a (src h0, src h1, dst h0, dst h1)
__global__ void swfill_k(const float* __restrict__ W, const float* __restrict__ a_s,
                         const float* __restrict__ a_d, unsigned short* __restrict__ wt,
                         int K, int KP_) {
  int tid = blockIdx.x * blockDim.x + threadIdx.x;
  if (tid >= 4 * KP_) return;
  int j = tid / KP_, k = tid - j * KP_;
  int hd = j & 1;
  const float* a = (j < 2) ? a_s : a_d;
  float s = 0.f;
  if (k < K)
    for (int c = 0; c < CH; ++c)
      s += W[(size_t)k * HC + hd * CH + c] * a[hd * CH + c];
  wt[(size_t)(HC + j) * KP_ + k] = f2bf(s);
}

// stacked [fc1;fc2] -> fc12t[384][640] bf16 transposed
__global__ void tcast2_k(const float* __restrict__ fc1, const float* __restrict__ fc2,
                         unsigned short* __restrict__ out) {
  int i = blockIdx.x * blockDim.x + threadIdx.x;
  if (i >= 384 * AST) return;
  int n = i / AST, k = i - n * AST;
  float v = 0.f;
  if (n < CH) {
    if (k < CH) v = fc1[(size_t)k * CH + n];
    else if (k >= KPA && k - KPA < CH) v = fc2[(size_t)(k - KPA) * CH + n];
  }
  out[i] = f2bf(v);
}

__global__ void gbias_k(const float* __restrict__ b1, const float* __restrict__ b2,
                        const float* __restrict__ mb, float* __restrict__ gb) {
  int c = blockIdx.x * blockDim.x + threadIdx.x;
  if (c >= KPA) return;
  gb[c] = (c < CH) ? (b1[c] + b2[c] + mb[c]) : 0.f;
}

// ============ MFMA GEMM with fused epilogues ============
// BM=128 BN=64 BK=64, 4 waves, 48KB LDS -> 3 blocks/CU, depth-2 counted-vmcnt
// pipeline, raw barriers, XCD-bijective swizzle.
// ilv=1: write Cb as f16, head-interleaved (pos = gn<312 ? 2gn : 2(gn-312)+1).
__global__ __launch_bounds__(256) void gemm_bb(
    const unsigned short* __restrict__ A, int lda,
    const unsigned short* __restrict__ Bt,
    unsigned short* __restrict__ Cb, float* __restrict__ Cf,
    float* __restrict__ Sc, const float* __restrict__ bias,
    const unsigned short* __restrict__ Xg, const unsigned short* __restrict__ Hg,
    int M, int N, int KP_, int ldc, int act, int gx, int ilv)
{
  const int nwg = gridDim.x, orig = blockIdx.x;
  const int q = nwg >> 3, r = nwg & 7;
  const int xcd = orig & 7, loc = orig >> 3;
  const int swz = (xcd < r ? xcd * (q + 1) : r * (q + 1) + (xcd - r) * q) + loc;
  const int bn = (swz % gx) * 64, bm = (swz / gx) * 128;

  __shared__ unsigned short As[2][128 * 64];
  __shared__ unsigned short Bs[2][64 * 64];
  const int tid = threadIdx.x, lane = tid & 63, w = tid >> 6;
  const int rr = lane >> 3;
  const int cc8 = (lane & 7) ^ rr;

  const int nkt = KP_ >> 6;

  auto stage = [&](int b, int kt) {
    #pragma unroll
    for (int i = 0; i < 4; ++i) {
      int R = w * 32 + i * 8;
      gl_lds16(A + (size_t)(bm + R + rr) * lda + kt * 64 + cc8 * 8, &As[b][R * 64]);
    }
    #pragma unroll
    for (int i = 0; i < 2; ++i) {
      int R = w * 16 + i * 8;
      gl_lds16(Bt + (size_t)(bn + R + rr) * KP_ + kt * 64 + cc8 * 8, &Bs[b][R * 64]);
    }
  };

  const int r16 = lane & 15, g4 = lane >> 4;
  f32x4 zf = {0.f, 0.f, 0.f, 0.f};
  f32x4 acc[2][4];
  #pragma unroll
  for (int m = 0; m < 2; ++m)
    #pragma unroll
    for (int n = 0; n < 4; ++n) acc[m][n] = zf;

  stage(0, 0);
  stage(1, 1);
  int buf = 0;
  for (int kt = 0; kt < nkt; ++kt) {
    if (kt == nkt - 1) asm volatile("s_waitcnt vmcnt(0)" ::: "memory");
    else               asm volatile("s_waitcnt vmcnt(6)" ::: "memory");
    __builtin_amdgcn_s_barrier();
    #pragma unroll
    for (int k2 = 0; k2 < 2; ++k2) {
      s16x8 bfr[4], afr[2];
      #pragma unroll
      for (int n = 0; n < 4; ++n) {
        int rB = n * 16 + r16;
        int ch = (k2 * 4 + g4) ^ (rB & 7);
        bfr[n] = *(const s16x8*)&Bs[buf][rB * 64 + ch * 8];
      }
      #pragma unroll
      for (int m = 0; m < 2; ++m) {
        int rA = w * 32 + m * 16 + r16;
        int ch = (k2 * 4 + g4) ^ (rA & 7);
        afr[m] = *(const s16x8*)&As[buf][rA * 64 + ch * 8];
      }
      __builtin_amdgcn_s_setprio(1);
      #pragma unroll
      for (int m = 0; m < 2; ++m)
        #pragma unroll
        for (int n = 0; n < 4; ++n)
          acc[m][n] = __builtin_amdgcn_mfma_f32_16x16x32_bf16(afr[m], bfr[n],
                                                              acc[m][n], 0, 0, 0);
      __builtin_amdgcn_s_setprio(0);
    }
    __builtin_amdgcn_s_barrier();
    if (kt + 2 < nkt) stage(buf, kt + 2);
    buf ^= 1;
  }

  #pragma unroll
  for (int m = 0; m < 2; ++m) {
    int gm0 = bm + w * 32 + m * 16 + g4 * 4;
    #pragma unroll
    for (int n = 0; n < 4; ++n) {
      int gn = bn + n * 16 + r16;
      if (gn >= N) continue;
      float bv = bias ? bias[gn] : 0.f;
      #pragma unroll
      for (int r2 = 0; r2 < 4; ++r2) {
        int gm = gm0 + r2;
        if (gm >= M) continue;
        float v = acc[m][n][r2];
        if (Sc && gn >= HC) { Sc[(size_t)gm * 4 + (gn - HC)] = v; continue; }
        v += bv;
        if (Xg) {
          float g = 1.f / (1.f + __expf(-v));
          float xv = bf2f(Xg[(size_t)gm * ldc + gn]);
          float hv = bf2f(Hg[(size_t)gm * ldc + gn]);
          Cb[(size_t)gm * ldc + gn] = f2bf(g * xv + (1.f - g) * hv);
        } else if (ilv) {
          int pos = (gn < CH) ? 2 * gn : 2 * (gn - CH) + 1;
          union { _Float16 h; unsigned short u; } cv;
          cv.h = (_Float16)v;
          Cb[(size_t)gm * ldc + pos] = cv.u;
        } else {
          if (act) v = v > 0.f ? v : 0.f;
          if (Cb) Cb[(size_t)gm * ldc + gn] = f2bf(v);
          else    Cf[(size_t)gm * ldc + gn] = v;
        }
      }
    }
  }
}

// ============ CSR build ============
__global__ void hist_k(const int* __restrict__ ei, int* __restrict__ cnt) {
  int e = blockIdx.x * blockDim.x + threadIdx.x;
  if (e >= NETOT) return;
  int d = (e < NEDGE0) ? ei[NEDGE0 + e] : e - NEDGE0;
  atomicAdd(&cnt[d], 1);
}

__global__ __launch_bounds__(1024) void scan_k(const int* __restrict__ cnt,
                                               int* __restrict__ rowptr) {
  __shared__ int wsum[16];
  __shared__ int carry_s;
  int t = threadIdx.x, lane = t & 63, wv = t >> 6;
  if (t == 0) carry_s = 0;
  __syncthreads();
  for (int base = 0; base < NNODES; base += 1024) {
    int idx = base + t;
    int v = (idx < NNODES) ? cnt[idx] : 0;
    int s = v;
    #pragma unroll
    for (int off = 1; off < 64; off <<= 1) {
      int x = __shfl_up(s, off);
      if (lane >= off) s += x;
    }
    if (lane == 63) wsum[wv] = s;
    __syncthreads();
    if (wv == 0) {
      int ws = (lane < 16) ? wsum[lane] : 0;
      #pragma unroll
      for (int off = 1; off < 16; off <<= 1) {
        int x = __shfl_up(ws, off);
        if (lane >= off) ws += x;
      }
      if (lane < 16) wsum[lane] = ws;
    }
    __syncthreads();
    int carry = carry_s;
    int woff = wv ? wsum[wv - 1] : 0;
    if (idx < NNODES) rowptr[idx] = carry + woff + s - v;
    __syncthreads();
    if (t == 1023) carry_s = carry + wsum[15];
    __syncthreads();
  }
  if (t == 0) rowptr[NNODES] = carry_s;
}

__global__ void scatter_k(const int* __restrict__ ei, const int* __restrict__ rowptr,
                          int* __restrict__ cur, int* __restrict__ esrc) {
  int e = blockIdx.x * blockDim.x + threadIdx.x;
  if (e >= NETOT) return;
  int s, d;
  if (e < NEDGE0) { s = ei[e]; d = ei[NEDGE0 + e]; }
  else { s = d = e - NEDGE0; }
  int pos = rowptr[d] + atomicAdd(&cur[d], 1);
  esrc[pos] = s;
}

// ============ fused edge softmax + gather (wave per node, fdot2) ============
// h is f16 head-interleaved [n][624]; out bf16 x-slot [n][KPA] (stride AST).
__global__ __launch_bounds__(256) void msg2_k(
    const int* __restrict__ rowptr, const int* __restrict__ esrc,
    const float* __restrict__ Sc, const _Float16* __restrict__ h,
    const float* __restrict__ bias, int act, unsigned short* __restrict__ out)
{
  int wid = (blockIdx.x * blockDim.x + threadIdx.x) >> 6;
  int lane = threadIdx.x & 63;
  if (wid >= NNODES) return;
  int e0 = rowptr[wid], e1 = rowptr[wid + 1];
  float sd0 = Sc[(size_t)wid * 4 + 2], sd1 = Sc[(size_t)wid * 4 + 3];

  // ---- phase 1: exact per-head max & sum ----
  float m0 = -1e30f, m1 = -1e30f, z0 = 0.f, z1 = 0.f;
  for (int base = e0; base < e1; base += 64) {
    int cnt = e1 - base; if (cnt > 64) cnt = 64;
    float a0 = -1e30f, a1 = -1e30f;
    if (lane < cnt) {
      int sl = esrc[base + lane];
      f32x4 sv = *(const f32x4*)(Sc + (size_t)sl * 4);
      a0 = sv[0] + sd0; a0 = a0 > 0.f ? a0 : 0.2f * a0;
      a1 = sv[1] + sd1; a1 = a1 > 0.f ? a1 : 0.2f * a1;
    }
    float cm0 = a0, cm1 = a1;
    #pragma unroll
    for (int off = 32; off; off >>= 1) {
      cm0 = fmaxf(cm0, __shfl_xor(cm0, off));
      cm1 = fmaxf(cm1, __shfl_xor(cm1, off));
    }
    float nm0 = fmaxf(m0, cm0), nm1 = fmaxf(m1, cm1);
    z0 *= __expf(m0 - nm0); z1 *= __expf(m1 - nm1);
    m0 = nm0; m1 = nm1;
    float w0 = (lane < cnt) ? __expf(a0 - m0) : 0.f;
    float w1 = (lane < cnt) ? __expf(a1 - m1) : 0.f;
    #pragma unroll
    for (int off = 32; off; off >>= 1) {
      w0 += __shfl_xor(w0, off);
      w1 += __shfl_xor(w1, off);
    }
    z0 += w0; z1 += w1;
  }
  float i0 = 0.5f / (z0 + 1e-16f), i1 = 0.5f / (z1 + 1e-16f);

  const int  j1   = lane;                          // chunk 0..63 (4 ch pairs)
  const int  j2   = 64 + (lane < 14 ? lane : 13);  // chunks 64..77
  const bool j2on = (lane < 14);

  float f1[4] = {0, 0, 0, 0};
  float f2[4] = {0, 0, 0, 0};

  // ---- phase 2: final coefs + packed-dot gather ----
  for (int base = e0; base < e1; base += 64) {
    int cnt = e1 - base; if (cnt > 64) cnt = 64;
    int sl = 0, cpi = 0;
    if (lane < cnt) {
      sl = esrc[base + lane];
      f32x4 sv = *(const f32x4*)(Sc + (size_t)sl * 4);
      float a0 = sv[0] + sd0; a0 = a0 > 0.f ? a0 : 0.2f * a0;
      float a1 = sv[1] + sd1; a1 = a1 > 0.f ? a1 : 0.2f * a1;
      float c0 = __expf(a0 - m0) * i0;
      float c1 = __expf(a1 - m1) * i1;
      union { pk16x2 h2; int i; } u;
      u.h2 = __builtin_amdgcn_cvt_pkrtz(c0, c1);
      cpi = u.i;
    }
    for (int e = 0; e < cnt; ++e) {
      int s  = __shfl(sl, e);
      int cb = __shfl(cpi, e);
      union { int i; f16x2 h2; } uc; uc.i = cb;
      f16x2 cp  = uc.h2;
      f16x2 cp2 = j2on ? cp : (f16x2)(_Float16)0;
      const _Float16* hp = h + (size_t)s * HC;
      union { f16x8 v8; f16x2 v2[4]; } ua, ub;
      ua.v8 = *(const f16x8*)(hp + j1 * 8);
      ub.v8 = *(const f16x8*)(hp + j2 * 8);
      #pragma unroll
      for (int r = 0; r < 4; ++r) {
        f1[r] = __builtin_amdgcn_fdot2(ua.v2[r], cp,  f1[r], false);
        f2[r] = __builtin_amdgcn_fdot2(ub.v2[r], cp2, f2[r], false);
      }
    }
  }

  // ---- epilogue: bias + act + pack bf16 ----
  unsigned short* op = out + (size_t)wid * AST;
  {
    f32x4 bv = *(const f32x4*)(bias + j1 * 4);
    s16x4 r4;
    #pragma unroll
    for (int r = 0; r < 4; ++r) {
      float v = f1[r] + bv[r];
      if (act) v = v > 0.f ? v : 0.f;
      r4[r] = (short)f2bf(v);
    }
    *(s16x4*)(op + j1 * 4) = r4;
  }
  if (lane < 16) {
    s16x4 q4 = {0, 0, 0, 0};
    if (j2on) {
      f32x4 bv = *(const f32x4*)(bias + j2 * 4);
      #pragma unroll
      for (int r = 0; r < 4; ++r) {
        float v = f2[r] + bv[r];
        if (act) v = v > 0.f ? v : 0.f;
        q4[r] = (short)f2bf(v);
      }
    }
    *(s16x4*)(op + 256 + lane * 4) = q4;
  }
}

// ============ pooling (sorted batch -> graph ranges) ============
__global__ void gptr_k(const int* __restrict__ batch, int* __restrict__ gptr) {
  int g = blockIdx.x * blockDim.x + threadIdx.x;
  if (g > NGRAPH) return;
  int lo = 0, hi = NNODES;
  while (lo < hi) { int mid = (lo + hi) >> 1; if (batch[mid] < g) lo = mid + 1; else hi = mid; }
  gptr[g] = lo;
}

__global__ __launch_bounds__(256) void pool_k(const unsigned short* __restrict__ hs,
                                              const int* __restrict__ gptr,
                                              unsigned short* __restrict__ pooled) {
  int g = blockIdx.x;
  int n0 = gptr[g], n1 = gptr[g + 1];
  float inv = (n1 > n0) ? 1.f / (float)(n1 - n0) : 0.f;
  for (int c = threadIdx.x; c < KPA; c += 256) {
    float s = 0.f;
    if (c < CH)
      for (int n = n0; n < n1; ++n) s += bf2f(hs[(size_t)n * AST + c]);
    pooled[(size_t)g * KPA + c] = f2bf(s * inv);
  }
}

extern "C" void kernel_launch(void* const* d_in, const int* in_sizes, int n_in,
                              void* d_out, int out_size, void* d_ws, size_t ws_size,
                              hipStream_t stream)
{
  const float* mol_x = (const float*)d_in[0];
  const int*   ei    = (const int*)d_in[1];
  const int*   batch = (const int*)d_in[2];
  const float* W0  = (const float*)d_in[3];
  const float* as0 = (const float*)d_in[4];
  const float* ad0 = (const float*)d_in[5];
  const float* b0  = (const float*)d_in[6];
  const float* W1  = (const float*)d_in[7];
  const float* as1 = (const float*)d_in[8];
  const float* ad1 = (const float*)d_in[9];
  const float* b1  = (const float*)d_in[10];
  const float* W2  = (const float*)d_in[11];
  const float* as2 = (const float*)d_in[12];
  const float* ad2 = (const float*)d_in[13];
  const float* b2  = (const float*)d_in[14];
  const float* fc1w = (const float*)d_in[15];
  const float* fc1b = (const float*)d_in[16];
  const float* fc2w = (const float*)d_in[17];
  const float* fc2b = (const float*)d_in[18];
  const float* mbias = (const float*)d_in[19];
  const float* g1w = (const float*)d_in[20];
  const float* g1b = (const float*)d_in[21];
  const float* g2w = (const float*)d_in[22];
  const float* g2b = (const float*)d_in[23];
  float* out = (float*)d_out;

  char* ws = (char*)d_ws;
  size_t off = 0;
  auto alloc = [&](size_t b) { size_t r = off; off += (b + 255) & ~(size_t)255; return r; };
  unsigned short* h_b  = (unsigned short*)(ws + alloc((size_t)NNODES * HC * 2));
  unsigned short* actA = (unsigned short*)(ws + alloc((size_t)MP * AST * 2));
  unsigned short* actB = (unsigned short*)(ws + alloc((size_t)MP * AST * 2));
  unsigned short* xb0  = (unsigned short*)(ws + alloc((size_t)MP * KP0 * 2));
  float* Sc     = (float*)(ws + alloc((size_t)MP * 4 * 4));
  int*   cnt    = (int*)(ws + alloc((size_t)NNODES * 4));
  int*   cnt2   = (int*)(ws + alloc((size_t)NNODES * 4));
  int*   rowptr = (int*)(ws + alloc((size_t)(NNODES + 1) * 4));
  int*   esrc   = (int*)(ws + alloc((size_t)NETOT * 4));
  int*   gptr   = (int*)(ws + alloc((size_t)(NGRAPH + 1) * 4));
  float* gbias  = (float*)(ws + alloc((size_t)KPA * 4));
  unsigned short* pooled_b = (unsigned short*)(ws + alloc((size_t)NGRAPH * KPA * 2));
  unsigned short* gbuf_b   = (unsigned short*)(ws + alloc((size_t)NGRAPH * GW1 * 2));
  unsigned short* w0t   = (unsigned short*)(ws + alloc((size_t)NP_HC * KP0 * 2));
  unsigned short* w1t   = (unsigned short*)(ws + alloc((size_t)NP_HC * KPA * 2));
  unsigned short* w2t   = (unsigned short*)(ws + alloc((size_t)NP_HC * KPA * 2));
  unsigned short* fc12t = (unsigned short*)(ws + alloc((size_t)384 * AST * 2));
  unsigned short* g1t   = (unsigned short*)(ws + alloc((size_t)GW1 * KPA * 2));
  unsigned short* g2t   = (unsigned short*)(ws + alloc((size_t)128 * GW1 * 2));

  // ---- pre-pass ----
  hipMemsetAsync(cnt, 0, (size_t)NNODES * 4, stream);
  hipMemsetAsync(cnt2, 0, (size_t)NNODES * 4, stream);
  hist_k<<<(NETOT + 255) / 256, 256, 0, stream>>>(ei, cnt);
  scan_k<<<1, 1024, 0, stream>>>(cnt, rowptr);
  scatter_k<<<(NETOT + 255) / 256, 256, 0, stream>>>(ei, rowptr, cnt2, esrc);
  gptr_k<<<(NGRAPH + 256) / 256, 256, 0, stream>>>(batch, gptr);
  cvt0_k<<<(MP * KP0 + 255) / 256, 256, 0, stream>>>(mol_x, xb0);
  tcast_k<<<(NP_HC * KP0 + 255) / 256, 256, 0, stream>>>(W0, w0t, 78, HC, KP0, NP_HC);
  tcast_k<<<(NP_HC * KPA + 255) / 256, 256, 0, stream>>>(W1, w1t, CH, HC, KPA, NP_HC);
  tcast_k<<<(NP_HC * KPA + 255) / 256, 256, 0, stream>>>(W2, w2t, CH, HC, KPA, NP_HC);
  swfill_k<<<(4 * KP0 + 255) / 256, 256, 0, stream>>>(W0, as0, ad0, w0t, 78, KP0);
  swfill_k<<<(4 * KPA + 255) / 256, 256, 0, stream>>>(W1, as1, ad1, w1t, CH, KPA);
  swfill_k<<<(4 * KPA + 255) / 256, 256, 0, stream>>>(W2, as2, ad2, w2t, CH, KPA);
  tcast2_k<<<(384 * AST + 255) / 256, 256, 0, stream>>>(fc1w, fc2w, fc12t);
  gbias_k<<<2, 256, 0, stream>>>(fc1b, fc2b, mbias, gbias);
  tcast_k<<<(GW1 * KPA + 255) / 256, 256, 0, stream>>>(g1w, g1t, CH, GW1, KPA, GW1);
  tcast_k<<<(128 * GW1 + 255) / 256, 256, 0, stream>>>(g2w, g2t, GW1, 128, GW1, 128);

  auto mgemm = [&](const unsigned short* A, int lda, const unsigned short* Bt,
                   unsigned short* Cb, float* Cf, float* Sc_, const float* bias,
                   const unsigned short* Xg, const unsigned short* Hg,
                   int M, int N, int KP_, int ldc, int act, int ilv) {
    int gx = (N + 63) / 64, gy = (M + 127) / 128;
    hipLaunchKernelGGL(gemm_bb, dim3(gx * gy), dim3(256), 0, stream, A, lda, Bt,
                       Cb, Cf, Sc_, bias, Xg, Hg, M, N, KP_, ldc, act, gx, ilv);
  };

  const int MSGB = (NNODES * 64 + 255) / 256;
  unsigned short* hA = actA + KPA;
  unsigned short* hB = actB + KPA;
  const _Float16* h_f = (const _Float16*)h_b;

  // ---- layer 0 ----
  mgemm(xb0, KP0, w0t, h_b, nullptr, Sc, nullptr, nullptr, nullptr,
        NNODES, NFEAT, KP0, HC, 0, 1);
  msg2_k<<<MSGB, 256, 0, stream>>>(rowptr, esrc, Sc, h_f, b0, 1, hA);

  // ---- layer 1 ----
  mgemm(hA, AST, w1t, h_b, nullptr, Sc, nullptr, nullptr, nullptr,
        NNODES, NFEAT, KPA, HC, 0, 1);
  msg2_k<<<MSGB, 256, 0, stream>>>(rowptr, esrc, Sc, h_f, b1, 1, actA);
  mgemm(actA, AST, fc12t, hB, nullptr, nullptr, gbias, actA, hA,
        NNODES, KPA, AST, AST, 0, 0);

  // ---- layer 2 ----
  mgemm(hB, AST, w2t, h_b, nullptr, Sc, nullptr, nullptr, nullptr,
        NNODES, NFEAT, KPA, HC, 0, 1);
  msg2_k<<<MSGB, 256, 0, stream>>>(rowptr, esrc, Sc, h_f, b2, 0, actB);
  mgemm(actB, AST, fc12t, hA, nullptr, nullptr, gbias, actB, hB,
        NNODES, KPA, AST, AST, 0, 0);

  // ---- pool + head ----
  pool_k<<<NGRAPH, 256, 0, stream>>>(hA, gptr, pooled_b);
  mgemm(pooled_b, KPA, g1t, gbuf_b, nullptr, nullptr, g1b, nullptr, nullptr,
        NGRAPH, GW1, KPA, GW1, 1, 0);
  mgemm(gbuf_b, GW1, g2t, nullptr, out, nullptr, g2b, nullptr, nullptr,
        NGRAPH, 128, GW1, 128, 0, 0);
}

// Round 10
// 698.363 us; speedup vs baseline: 6.7641x; 1.1445x over previous
//
#include <hip/hip_runtime.h>
#include <cstdint>
#include <cstddef>

#define NNODES 50000
#define NEDGE0 400000
#define NETOT  450000
#define NGRAPH 1024
#define CH     312
#define HC     624
#define MP     50048     // NNODES padded to 128
#define KPA    320       // CH padded to 64 (slot width, shorts)
#define AST    640       // activation row stride = 2 slots
#define KP0    128       // 78 padded (layer-0 input)
#define GW1    1024      // head fc1 width

typedef __attribute__((ext_vector_type(4))) float f32x4;
typedef __attribute__((ext_vector_type(8))) short s16x8;

__device__ __forceinline__ unsigned short f2bf(float x) {
  union { float f; unsigned u; } v; v.f = x;
  unsigned r = v.u + 0x7fffu + ((v.u >> 16) & 1u);   // RNE
  return (unsigned short)(r >> 16);
}
__device__ __forceinline__ float bf2f(unsigned short u) {
  union { unsigned u; float f; } v; v.u = ((unsigned)u) << 16;
  return v.f;
}
__device__ __forceinline__ void gl_lds16(const unsigned short* g, unsigned short* l) {
  __builtin_amdgcn_global_load_lds(
      (const __attribute__((address_space(1))) unsigned int*)g,
      (__attribute__((address_space(3))) unsigned int*)l, 16, 0, 0);
}

// ============ conversions / weight prep ============
__global__ void cvt0_k(const float* __restrict__ in, unsigned short* __restrict__ out) {
  int i = blockIdx.x * blockDim.x + threadIdx.x;
  if (i >= MP * KP0) return;
  int n = i >> 7, c = i & 127;
  out[i] = (n < NNODES && c < 78) ? f2bf(in[(size_t)n * 78 + c]) : (unsigned short)0;
}

// generic transpose+cast: in f32 [K][N] -> out bf16 [NP_][KP_] (head GEMM weights)
__global__ void tcast_k(const float* __restrict__ in, unsigned short* __restrict__ out,
                        int K, int N, int KP_, int NP_) {
  int i = blockIdx.x * blockDim.x + threadIdx.x;
  if (i >= NP_ * KP_) return;
  int n = i / KP_, k = i - n * KP_;
  out[i] = (n < N && k < K) ? f2bf(in[(size_t)k * N + n]) : (unsigned short)0;
}

// combined head-stacked weight: out[384][2*KX] = 0.5 * [W_h0 ; W_h1] transposed
__global__ void combcast_k(const float* __restrict__ W, unsigned short* __restrict__ out,
                           int K, int KX) {
  int i = blockIdx.x * blockDim.x + threadIdx.x;
  int W2 = 2 * KX;
  if (i >= 384 * W2) return;
  int n = i / W2, k = i - n * W2;
  float v = 0.f;
  if (n < CH) {
    int hd = (k >= KX) ? 1 : 0;
    int kk = hd ? k - KX : k;
    if (kk < K) v = 0.5f * W[(size_t)kk * HC + hd * CH + n];
  }
  out[i] = f2bf(v);
}

// score weight vectors: wa[4][KX] f32 = contracted W·a (src h0, src h1, dst h0, dst h1)
__global__ void wafill_k(const float* __restrict__ W, const float* __restrict__ a_s,
                         const float* __restrict__ a_d, float* __restrict__ wa,
                         int K, int KX) {
  int tid = blockIdx.x * blockDim.x + threadIdx.x;
  if (tid >= 4 * KX) return;
  int j = tid / KX, k = tid - j * KX;
  int hd = j & 1;
  const float* a = (j < 2) ? a_s : a_d;
  float s = 0.f;
  if (k < K)
    for (int c = 0; c < CH; ++c)
      s += W[(size_t)k * HC + hd * CH + c] * a[hd * CH + c];
  wa[j * KX + k] = s;
}

// stacked [fc1;fc2] -> fc12t[384][640] bf16 transposed
__global__ void tcast2_k(const float* __restrict__ fc1, const float* __restrict__ fc2,
                         unsigned short* __restrict__ out) {
  int i = blockIdx.x * blockDim.x + threadIdx.x;
  if (i >= 384 * AST) return;
  int n = i / AST, k = i - n * AST;
  float v = 0.f;
  if (n < CH) {
    if (k < CH) v = fc1[(size_t)k * CH + n];
    else if (k >= KPA && k - KPA < CH) v = fc2[(size_t)(k - KPA) * CH + n];
  }
  out[i] = f2bf(v);
}

__global__ void gbias_k(const float* __restrict__ b1, const float* __restrict__ b2,
                        const float* __restrict__ mb, float* __restrict__ gb) {
  int c = blockIdx.x * blockDim.x + threadIdx.x;
  if (c >= KPA) return;
  gb[c] = (c < CH) ? (b1[c] + b2[c] + mb[c]) : 0.f;
}

__global__ void bpad_k(const float* __restrict__ b, float* __restrict__ bp) {
  int c = blockIdx.x * blockDim.x + threadIdx.x;
  if (c >= KPA) return;
  bp[c] = (c < CH) ? b[c] : 0.f;
}

// ============ MFMA GEMM with fused epilogues ============
// BM=128 BN=64 BK=64, 4 waves, 48KB LDS -> 3 blocks/CU, depth-2 counted-vmcnt
// pipeline, raw barriers, XCD-bijective swizzle. Gate epilogue optional.
__global__ __launch_bounds__(256) void gemm_bb(
    const unsigned short* __restrict__ A, int lda,
    const unsigned short* __restrict__ Bt,
    unsigned short* __restrict__ Cb, float* __restrict__ Cf,
    const float* __restrict__ bias,
    const unsigned short* __restrict__ Xg, const unsigned short* __restrict__ Hg,
    int M, int N, int KP_, int ldc, int act, int gx)
{
  const int nwg = gridDim.x, orig = blockIdx.x;
  const int q = nwg >> 3, r = nwg & 7;
  const int xcd = orig & 7, loc = orig >> 3;
  const int swz = (xcd < r ? xcd * (q + 1) : r * (q + 1) + (xcd - r) * q) + loc;
  const int bn = (swz % gx) * 64, bm = (swz / gx) * 128;

  __shared__ unsigned short As[2][128 * 64];
  __shared__ unsigned short Bs[2][64 * 64];
  const int tid = threadIdx.x, lane = tid & 63, w = tid >> 6;
  const int rr = lane >> 3;
  const int cc8 = (lane & 7) ^ rr;

  const int nkt = KP_ >> 6;

  auto stage = [&](int b, int kt) {
    #pragma unroll
    for (int i = 0; i < 4; ++i) {
      int R = w * 32 + i * 8;
      gl_lds16(A + (size_t)(bm + R + rr) * lda + kt * 64 + cc8 * 8, &As[b][R * 64]);
    }
    #pragma unroll
    for (int i = 0; i < 2; ++i) {
      int R = w * 16 + i * 8;
      gl_lds16(Bt + (size_t)(bn + R + rr) * KP_ + kt * 64 + cc8 * 8, &Bs[b][R * 64]);
    }
  };

  const int r16 = lane & 15, g4 = lane >> 4;
  f32x4 zf = {0.f, 0.f, 0.f, 0.f};
  f32x4 acc[2][4];
  #pragma unroll
  for (int m = 0; m < 2; ++m)
    #pragma unroll
    for (int n = 0; n < 4; ++n) acc[m][n] = zf;

  stage(0, 0);
  stage(1, 1);
  int buf = 0;
  for (int kt = 0; kt < nkt; ++kt) {
    if (kt == nkt - 1) asm volatile("s_waitcnt vmcnt(0)" ::: "memory");
    else               asm volatile("s_waitcnt vmcnt(6)" ::: "memory");
    __builtin_amdgcn_s_barrier();
    #pragma unroll
    for (int k2 = 0; k2 < 2; ++k2) {
      s16x8 bfr[4], afr[2];
      #pragma unroll
      for (int n = 0; n < 4; ++n) {
        int rB = n * 16 + r16;
        int ch = (k2 * 4 + g4) ^ (rB & 7);
        bfr[n] = *(const s16x8*)&Bs[buf][rB * 64 + ch * 8];
      }
      #pragma unroll
      for (int m = 0; m < 2; ++m) {
        int rA = w * 32 + m * 16 + r16;
        int ch = (k2 * 4 + g4) ^ (rA & 7);
        afr[m] = *(const s16x8*)&As[buf][rA * 64 + ch * 8];
      }
      __builtin_amdgcn_s_setprio(1);
      #pragma unroll
      for (int m = 0; m < 2; ++m)
        #pragma unroll
        for (int n = 0; n < 4; ++n)
          acc[m][n] = __builtin_amdgcn_mfma_f32_16x16x32_bf16(afr[m], bfr[n],
                                                              acc[m][n], 0, 0, 0);
      __builtin_amdgcn_s_setprio(0);
    }
    __builtin_amdgcn_s_barrier();
    if (kt + 2 < nkt) stage(buf, kt + 2);
    buf ^= 1;
  }

  #pragma unroll
  for (int m = 0; m < 2; ++m) {
    int gm0 = bm + w * 32 + m * 16 + g4 * 4;
    #pragma unroll
    for (int n = 0; n < 4; ++n) {
      int gn = bn + n * 16 + r16;
      if (gn >= N) continue;
      float bv = bias ? bias[gn] : 0.f;
      #pragma unroll
      for (int r2 = 0; r2 < 4; ++r2) {
        int gm = gm0 + r2;
        if (gm >= M) continue;
        float v = acc[m][n][r2] + bv;
        if (Xg) {
          float g = 1.f / (1.f + __expf(-v));
          float xv = bf2f(Xg[(size_t)gm * ldc + gn]);
          float hv = bf2f(Hg[(size_t)gm * ldc + gn]);
          Cb[(size_t)gm * ldc + gn] = f2bf(g * xv + (1.f - g) * hv);
        } else {
          if (act) v = v > 0.f ? v : 0.f;
          if (Cb) Cb[(size_t)gm * ldc + gn] = f2bf(v);
          else    Cf[(size_t)gm * ldc + gn] = v;
        }
      }
    }
  }
}

// ============ CSR build ============
__global__ void hist_k(const int* __restrict__ ei, int* __restrict__ cnt) {
  int e = blockIdx.x * blockDim.x + threadIdx.x;
  if (e >= NETOT) return;
  int d = (e < NEDGE0) ? ei[NEDGE0 + e] : e - NEDGE0;
  atomicAdd(&cnt[d], 1);
}

__global__ __launch_bounds__(1024) void scan_k(const int* __restrict__ cnt,
                                               int* __restrict__ rowptr) {
  __shared__ int wsum[16];
  __shared__ int carry_s;
  int t = threadIdx.x, lane = t & 63, wv = t >> 6;
  if (t == 0) carry_s = 0;
  __syncthreads();
  for (int base = 0; base < NNODES; base += 1024) {
    int idx = base + t;
    int v = (idx < NNODES) ? cnt[idx] : 0;
    int s = v;
    #pragma unroll
    for (int off = 1; off < 64; off <<= 1) {
      int x = __shfl_up(s, off);
      if (lane >= off) s += x;
    }
    if (lane == 63) wsum[wv] = s;
    __syncthreads();
    if (wv == 0) {
      int ws = (lane < 16) ? wsum[lane] : 0;
      #pragma unroll
      for (int off = 1; off < 16; off <<= 1) {
        int x = __shfl_up(ws, off);
        if (lane >= off) ws += x;
      }
      if (lane < 16) wsum[lane] = ws;
    }
    __syncthreads();
    int carry = carry_s;
    int woff = wv ? wsum[wv - 1] : 0;
    if (idx < NNODES) rowptr[idx] = carry + woff + s - v;
    __syncthreads();
    if (t == 1023) carry_s = carry + wsum[15];
    __syncthreads();
  }
  if (t == 0) rowptr[NNODES] = carry_s;
}

__global__ void scatter_k(const int* __restrict__ ei, const int* __restrict__ rowptr,
                          int* __restrict__ cur, int* __restrict__ esrc) {
  int e = blockIdx.x * blockDim.x + threadIdx.x;
  if (e >= NETOT) return;
  int s, d;
  if (e < NEDGE0) { s = ei[e]; d = ei[NEDGE0 + e]; }
  else { s = d = e - NEDGE0; }
  int pos = rowptr[d] + atomicAdd(&cur[d], 1);
  esrc[pos] = s;
}

// ============ per-node scores: Sc[n][4] = X[n] · wa[j] ============
template<int NCH>
__global__ __launch_bounds__(256) void scoresX_k(
    const unsigned short* __restrict__ X, int stride,
    const float* __restrict__ wa, float* __restrict__ Sc)
{
  int wid = (blockIdx.x * blockDim.x + threadIdx.x) >> 6;
  int lane = threadIdx.x & 63;
  if (wid >= NNODES) return;
  const int K = NCH * 8;
  float d[4] = {0, 0, 0, 0};
  if (lane < NCH) {
    s16x8 xv = *(const s16x8*)(X + (size_t)wid * stride + lane * 8);
    float xf[8];
    #pragma unroll
    for (int r = 0; r < 8; ++r) xf[r] = bf2f((unsigned short)xv[r]);
    #pragma unroll
    for (int j = 0; j < 4; ++j) {
      const float* wp = wa + j * K + lane * 8;
      float s = 0.f;
      #pragma unroll
      for (int r = 0; r < 8; ++r) s += xf[r] * wp[r];
      d[j] = s;
    }
  }
  #pragma unroll
  for (int off = 32; off; off >>= 1) {
    #pragma unroll
    for (int j = 0; j < 4; ++j) d[j] += __shfl_xor(d[j], off);
  }
  if (lane == 0) {
    f32x4 v = {d[0], d[1], d[2], d[3]};
    *(f32x4*)(Sc + (size_t)wid * 4) = v;
  }
}

// ============ fused edge softmax + X-aggregate (wave per node) ============
// Gathers X[src] (NCH 16B-chunks/row) with per-head softmax coefs into
// xagg[n] = [head0 NCH*8 | head1 NCH*8] bf16.
template<int NCH>
__global__ __launch_bounds__(256) void msgX_k(
    const int* __restrict__ rowptr, const int* __restrict__ esrc,
    const float* __restrict__ Sc, const unsigned short* __restrict__ X,
    int stride, unsigned short* __restrict__ xagg)
{
  int wid = (blockIdx.x * blockDim.x + threadIdx.x) >> 6;
  int lane = threadIdx.x & 63;
  if (wid >= NNODES) return;
  int e0 = rowptr[wid], e1 = rowptr[wid + 1];
  float sd0 = Sc[(size_t)wid * 4 + 2], sd1 = Sc[(size_t)wid * 4 + 3];

  // ---- phase 1: exact per-head max & sum ----
  float m0 = -1e30f, m1 = -1e30f, z0 = 0.f, z1 = 0.f;
  for (int base = e0; base < e1; base += 64) {
    int cnt = e1 - base; if (cnt > 64) cnt = 64;
    float a0 = -1e30f, a1 = -1e30f;
    if (lane < cnt) {
      int sl = esrc[base + lane];
      f32x4 sv = *(const f32x4*)(Sc + (size_t)sl * 4);
      a0 = sv[0] + sd0; a0 = a0 > 0.f ? a0 : 0.2f * a0;
      a1 = sv[1] + sd1; a1 = a1 > 0.f ? a1 : 0.2f * a1;
    }
    float cm0 = a0, cm1 = a1;
    #pragma unroll
    for (int off = 32; off; off >>= 1) {
      cm0 = fmaxf(cm0, __shfl_xor(cm0, off));
      cm1 = fmaxf(cm1, __shfl_xor(cm1, off));
    }
    float nm0 = fmaxf(m0, cm0), nm1 = fmaxf(m1, cm1);
    z0 *= __expf(m0 - nm0); z1 *= __expf(m1 - nm1);
    m0 = nm0; m1 = nm1;
    float w0 = (lane < cnt) ? __expf(a0 - m0) : 0.f;
    float w1 = (lane < cnt) ? __expf(a1 - m1) : 0.f;
    #pragma unroll
    for (int off = 32; off; off >>= 1) {
      w0 += __shfl_xor(w0, off);
      w1 += __shfl_xor(w1, off);
    }
    z0 += w0; z1 += w1;
  }
  float i0 = 1.f / (z0 + 1e-16f), i1 = 1.f / (z1 + 1e-16f);

  float a0h[8] = {0,0,0,0,0,0,0,0};
  float a1h[8] = {0,0,0,0,0,0,0,0};

  // ---- phase 2: final coefs + weighted X gather ----
  for (int base = e0; base < e1; base += 64) {
    int cnt = e1 - base; if (cnt > 64) cnt = 64;
    int sl = 0;
    float c0 = 0.f, c1 = 0.f;
    if (lane < cnt) {
      sl = esrc[base + lane];
      f32x4 sv = *(const f32x4*)(Sc + (size_t)sl * 4);
      float a0 = sv[0] + sd0; a0 = a0 > 0.f ? a0 : 0.2f * a0;
      float a1 = sv[1] + sd1; a1 = a1 > 0.f ? a1 : 0.2f * a1;
      c0 = __expf(a0 - m0) * i0;
      c1 = __expf(a1 - m1) * i1;
    }
    if (NCH == 40) {
      for (int e = 0; e < cnt; ++e) {
        int   s  = __shfl(sl, e);
        float w0 = __shfl(c0, e), w1 = __shfl(c1, e);
        if (lane < NCH) {
          s16x8 xv = *(const s16x8*)(X + (size_t)s * stride + lane * 8);
          #pragma unroll
          for (int r = 0; r < 8; ++r) {
            float xf = bf2f((unsigned short)xv[r]);
            a0h[r] += w0 * xf;
            a1h[r] += w1 * xf;
          }
        }
      }
    } else {  // NCH == 16: 4 edges per step, lane = (edge-sub << 4) | chunk
      for (int e = 0; e < cnt; e += 4) {
        int ee = e + (lane >> 4);
        bool on = ee < cnt;
        int   s  = __shfl(sl, on ? ee : e);
        float w0 = __shfl(c0, on ? ee : e), w1 = __shfl(c1, on ? ee : e);
        if (on) {
          s16x8 xv = *(const s16x8*)(X + (size_t)s * stride + (lane & 15) * 8);
          #pragma unroll
          for (int r = 0; r < 8; ++r) {
            float xf = bf2f((unsigned short)xv[r]);
            a0h[r] += w0 * xf;
            a1h[r] += w1 * xf;
          }
        }
      }
    }
  }

  if (NCH == 16) {   // fold the 4 edge-sub groups (lanes l, l+16, l+32, l+48)
    #pragma unroll
    for (int r = 0; r < 8; ++r) {
      a0h[r] += __shfl_xor(a0h[r], 16); a0h[r] += __shfl_xor(a0h[r], 32);
      a1h[r] += __shfl_xor(a1h[r], 16); a1h[r] += __shfl_xor(a1h[r], 32);
    }
  }
  if (lane < NCH) {
    s16x8 o0, o1;
    #pragma unroll
    for (int r = 0; r < 8; ++r) {
      o0[r] = (short)f2bf(a0h[r]);
      o1[r] = (short)f2bf(a1h[r]);
    }
    unsigned short* op = xagg + (size_t)wid * (2 * NCH * 8);
    *(s16x8*)(op + lane * 8) = o0;
    *(s16x8*)(op + NCH * 8 + lane * 8) = o1;
  }
}

// ============ pooling (sorted batch -> graph ranges) ============
__global__ void gptr_k(const int* __restrict__ batch, int* __restrict__ gptr) {
  int g = blockIdx.x * blockDim.x + threadIdx.x;
  if (g > NGRAPH) return;
  int lo = 0, hi = NNODES;
  while (lo < hi) { int mid = (lo + hi) >> 1; if (batch[mid] < g) lo = mid + 1; else hi = mid; }
  gptr[g] = lo;
}

__global__ __launch_bounds__(256) void pool_k(const unsigned short* __restrict__ hs,
                                              const int* __restrict__ gptr,
                                              unsigned short* __restrict__ pooled) {
  int g = blockIdx.x;
  int n0 = gptr[g], n1 = gptr[g + 1];
  float inv = (n1 > n0) ? 1.f / (float)(n1 - n0) : 0.f;
  for (int c = threadIdx.x; c < KPA; c += 256) {
    float s = 0.f;
    if (c < CH)
      for (int n = n0; n < n1; ++n) s += bf2f(hs[(size_t)n * AST + c]);
    pooled[(size_t)g * KPA + c] = f2bf(s * inv);
  }
}

extern "C" void kernel_launch(void* const* d_in, const int* in_sizes, int n_in,
                              void* d_out, int out_size, void* d_ws, size_t ws_size,
                              hipStream_t stream)
{
  const float* mol_x = (const float*)d_in[0];
  const int*   ei    = (const int*)d_in[1];
  const int*   batch = (const int*)d_in[2];
  const float* W0  = (const float*)d_in[3];
  const float* as0 = (const float*)d_in[4];
  const float* ad0 = (const float*)d_in[5];
  const float* b0  = (const float*)d_in[6];
  const float* W1  = (const float*)d_in[7];
  const float* as1 = (const float*)d_in[8];
  const float* ad1 = (const float*)d_in[9];
  const float* b1  = (const float*)d_in[10];
  const float* W2  = (const float*)d_in[11];
  const float* as2 = (const float*)d_in[12];
  const float* ad2 = (const float*)d_in[13];
  const float* b2  = (const float*)d_in[14];
  const float* fc1w = (const float*)d_in[15];
  const float* fc1b = (const float*)d_in[16];
  const float* fc2w = (const float*)d_in[17];
  const float* fc2b = (const float*)d_in[18];
  const float* mbias = (const float*)d_in[19];
  const float* g1w = (const float*)d_in[20];
  const float* g1b = (const float*)d_in[21];
  const float* g2w = (const float*)d_in[22];
  const float* g2b = (const float*)d_in[23];
  float* out = (float*)d_out;

  char* ws = (char*)d_ws;
  size_t off = 0;
  auto alloc = [&](size_t b) { size_t r = off; off += (b + 255) & ~(size_t)255; return r; };
  unsigned short* xagg = (unsigned short*)(ws + alloc((size_t)MP * AST * 2));
  unsigned short* actA = (unsigned short*)(ws + alloc((size_t)MP * AST * 2));
  unsigned short* actB = (unsigned short*)(ws + alloc((size_t)MP * AST * 2));
  unsigned short* xb0  = (unsigned short*)(ws + alloc((size_t)MP * KP0 * 2));
  float* Sc     = (float*)(ws + alloc((size_t)MP * 4 * 4));
  int*   cnt    = (int*)(ws + alloc((size_t)NNODES * 4));
  int*   cnt2   = (int*)(ws + alloc((size_t)NNODES * 4));
  int*   rowptr = (int*)(ws + alloc((size_t)(NNODES + 1) * 4));
  int*   esrc   = (int*)(ws + alloc((size_t)NETOT * 4));
  int*   gptr   = (int*)(ws + alloc((size_t)(NGRAPH + 1) * 4));
  float* gbias  = (float*)(ws + alloc((size_t)KPA * 4));
  float* bp0    = (float*)(ws + alloc((size_t)KPA * 4));
  float* bp1    = (float*)(ws + alloc((size_t)KPA * 4));
  float* bp2    = (float*)(ws + alloc((size_t)KPA * 4));
  float* wa0    = (float*)(ws + alloc((size_t)4 * KP0 * 4));
  float* wa1    = (float*)(ws + alloc((size_t)4 * KPA * 4));
  float* wa2    = (float*)(ws + alloc((size_t)4 * KPA * 4));
  unsigned short* pooled_b = (unsigned short*)(ws + alloc((size_t)NGRAPH * KPA * 2));
  unsigned short* gbuf_b   = (unsigned short*)(ws + alloc((size_t)NGRAPH * GW1 * 2));
  unsigned short* comb0t = (unsigned short*)(ws + alloc((size_t)384 * 256 * 2));
  unsigned short* comb1t = (unsigned short*)(ws + alloc((size_t)384 * AST * 2));
  unsigned short* comb2t = (unsigned short*)(ws + alloc((size_t)384 * AST * 2));
  unsigned short* fc12t  = (unsigned short*)(ws + alloc((size_t)384 * AST * 2));
  unsigned short* g1t    = (unsigned short*)(ws + alloc((size_t)GW1 * KPA * 2));
  unsigned short* g2t    = (unsigned short*)(ws + alloc((size_t)128 * GW1 * 2));

  // ---- pre-pass ----
  hipMemsetAsync(cnt, 0, (size_t)NNODES * 4, stream);
  hipMemsetAsync(cnt2, 0, (size_t)NNODES * 4, stream);
  hist_k<<<(NETOT + 255) / 256, 256, 0, stream>>>(ei, cnt);
  scan_k<<<1, 1024, 0, stream>>>(cnt, rowptr);
  scatter_k<<<(NETOT + 255) / 256, 256, 0, stream>>>(ei, rowptr, cnt2, esrc);
  gptr_k<<<(NGRAPH + 256) / 256, 256, 0, stream>>>(batch, gptr);
  cvt0_k<<<(MP * KP0 + 255) / 256, 256, 0, stream>>>(mol_x, xb0);
  combcast_k<<<(384 * 256 + 255) / 256, 256, 0, stream>>>(W0, comb0t, 78, KP0);
  combcast_k<<<(384 * AST + 255) / 256, 256, 0, stream>>>(W1, comb1t, CH, KPA);
  combcast_k<<<(384 * AST + 255) / 256, 256, 0, stream>>>(W2, comb2t, CH, KPA);
  wafill_k<<<(4 * KP0 + 255) / 256, 256, 0, stream>>>(W0, as0, ad0, wa0, 78, KP0);
  wafill_k<<<(4 * KPA + 255) / 256, 256, 0, stream>>>(W1, as1, ad1, wa1, CH, KPA);
  wafill_k<<<(4 * KPA + 255) / 256, 256, 0, stream>>>(W2, as2, ad2, wa2, CH, KPA);
  tcast2_k<<<(384 * AST + 255) / 256, 256, 0, stream>>>(fc1w, fc2w, fc12t);
  gbias_k<<<2, 256, 0, stream>>>(fc1b, fc2b, mbias, gbias);
  bpad_k<<<2, 256, 0, stream>>>(b0, bp0);
  bpad_k<<<2, 256, 0, stream>>>(b1, bp1);
  bpad_k<<<2, 256, 0, stream>>>(b2, bp2);
  tcast_k<<<(GW1 * KPA + 255) / 256, 256, 0, stream>>>(g1w, g1t, CH, GW1, KPA, GW1);
  tcast_k<<<(128 * GW1 + 255) / 256, 256, 0, stream>>>(g2w, g2t, GW1, 128, GW1, 128);

  auto mgemm = [&](const unsigned short* A, int lda, const unsigned short* Bt,
                   unsigned short* Cb, float* Cf, const float* bias,
                   const unsigned short* Xg, const unsigned short* Hg,
                   int M, int N, int KP_, int ldc, int act) {
    int gx = (N + 63) / 64, gy = (M + 127) / 128;
    hipLaunchKernelGGL(gemm_bb, dim3(gx * gy), dim3(256), 0, stream, A, lda, Bt,
                       Cb, Cf, bias, Xg, Hg, M, N, KP_, ldc, act, gx);
  };

  const int MSGB = (NNODES * 64 + 255) / 256;
  unsigned short* hA = actA + KPA;   // h-slot of actA
  unsigned short* hB = actB + KPA;   // h-slot of actB

  // ---- layer 0: scores on xb0 -> aggregate X -> combined GEMM -> hA ----
  scoresX_k<16><<<MSGB, 256, 0, stream>>>(xb0, KP0, wa0, Sc);
  msgX_k<16><<<MSGB, 256, 0, stream>>>(rowptr, esrc, Sc, xb0, KP0, xagg);
  mgemm(xagg, 256, comb0t, hA, nullptr, bp0, nullptr, nullptr,
        NNODES, KPA, 256, AST, 1);

  // ---- layer 1 ----
  scoresX_k<40><<<MSGB, 256, 0, stream>>>(hA, AST, wa1, Sc);
  msgX_k<40><<<MSGB, 256, 0, stream>>>(rowptr, esrc, Sc, hA, AST, xagg);
  mgemm(xagg, AST, comb1t, actA, nullptr, bp1, nullptr, nullptr,
        NNODES, KPA, AST, AST, 1);                       // x-slot of actA
  mgemm(actA, AST, fc12t, hB, nullptr, gbias, actA, hA,
        NNODES, KPA, AST, AST, 0);                       // gate -> hB

  // ---- layer 2 ----
  scoresX_k<40><<<MSGB, 256, 0, stream>>>(hB, AST, wa2, Sc);
  msgX_k<40><<<MSGB, 256, 0, stream>>>(rowptr, esrc, Sc, hB, AST, xagg);
  mgemm(xagg, AST, comb2t, actB, nullptr, bp2, nullptr, nullptr,
        NNODES, KPA, AST, AST, 0);                       // x-slot of actB (no relu)
  mgemm(actB, AST, fc12t, hA, nullptr, gbias, actB, hB,
        NNODES, KPA, AST, AST, 0);                       // gate -> hA

  // ---- pool + head ----
  pool_k<<<NGRAPH, 256, 0, stream>>>(hA, gptr, pooled_b);
  mgemm(pooled_b, KPA, g1t, gbuf_b, nullptr, g1b, nullptr, nullptr,
        NGRAPH, GW1, KPA, GW1, 1);
  mgemm(gbuf_b, GW1, g2t, nullptr, out, g2b, nullptr, nullptr,
        NGRAPH, 128, GW1, 128, 0);
}

// Round 11
// 601.672 us; speedup vs baseline: 7.8511x; 1.1607x over previous
//
#include <hip/hip_runtime.h>
#include <cstdint>
#include <cstddef>

#define NNODES 50000
#define NEDGE0 400000
#define NETOT  450000
#define NGRAPH 1024
#define CH     312
#define HC     624
#define MP     50048     // NNODES padded to 128
#define KPA    320       // CH padded to 64 (slot width, shorts)
#define AST    640       // activation row stride = 2 slots
#define KP0    128       // 78 padded (layer-0 input)
#define GW1    1024      // head fc1 width

typedef __attribute__((ext_vector_type(4))) float f32x4;
typedef __attribute__((ext_vector_type(8))) short s16x8;

__device__ __forceinline__ unsigned short f2bf(float x) {
  union { float f; unsigned u; } v; v.f = x;
  unsigned r = v.u + 0x7fffu + ((v.u >> 16) & 1u);   // RNE
  return (unsigned short)(r >> 16);
}
__device__ __forceinline__ float bf2f(unsigned short u) {
  union { unsigned u; float f; } v; v.u = ((unsigned)u) << 16;
  return v.f;
}
__device__ __forceinline__ void gl_lds16(const unsigned short* g, unsigned short* l) {
  __builtin_amdgcn_global_load_lds(
      (const __attribute__((address_space(1))) unsigned int*)g,
      (__attribute__((address_space(3))) unsigned int*)l, 16, 0, 0);
}

// ============ conversions / weight prep ============
__global__ void cvt0_k(const float* __restrict__ in, unsigned short* __restrict__ out) {
  int i = blockIdx.x * blockDim.x + threadIdx.x;
  if (i >= MP * KP0) return;
  int n = i >> 7, c = i & 127;
  out[i] = (n < NNODES && c < 78) ? f2bf(in[(size_t)n * 78 + c]) : (unsigned short)0;
}

// generic transpose+cast: in f32 [K][N] -> out bf16 [NP_][KP_] (head GEMM weights)
__global__ void tcast_k(const float* __restrict__ in, unsigned short* __restrict__ out,
                        int K, int N, int KP_, int NP_) {
  int i = blockIdx.x * blockDim.x + threadIdx.x;
  if (i >= NP_ * KP_) return;
  int n = i / KP_, k = i - n * KP_;
  out[i] = (n < N && k < K) ? f2bf(in[(size_t)k * N + n]) : (unsigned short)0;
}

// combined head-stacked weight: out[384][2*KX] = 0.5 * [W_h0 ; W_h1] transposed
__global__ void combcast_k(const float* __restrict__ W, unsigned short* __restrict__ out,
                           int K, int KX) {
  int i = blockIdx.x * blockDim.x + threadIdx.x;
  int W2 = 2 * KX;
  if (i >= 384 * W2) return;
  int n = i / W2, k = i - n * W2;
  float v = 0.f;
  if (n < CH) {
    int hd = (k >= KX) ? 1 : 0;
    int kk = hd ? k - KX : k;
    if (kk < K) v = 0.5f * W[(size_t)kk * HC + hd * CH + n];
  }
  out[i] = f2bf(v);
}

// score weight vectors: wa[4][KX] f32 = contracted W·a (src h0, src h1, dst h0, dst h1)
__global__ void wafill_k(const float* __restrict__ W, const float* __restrict__ a_s,
                         const float* __restrict__ a_d, float* __restrict__ wa,
                         int K, int KX) {
  int tid = blockIdx.x * blockDim.x + threadIdx.x;
  if (tid >= 4 * KX) return;
  int j = tid / KX, k = tid - j * KX;
  int hd = j & 1;
  const float* a = (j < 2) ? a_s : a_d;
  float s = 0.f;
  if (k < K)
    for (int c = 0; c < CH; ++c)
      s += W[(size_t)k * HC + hd * CH + c] * a[hd * CH + c];
  wa[j * KX + k] = s;
}

// stacked [fc1;fc2] -> fc12t[384][640] bf16 transposed
__global__ void tcast2_k(const float* __restrict__ fc1, const float* __restrict__ fc2,
                         unsigned short* __restrict__ out) {
  int i = blockIdx.x * blockDim.x + threadIdx.x;
  if (i >= 384 * AST) return;
  int n = i / AST, k = i - n * AST;
  float v = 0.f;
  if (n < CH) {
    if (k < CH) v = fc1[(size_t)k * CH + n];
    else if (k >= KPA && k - KPA < CH) v = fc2[(size_t)(k - KPA) * CH + n];
  }
  out[i] = f2bf(v);
}

// merged bias prep: bp0/bp1/bp2 (padded) + gbias
__global__ void biasprep_k(const float* __restrict__ b0_, const float* __restrict__ b1_,
                           const float* __restrict__ b2_, const float* __restrict__ fc1b,
                           const float* __restrict__ fc2b, const float* __restrict__ mb,
                           float* __restrict__ bp0, float* __restrict__ bp1,
                           float* __restrict__ bp2, float* __restrict__ gb) {
  int i = blockIdx.x * blockDim.x + threadIdx.x;
  if (i >= 4 * KPA) return;
  int seg = i / KPA, c = i - seg * KPA;
  bool in = c < CH;
  if (seg == 0)      bp0[c] = in ? b0_[c] : 0.f;
  else if (seg == 1) bp1[c] = in ? b1_[c] : 0.f;
  else if (seg == 2) bp2[c] = in ? b2_[c] : 0.f;
  else               gb[c]  = in ? (fc1b[c] + fc2b[c] + mb[c]) : 0.f;
}

// ============ MFMA GEMM with fused epilogues ============
// BM=128 BN=64 BK=64, 4 waves, 48KB LDS -> 3 blocks/CU, depth-2 counted-vmcnt
// pipeline, raw barriers, XCD-bijective swizzle.
// Epilogue: acc -> LDS f32 [128][68] (aliases staging LDS) -> coalesced 16B stores;
// gate (Xg/Hg) reads are contiguous s16x8 in the copy-out layout.
__global__ __launch_bounds__(256) void gemm_bb(
    const unsigned short* __restrict__ A, int lda,
    const unsigned short* __restrict__ Bt,
    unsigned short* __restrict__ Cb, float* __restrict__ Cf,
    const float* __restrict__ bias,
    const unsigned short* __restrict__ Xg, const unsigned short* __restrict__ Hg,
    int M, int N, int KP_, int ldc, int act, int gx)
{
  const int nwg = gridDim.x, orig = blockIdx.x;
  const int q = nwg >> 3, r = nwg & 7;
  const int xcd = orig & 7, loc = orig >> 3;
  const int swz = (xcd < r ? xcd * (q + 1) : r * (q + 1) + (xcd - r) * q) + loc;
  const int bn = (swz % gx) * 64, bm = (swz / gx) * 128;

  __shared__ __align__(16) char smem[49152];
  unsigned short* As = (unsigned short*)smem;            // [2][128*64]
  unsigned short* Bs = (unsigned short*)(smem + 32768);  // [2][64*64]
  const int tid = threadIdx.x, lane = tid & 63, w = tid >> 6;
  const int rr = lane >> 3;
  const int cc8 = (lane & 7) ^ rr;

  const int nkt = KP_ >> 6;

  auto stage = [&](int b, int kt) {
    #pragma unroll
    for (int i = 0; i < 4; ++i) {
      int R = w * 32 + i * 8;
      gl_lds16(A + (size_t)(bm + R + rr) * lda + kt * 64 + cc8 * 8,
               As + b * 8192 + R * 64);
    }
    #pragma unroll
    for (int i = 0; i < 2; ++i) {
      int R = w * 16 + i * 8;
      gl_lds16(Bt + (size_t)(bn + R + rr) * KP_ + kt * 64 + cc8 * 8,
               Bs + b * 4096 + R * 64);
    }
  };

  const int r16 = lane & 15, g4 = lane >> 4;
  f32x4 zf = {0.f, 0.f, 0.f, 0.f};
  f32x4 acc[2][4];
  #pragma unroll
  for (int m = 0; m < 2; ++m)
    #pragma unroll
    for (int n = 0; n < 4; ++n) acc[m][n] = zf;

  stage(0, 0);
  stage(1, 1);
  int buf = 0;
  for (int kt = 0; kt < nkt; ++kt) {
    if (kt == nkt - 1) asm volatile("s_waitcnt vmcnt(0)" ::: "memory");
    else               asm volatile("s_waitcnt vmcnt(6)" ::: "memory");
    __builtin_amdgcn_s_barrier();
    #pragma unroll
    for (int k2 = 0; k2 < 2; ++k2) {
      s16x8 bfr[4], afr[2];
      #pragma unroll
      for (int n = 0; n < 4; ++n) {
        int rB = n * 16 + r16;
        int ch = (k2 * 4 + g4) ^ (rB & 7);
        bfr[n] = *(const s16x8*)&Bs[buf * 4096 + rB * 64 + ch * 8];
      }
      #pragma unroll
      for (int m = 0; m < 2; ++m) {
        int rA = w * 32 + m * 16 + r16;
        int ch = (k2 * 4 + g4) ^ (rA & 7);
        afr[m] = *(const s16x8*)&As[buf * 8192 + rA * 64 + ch * 8];
      }
      __builtin_amdgcn_s_setprio(1);
      #pragma unroll
      for (int m = 0; m < 2; ++m)
        #pragma unroll
        for (int n = 0; n < 4; ++n)
          acc[m][n] = __builtin_amdgcn_mfma_f32_16x16x32_bf16(afr[m], bfr[n],
                                                              acc[m][n], 0, 0, 0);
      __builtin_amdgcn_s_setprio(0);
    }
    __builtin_amdgcn_s_barrier();
    if (kt + 2 < nkt) stage(buf, kt + 2);
    buf ^= 1;
  }

  // ---- epilogue: acc -> LDS f32 (aliases As/Bs, all reads done) ----
  float* Ct = (float*)smem;                  // [128][68]
  #pragma unroll
  for (int m = 0; m < 2; ++m) {
    int row0 = w * 32 + m * 16 + g4 * 4;
    #pragma unroll
    for (int n = 0; n < 4; ++n) {
      int col = n * 16 + r16;
      #pragma unroll
      for (int r2 = 0; r2 < 4; ++r2)
        Ct[(row0 + r2) * 68 + col] = acc[m][n][r2];
    }
  }
  __builtin_amdgcn_s_barrier();

  if (Cf) {
    for (int c = tid; c < 128 * 16; c += 256) {
      int row = c >> 4, c4 = (c & 15) * 4;
      int gm = bm + row, gn = bn + c4;
      if (gm >= M) continue;
      f32x4 v;
      #pragma unroll
      for (int rj = 0; rj < 4; ++rj) {
        float x = Ct[row * 68 + c4 + rj] + bias[gn + rj];
        if (act) x = x > 0.f ? x : 0.f;
        v[rj] = x;
      }
      *(f32x4*)(Cf + (size_t)gm * ldc + gn) = v;
    }
  } else {
    for (int c = tid; c < 128 * 8; c += 256) {
      int row = c >> 3, c8 = (c & 7) * 8;
      int gm = bm + row, gn = bn + c8;
      if (gm >= M) continue;
      size_t obase = (size_t)gm * ldc + gn;
      s16x8 o;
      if (Xg) {
        s16x8 xv = *(const s16x8*)(Xg + obase);
        s16x8 hv = *(const s16x8*)(Hg + obase);
        #pragma unroll
        for (int rj = 0; rj < 8; ++rj) {
          float v = Ct[row * 68 + c8 + rj] + bias[gn + rj];
          float g = 1.f / (1.f + __expf(-v));
          float x = bf2f((unsigned short)xv[rj]);
          float h = bf2f((unsigned short)hv[rj]);
          o[rj] = (short)f2bf(g * x + (1.f - g) * h);
        }
      } else {
        #pragma unroll
        for (int rj = 0; rj < 8; ++rj) {
          float v = Ct[row * 68 + c8 + rj] + bias[gn + rj];
          if (act) v = v > 0.f ? v : 0.f;
          o[rj] = (short)f2bf(v);
        }
      }
      *(s16x8*)(Cb + obase) = o;
    }
  }
}

// ============ CSR build ============
__global__ void hist_k(const int* __restrict__ ei, int* __restrict__ cnt) {
  int e = blockIdx.x * blockDim.x + threadIdx.x;
  if (e >= NETOT) return;
  int d = (e < NEDGE0) ? ei[NEDGE0 + e] : e - NEDGE0;
  atomicAdd(&cnt[d], 1);
}

__global__ __launch_bounds__(1024) void scan_k(const int* __restrict__ cnt,
                                               int* __restrict__ rowptr) {
  __shared__ int wsum[16];
  __shared__ int carry_s;
  int t = threadIdx.x, lane = t & 63, wv = t >> 6;
  if (t == 0) carry_s = 0;
  __syncthreads();
  for (int base = 0; base < NNODES; base += 1024) {
    int idx = base + t;
    int v = (idx < NNODES) ? cnt[idx] : 0;
    int s = v;
    #pragma unroll
    for (int off = 1; off < 64; off <<= 1) {
      int x = __shfl_up(s, off);
      if (lane >= off) s += x;
    }
    if (lane == 63) wsum[wv] = s;
    __syncthreads();
    if (wv == 0) {
      int ws = (lane < 16) ? wsum[lane] : 0;
      #pragma unroll
      for (int off = 1; off < 16; off <<= 1) {
        int x = __shfl_up(ws, off);
        if (lane >= off) ws += x;
      }
      if (lane < 16) wsum[lane] = ws;
    }
    __syncthreads();
    int carry = carry_s;
    int woff = wv ? wsum[wv - 1] : 0;
    if (idx < NNODES) rowptr[idx] = carry + woff + s - v;
    __syncthreads();
    if (t == 1023) carry_s = carry + wsum[15];
    __syncthreads();
  }
  if (t == 0) rowptr[NNODES] = carry_s;
}

__global__ void scatter_k(const int* __restrict__ ei, const int* __restrict__ rowptr,
                          int* __restrict__ cur, int* __restrict__ esrc) {
  int e = blockIdx.x * blockDim.x + threadIdx.x;
  if (e >= NETOT) return;
  int s, d;
  if (e < NEDGE0) { s = ei[e]; d = ei[NEDGE0 + e]; }
  else { s = d = e - NEDGE0; }
  int pos = rowptr[d] + atomicAdd(&cur[d], 1);
  esrc[pos] = s;
}

// ============ per-node scores: Sc[n][4] = X[n] · wa[j] ============
template<int NCH>
__global__ __launch_bounds__(256) void scoresX_k(
    const unsigned short* __restrict__ X, int stride,
    const float* __restrict__ wa, float* __restrict__ Sc)
{
  int wid = (blockIdx.x * blockDim.x + threadIdx.x) >> 6;
  int lane = threadIdx.x & 63;
  if (wid >= NNODES) return;
  const int K = NCH * 8;
  float d[4] = {0, 0, 0, 0};
  if (lane < NCH) {
    s16x8 xv = *(const s16x8*)(X + (size_t)wid * stride + lane * 8);
    float xf[8];
    #pragma unroll
    for (int r = 0; r < 8; ++r) xf[r] = bf2f((unsigned short)xv[r]);
    #pragma unroll
    for (int j = 0; j < 4; ++j) {
      const float* wp = wa + j * K + lane * 8;
      float s = 0.f;
      #pragma unroll
      for (int r = 0; r < 8; ++r) s += xf[r] * wp[r];
      d[j] = s;
    }
  }
  #pragma unroll
  for (int off = 32; off; off >>= 1) {
    #pragma unroll
    for (int j = 0; j < 4; ++j) d[j] += __shfl_xor(d[j], off);
  }
  if (lane == 0) {
    f32x4 v = {d[0], d[1], d[2], d[3]};
    *(f32x4*)(Sc + (size_t)wid * 4) = v;
  }
}

// ============ fused edge softmax + X-aggregate (wave per node) ============
template<int NCH>
__global__ __launch_bounds__(256) void msgX_k(
    const int* __restrict__ rowptr, const int* __restrict__ esrc,
    const float* __restrict__ Sc, const unsigned short* __restrict__ X,
    int stride, unsigned short* __restrict__ xagg)
{
  int wid = (blockIdx.x * blockDim.x + threadIdx.x) >> 6;
  int lane = threadIdx.x & 63;
  if (wid >= NNODES) return;
  int e0 = rowptr[wid], e1 = rowptr[wid + 1];
  float sd0 = Sc[(size_t)wid * 4 + 2], sd1 = Sc[(size_t)wid * 4 + 3];

  // ---- phase 1: exact per-head max & sum ----
  float m0 = -1e30f, m1 = -1e30f, z0 = 0.f, z1 = 0.f;
  for (int base = e0; base < e1; base += 64) {
    int cnt = e1 - base; if (cnt > 64) cnt = 64;
    float a0 = -1e30f, a1 = -1e30f;
    if (lane < cnt) {
      int sl = esrc[base + lane];
      f32x4 sv = *(const f32x4*)(Sc + (size_t)sl * 4);
      a0 = sv[0] + sd0; a0 = a0 > 0.f ? a0 : 0.2f * a0;
      a1 = sv[1] + sd1; a1 = a1 > 0.f ? a1 : 0.2f * a1;
    }
    float cm0 = a0, cm1 = a1;
    #pragma unroll
    for (int off = 32; off; off >>= 1) {
      cm0 = fmaxf(cm0, __shfl_xor(cm0, off));
      cm1 = fmaxf(cm1, __shfl_xor(cm1, off));
    }
    float nm0 = fmaxf(m0, cm0), nm1 = fmaxf(m1, cm1);
    z0 *= __expf(m0 - nm0); z1 *= __expf(m1 - nm1);
    m0 = nm0; m1 = nm1;
    float w0 = (lane < cnt) ? __expf(a0 - m0) : 0.f;
    float w1 = (lane < cnt) ? __expf(a1 - m1) : 0.f;
    #pragma unroll
    for (int off = 32; off; off >>= 1) {
      w0 += __shfl_xor(w0, off);
      w1 += __shfl_xor(w1, off);
    }
    z0 += w0; z1 += w1;
  }
  float i0 = 1.f / (z0 + 1e-16f), i1 = 1.f / (z1 + 1e-16f);

  float a0h[8] = {0,0,0,0,0,0,0,0};
  float a1h[8] = {0,0,0,0,0,0,0,0};

  // ---- phase 2: final coefs + weighted X gather ----
  for (int base = e0; base < e1; base += 64) {
    int cnt = e1 - base; if (cnt > 64) cnt = 64;
    int sl = 0;
    float c0 = 0.f, c1 = 0.f;
    if (lane < cnt) {
      sl = esrc[base + lane];
      f32x4 sv = *(const f32x4*)(Sc + (size_t)sl * 4);
      float a0 = sv[0] + sd0; a0 = a0 > 0.f ? a0 : 0.2f * a0;
      float a1 = sv[1] + sd1; a1 = a1 > 0.f ? a1 : 0.2f * a1;
      c0 = __expf(a0 - m0) * i0;
      c1 = __expf(a1 - m1) * i1;
    }
    if (NCH == 40) {
      for (int e = 0; e < cnt; ++e) {
        int   s  = __shfl(sl, e);
        float w0 = __shfl(c0, e), w1 = __shfl(c1, e);
        if (lane < NCH) {
          s16x8 xv = *(const s16x8*)(X + (size_t)s * stride + lane * 8);
          #pragma unroll
          for (int r = 0; r < 8; ++r) {
            float xf = bf2f((unsigned short)xv[r]);
            a0h[r] += w0 * xf;
            a1h[r] += w1 * xf;
          }
        }
      }
    } else {  // NCH == 16: 4 edges per step, lane = (edge-sub << 4) | chunk
      for (int e = 0; e < cnt; e += 4) {
        int ee = e + (lane >> 4);
        bool on = ee < cnt;
        int   s  = __shfl(sl, on ? ee : e);
        float w0 = __shfl(c0, on ? ee : e), w1 = __shfl(c1, on ? ee : e);
        if (on) {
          s16x8 xv = *(const s16x8*)(X + (size_t)s * stride + (lane & 15) * 8);
          #pragma unroll
          for (int r = 0; r < 8; ++r) {
            float xf = bf2f((unsigned short)xv[r]);
            a0h[r] += w0 * xf;
            a1h[r] += w1 * xf;
          }
        }
      }
    }
  }

  if (NCH == 16) {
    #pragma unroll
    for (int r = 0; r < 8; ++r) {
      a0h[r] += __shfl_xor(a0h[r], 16); a0h[r] += __shfl_xor(a0h[r], 32);
      a1h[r] += __shfl_xor(a1h[r], 16); a1h[r] += __shfl_xor(a1h[r], 32);
    }
  }
  if (lane < NCH) {
    s16x8 o0, o1;
    #pragma unroll
    for (int r = 0; r < 8; ++r) {
      o0[r] = (short)f2bf(a0h[r]);
      o1[r] = (short)f2bf(a1h[r]);
    }
    unsigned short* op = xagg + (size_t)wid * (2 * NCH * 8);
    *(s16x8*)(op + lane * 8) = o0;
    *(s16x8*)(op + NCH * 8 + lane * 8) = o1;
  }
}

// ============ pooling (sorted batch -> graph ranges) ============
__global__ void gptr_k(const int* __restrict__ batch, int* __restrict__ gptr) {
  int g = blockIdx.x * blockDim.x + threadIdx.x;
  if (g > NGRAPH) return;
  int lo = 0, hi = NNODES;
  while (lo < hi) { int mid = (lo + hi) >> 1; if (batch[mid] < g) lo = mid + 1; else hi = mid; }
  gptr[g] = lo;
}

__global__ __launch_bounds__(256) void pool_k(const unsigned short* __restrict__ hs,
                                              const int* __restrict__ gptr,
                                              unsigned short* __restrict__ pooled) {
  int g = blockIdx.x;
  int n0 = gptr[g], n1 = gptr[g + 1];
  float inv = (n1 > n0) ? 1.f / (float)(n1 - n0) : 0.f;
  for (int c = threadIdx.x; c < KPA; c += 256) {
    float s = 0.f;
    if (c < CH)
      for (int n = n0; n < n1; ++n) s += bf2f(hs[(size_t)n * AST + c]);
    pooled[(size_t)g * KPA + c] = f2bf(s * inv);
  }
}

extern "C" void kernel_launch(void* const* d_in, const int* in_sizes, int n_in,
                              void* d_out, int out_size, void* d_ws, size_t ws_size,
                              hipStream_t stream)
{
  const float* mol_x = (const float*)d_in[0];
  const int*   ei    = (const int*)d_in[1];
  const int*   batch = (const int*)d_in[2];
  const float* W0  = (const float*)d_in[3];
  const float* as0 = (const float*)d_in[4];
  const float* ad0 = (const float*)d_in[5];
  const float* b0  = (const float*)d_in[6];
  const float* W1  = (const float*)d_in[7];
  const float* as1 = (const float*)d_in[8];
  const float* ad1 = (const float*)d_in[9];
  const float* b1  = (const float*)d_in[10];
  const float* W2  = (const float*)d_in[11];
  const float* as2 = (const float*)d_in[12];
  const float* ad2 = (const float*)d_in[13];
  const float* b2  = (const float*)d_in[14];
  const float* fc1w = (const float*)d_in[15];
  const float* fc1b = (const float*)d_in[16];
  const float* fc2w = (const float*)d_in[17];
  const float* fc2b = (const float*)d_in[18];
  const float* mbias = (const float*)d_in[19];
  const float* g1w = (const float*)d_in[20];
  const float* g1b = (const float*)d_in[21];
  const float* g2w = (const float*)d_in[22];
  const float* g2b = (const float*)d_in[23];
  float* out = (float*)d_out;

  char* ws = (char*)d_ws;
  size_t off = 0;
  auto alloc = [&](size_t b) { size_t r = off; off += (b + 255) & ~(size_t)255; return r; };
  unsigned short* xagg = (unsigned short*)(ws + alloc((size_t)MP * AST * 2));
  unsigned short* actA = (unsigned short*)(ws + alloc((size_t)MP * AST * 2));
  unsigned short* actB = (unsigned short*)(ws + alloc((size_t)MP * AST * 2));
  unsigned short* xb0  = (unsigned short*)(ws + alloc((size_t)MP * KP0 * 2));
  float* Sc     = (float*)(ws + alloc((size_t)MP * 4 * 4));
  int*   cnt    = (int*)(ws + alloc((size_t)2 * NNODES * 4));
  int*   cnt2   = cnt + NNODES;
  int*   rowptr = (int*)(ws + alloc((size_t)(NNODES + 1) * 4));
  int*   esrc   = (int*)(ws + alloc((size_t)NETOT * 4));
  int*   gptr   = (int*)(ws + alloc((size_t)(NGRAPH + 1) * 4));
  float* gbias  = (float*)(ws + alloc((size_t)KPA * 4));
  float* bp0    = (float*)(ws + alloc((size_t)KPA * 4));
  float* bp1    = (float*)(ws + alloc((size_t)KPA * 4));
  float* bp2    = (float*)(ws + alloc((size_t)KPA * 4));
  float* wa0    = (float*)(ws + alloc((size_t)4 * KP0 * 4));
  float* wa1    = (float*)(ws + alloc((size_t)4 * KPA * 4));
  float* wa2    = (float*)(ws + alloc((size_t)4 * KPA * 4));
  unsigned short* pooled_b = (unsigned short*)(ws + alloc((size_t)NGRAPH * KPA * 2));
  unsigned short* gbuf_b   = (unsigned short*)(ws + alloc((size_t)NGRAPH * GW1 * 2));
  unsigned short* comb0t = (unsigned short*)(ws + alloc((size_t)384 * 256 * 2));
  unsigned short* comb1t = (unsigned short*)(ws + alloc((size_t)384 * AST * 2));
  unsigned short* comb2t = (unsigned short*)(ws + alloc((size_t)384 * AST * 2));
  unsigned short* fc12t  = (unsigned short*)(ws + alloc((size_t)384 * AST * 2));
  unsigned short* g1t    = (unsigned short*)(ws + alloc((size_t)GW1 * KPA * 2));
  unsigned short* g2t    = (unsigned short*)(ws + alloc((size_t)128 * GW1 * 2));

  // ---- pre-pass ----
  hipMemsetAsync(cnt, 0, (size_t)2 * NNODES * 4, stream);
  hist_k<<<(NETOT + 255) / 256, 256, 0, stream>>>(ei, cnt);
  scan_k<<<1, 1024, 0, stream>>>(cnt, rowptr);
  scatter_k<<<(NETOT + 255) / 256, 256, 0, stream>>>(ei, rowptr, cnt2, esrc);
  gptr_k<<<(NGRAPH + 256) / 256, 256, 0, stream>>>(batch, gptr);
  cvt0_k<<<(MP * KP0 + 255) / 256, 256, 0, stream>>>(mol_x, xb0);
  combcast_k<<<(384 * 256 + 255) / 256, 256, 0, stream>>>(W0, comb0t, 78, KP0);
  combcast_k<<<(384 * AST + 255) / 256, 256, 0, stream>>>(W1, comb1t, CH, KPA);
  combcast_k<<<(384 * AST + 255) / 256, 256, 0, stream>>>(W2, comb2t, CH, KPA);
  wafill_k<<<(4 * KP0 + 255) / 256, 256, 0, stream>>>(W0, as0, ad0, wa0, 78, KP0);
  wafill_k<<<(4 * KPA + 255) / 256, 256, 0, stream>>>(W1, as1, ad1, wa1, CH, KPA);
  wafill_k<<<(4 * KPA + 255) / 256, 256, 0, stream>>>(W2, as2, ad2, wa2, CH, KPA);
  tcast2_k<<<(384 * AST + 255) / 256, 256, 0, stream>>>(fc1w, fc2w, fc12t);
  biasprep_k<<<(4 * KPA + 255) / 256, 256, 0, stream>>>(b0, b1, b2, fc1b, fc2b, mbias,
                                                        bp0, bp1, bp2, gbias);
  tcast_k<<<(GW1 * KPA + 255) / 256, 256, 0, stream>>>(g1w, g1t, CH, GW1, KPA, GW1);
  tcast_k<<<(128 * GW1 + 255) / 256, 256, 0, stream>>>(g2w, g2t, GW1, 128, GW1, 128);

  auto mgemm = [&](const unsigned short* A, int lda, const unsigned short* Bt,
                   unsigned short* Cb, float* Cf, const float* bias,
                   const unsigned short* Xg, const unsigned short* Hg,
                   int M, int N, int KP_, int ldc, int act) {
    int gx = (N + 63) / 64, gy = (M + 127) / 128;
    hipLaunchKernelGGL(gemm_bb, dim3(gx * gy), dim3(256), 0, stream, A, lda, Bt,
                       Cb, Cf, bias, Xg, Hg, M, N, KP_, ldc, act, gx);
  };

  const int MSGB = (NNODES * 64 + 255) / 256;
  unsigned short* hA = actA + KPA;   // h-slot of actA
  unsigned short* hB = actB + KPA;   // h-slot of actB

  // ---- layer 0: scores on xb0 -> aggregate X -> combined GEMM -> hA ----
  scoresX_k<16><<<MSGB, 256, 0, stream>>>(xb0, KP0, wa0, Sc);
  msgX_k<16><<<MSGB, 256, 0, stream>>>(rowptr, esrc, Sc, xb0, KP0, xagg);
  mgemm(xagg, 256, comb0t, hA, nullptr, bp0, nullptr, nullptr,
        NNODES, KPA, 256, AST, 1);

  // ---- layer 1 ----
  scoresX_k<40><<<MSGB, 256, 0, stream>>>(hA, AST, wa1, Sc);
  msgX_k<40><<<MSGB, 256, 0, stream>>>(rowptr, esrc, Sc, hA, AST, xagg);
  mgemm(xagg, AST, comb1t, actA, nullptr, bp1, nullptr, nullptr,
        NNODES, KPA, AST, AST, 1);                       // x-slot of actA
  mgemm(actA, AST, fc12t, hB, nullptr, gbias, actA, hA,
        NNODES, KPA, AST, AST, 0);                       // gate -> hB

  // ---- layer 2 ----
  scoresX_k<40><<<MSGB, 256, 0, stream>>>(hB, AST, wa2, Sc);
  msgX_k<40><<<MSGB, 256, 0, stream>>>(rowptr, esrc, Sc, hB, AST, xagg);
  mgemm(xagg, AST, comb2t, actB, nullptr, bp2, nullptr, nullptr,
        NNODES, KPA, AST, AST, 0);                       // x-slot of actB (no relu)
  mgemm(actB, AST, fc12t, hA, nullptr, gbias, actB, hB,
        NNODES, KPA, AST, AST, 0);                       // gate -> hA

  // ---- pool + head ----
  pool_k<<<NGRAPH, 256, 0, stream>>>(hA, gptr, pooled_b);
  mgemm(pooled_b, KPA, g1t, gbuf_b, nullptr, g1b, nullptr, nullptr,
        NGRAPH, GW1, KPA, GW1, 1);
  mgemm(gbuf_b, GW1, g2t, nullptr, out, g2b, nullptr, nullptr,
        NGRAPH, 128, GW1, 128, 0);
}